// Round 4
// baseline (3312.708 us; speedup 1.0000x reference)
//
#include <hip/hip_runtime.h>

#define N_     50000
#define E_     150000
#define R_     3
#define H_     512
#define HEADS_ 8
#define DH_    64
#define NCLS_  23
#define CHUNK_ 12500   // nodes per QKV/MHA chunk (N_/4)
#define SCNB_  49      // ceil(N_/1024) scan blocks per relation

typedef unsigned short u16;
typedef unsigned int   u32;
typedef __attribute__((ext_vector_type(8))) short bf16x8;
typedef __attribute__((ext_vector_type(4))) float f32x4;

__device__ __forceinline__ float bf2f(u16 u) {
  union { u32 i; float f; } v; v.i = ((u32)u) << 16; return v.f;
}
__device__ __forceinline__ u16 f2bf(float f) {
  u32 u = __float_as_uint(f);
  u += 0x7fffu + ((u >> 16) & 1u);   // round-to-nearest-even
  return (u16)(u >> 16);
}

// 8 bf16 -> 8 fp32 via one 16B load
__device__ __forceinline__ void ld8(const u16* __restrict__ p, float o[8]) {
  uint4 v = *(const uint4*)p;
  o[0] = bf2f((u16)(v.x & 0xffff)); o[1] = bf2f((u16)(v.x >> 16));
  o[2] = bf2f((u16)(v.y & 0xffff)); o[3] = bf2f((u16)(v.y >> 16));
  o[4] = bf2f((u16)(v.z & 0xffff)); o[5] = bf2f((u16)(v.z >> 16));
  o[6] = bf2f((u16)(v.w & 0xffff)); o[7] = bf2f((u16)(v.w >> 16));
}

// wave-wide sum, result broadcast to all 64 lanes
__device__ __forceinline__ float wsumb(float v) {
  #pragma unroll
  for (int o = 32; o > 0; o >>= 1) v += __shfl_down(v, o, 64);
  return __shfl(v, 0, 64);
}

// async global->LDS, 16B per lane
__device__ __forceinline__ void gl_lds16(const u16* g, u16* l) {
  __builtin_amdgcn_global_load_lds(
      (const __attribute__((address_space(1))) unsigned int*)g,
      (__attribute__((address_space(3))) unsigned int*)l, 16, 0, 0);
}

// ---------------- ws-size probe fallback ----------------
__global__ __launch_bounds__(256) void write_const(u16* __restrict__ out, int n, float v) {
  int i = blockIdx.x * blockDim.x + threadIdx.x;
  if (i < n) out[i] = f2bf(v);
}

// ---------------- dtype probe ----------------
__global__ void detect_dtype(const void* __restrict__ wc, int* __restrict__ flag) {
  __shared__ int cnt;
  if (threadIdx.x == 0) cnt = 0;
  __syncthreads();
  const u16* p = (const u16*)wc;
  int ok = 0;
  for (int i = threadIdx.x; i < 2048; i += 256) {
    float a = fabsf(bf2f(p[i]));
    if (a <= 4.0f) ok++;
  }
  atomicAdd(&cnt, ok);
  __syncthreads();
  if (threadIdx.x == 0) *flag = (cnt >= 2000) ? 1 : 0;   // 1=bf16, 0=fp32
}

// stage float tensor -> bf16 ws
__global__ __launch_bounds__(256) void stage_bf16(const void* __restrict__ in, size_t off,
                                                  u16* __restrict__ out, int n,
                                                  const int* __restrict__ flag) {
  int i = blockIdx.x * blockDim.x + threadIdx.x;
  if (i >= n) return;
  out[i] = (*flag) ? ((const u16*)in)[off + i] : f2bf(((const float*)in)[off + i]);
}

// stage 512x512 weight slices TRANSPOSED: out[n][k] = in[k][n]; grid.z = matrix idx
__global__ __launch_bounds__(256) void stageT(const void* __restrict__ in, size_t in_off,
                                              size_t in_mstride, u16* __restrict__ out,
                                              size_t out_mstride, const int* __restrict__ flag) {
  __shared__ u16 tile[32][33];
  const int m = blockIdx.z;
  const size_t ib = in_off + (size_t)m * in_mstride;
  const size_t ob = (size_t)m * out_mstride;
  const int kb = blockIdx.x * 32, nb = blockIdx.y * 32;
  const int tx = threadIdx.x, ty = threadIdx.y;
  const bool isbf = (*flag != 0);
  #pragma unroll
  for (int i = 0; i < 32; i += 8) {
    size_t si = ib + (size_t)(kb + ty + i) * 512 + nb + tx;
    tile[ty + i][tx] = isbf ? ((const u16*)in)[si] : f2bf(((const float*)in)[si]);
  }
  __syncthreads();
  #pragma unroll
  for (int i = 0; i < 32; i += 8)
    out[ob + (size_t)(nb + ty + i) * 512 + kb + tx] = tile[tx][ty + i];
}

// stage Wout transposed + zero-padded to [128][512]
__global__ __launch_bounds__(256) void stage_wclsT(const void* __restrict__ in,
                                                   u16* __restrict__ out,
                                                   const int* __restrict__ flag) {
  int i = blockIdx.x * blockDim.x + threadIdx.x;
  if (i >= 128 * 512) return;
  int c = i >> 9, k = i & 511;
  u16 v = 0;
  if (c < NCLS_) {
    size_t si = (size_t)k * NCLS_ + c;
    v = (*flag) ? ((const u16*)in)[si] : f2bf(((const float*)in)[si]);
  }
  out[i] = v;
}
__global__ void stage_bcls(const void* __restrict__ in, u16* __restrict__ out,
                           const int* __restrict__ flag) {
  int i = threadIdx.x;
  if (i >= 128) return;
  u16 v = 0;
  if (i < NCLS_) v = (*flag) ? ((const u16*)in)[i] : f2bf(((const float*)in)[i]);
  out[i] = v;
}

// ---------------- degrees ----------------
__global__ __launch_bounds__(256) void deg_count(const int* __restrict__ src,
                                                 const int* __restrict__ dst,
                                                 float* __restrict__ degout,
                                                 float* __restrict__ degin) {
  int idx = blockIdx.x * blockDim.x + threadIdx.x;
  if (idx >= R_ * E_) return;
  int r = idx / E_;
  atomicAdd(&degout[r * N_ + src[idx]], 1.0f);
  atomicAdd(&degin [r * N_ + dst[idx]], 1.0f);
}
__global__ __launch_bounds__(256) void deg_fin(float* __restrict__ deg) {
  int idx = blockIdx.x * blockDim.x + threadIdx.x;
  if (idx >= 2 * R_ * N_) return;
  deg[idx] = rsqrtf(fmaxf(deg[idx], 1.0f));
}

// ---------------- CSR build: parallel 3-phase exclusive scan ----------------
__global__ __launch_bounds__(256) void scan_blksum(const float* __restrict__ cnt,
                                                   u32* __restrict__ partial) {
  const int r = blockIdx.y, b = blockIdx.x;
  const int base = b * 1024;
  const float* c = cnt + (size_t)r * N_;
  const int t = threadIdx.x;
  u32 s = 0;
  #pragma unroll
  for (int k = 0; k < 4; ++k) {
    int i = base + t * 4 + k;
    if (i < N_) s += (u32)c[i];
  }
  #pragma unroll
  for (int o = 32; o > 0; o >>= 1) s += __shfl_down(s, o, 64);
  __shared__ u32 ws[4];
  if ((t & 63) == 0) ws[t >> 6] = s;
  __syncthreads();
  if (t == 0) partial[r * SCNB_ + b] = ws[0] + ws[1] + ws[2] + ws[3];
}

__global__ void scan_partials(u32* __restrict__ partial, u32* __restrict__ ptr) {
  const int r = blockIdx.x;
  u32* p = partial + r * SCNB_;
  const int l = threadIdx.x;           // 64 threads = 1 wave
  u32 v = (l < SCNB_) ? p[l] : 0u;
  u32 s = v;
  #pragma unroll
  for (int o = 1; o < 64; o <<= 1) {
    u32 n = __shfl_up(s, o, 64);
    if (l >= o) s += n;
  }
  if (l < SCNB_) p[l] = s - v;         // exclusive
  if (l == 63) ptr[(size_t)r * (N_ + 1) + N_] = s;   // grand total
}

__global__ __launch_bounds__(256) void scan_write(const float* __restrict__ cnt,
                                                  const u32* __restrict__ partial,
                                                  u32* __restrict__ ptr) {
  const int r = blockIdx.y, b = blockIdx.x;
  const int base = b * 1024;
  const float* c = cnt + (size_t)r * N_;
  u32* p = ptr + (size_t)r * (N_ + 1);
  const int t = threadIdx.x, lane = t & 63, w = t >> 6;
  u32 v[4]; u32 ts = 0;
  #pragma unroll
  for (int k = 0; k < 4; ++k) {
    int i = base + t * 4 + k;
    v[k] = (i < N_) ? (u32)c[i] : 0u;
    ts += v[k];
  }
  u32 s = ts;
  #pragma unroll
  for (int o = 1; o < 64; o <<= 1) {
    u32 n = __shfl_up(s, o, 64);
    if (lane >= o) s += n;
  }
  __shared__ u32 ws[4];
  if (lane == 63) ws[w] = s;
  __syncthreads();
  u32 off = partial[r * SCNB_ + b];
  for (int k = 0; k < w; ++k) off += ws[k];
  off += s - ts;                        // exclusive offset of this thread
  u32 run = 0;
  #pragma unroll
  for (int k = 0; k < 4; ++k) {
    int i = base + t * 4 + k;
    if (i < N_) p[i] = off + run;
    run += v[k];
  }
}

__global__ __launch_bounds__(256) void csr_scatter(const int* __restrict__ dst,
                                                   const u32* __restrict__ ptr,
                                                   u32* __restrict__ fill,
                                                   u32* __restrict__ eidx) {
  int idx = blockIdx.x * blockDim.x + threadIdx.x;
  if (idx >= R_ * E_) return;
  int r = idx / E_, e = idx - r * E_;
  int d = dst[idx];
  u32 pos = ptr[(size_t)r * (N_ + 1) + d] + atomicAdd(&fill[(size_t)r * N_ + d], 1u);
  eidx[(size_t)r * E_ + pos] = (u32)e;
}

// ---- legacy 128x128 MFMA GEMM (kept for the small classifier GEMM) ----
__global__ __launch_bounds__(256, 2) void gemm_mfma(const u16* __restrict__ A,
                                                    const u16* __restrict__ BT,
                                                    const u16* __restrict__ bias,
                                                    u16* __restrict__ C,
                                                    int M, int ldc) {
  __shared__ u16 As[128 * 32];
  __shared__ u16 Bs[128 * 32];
  const int t = threadIdx.x;
  const int w = t >> 6, l = t & 63;
  const int bm = blockIdx.x * 128, bn = blockIdx.y * 128;
  const int wm = (w & 1) * 64, wn = (w >> 1) * 64;
  const int srow = w * 16 + (l >> 2);
  const int scol = (l & 3) * 8;
  f32x4 acc[4][4] = {};

  for (int k0 = 0; k0 < 512; k0 += 32) {
    #pragma unroll
    for (int p = 0; p < 2; ++p) {
      gl_lds16(A  + (size_t)(bm + p * 64 + srow) * 512 + k0 + scol, &As[(p * 64 + w * 16) * 32]);
      gl_lds16(BT + (size_t)(bn + p * 64 + srow) * 512 + k0 + scol, &Bs[(p * 64 + w * 16) * 32]);
    }
    __syncthreads();
    bf16x8 af[4], bfr[4];
    #pragma unroll
    for (int i = 0; i < 4; ++i) {
      af[i]  = *(const bf16x8*)&As[(wm + i * 16 + (l & 15)) * 32 + (l >> 4) * 8];
      bfr[i] = *(const bf16x8*)&Bs[(wn + i * 16 + (l & 15)) * 32 + (l >> 4) * 8];
    }
    #pragma unroll
    for (int mi = 0; mi < 4; ++mi)
      #pragma unroll
      for (int ni = 0; ni < 4; ++ni)
        acc[mi][ni] = __builtin_amdgcn_mfma_f32_16x16x32_bf16(af[mi], bfr[ni], acc[mi][ni], 0, 0, 0);
    __syncthreads();
  }

  float bv[4] = {0.f, 0.f, 0.f, 0.f};
  if (bias) {
    #pragma unroll
    for (int ni = 0; ni < 4; ++ni) bv[ni] = bf2f(bias[bn + wn + ni * 16 + (l & 15)]);
  }
  const int col0 = bn + wn + (l & 15);
  #pragma unroll
  for (int mi = 0; mi < 4; ++mi) {
    #pragma unroll
    for (int reg = 0; reg < 4; ++reg) {
      int gr = bm + wm + mi * 16 + (l >> 4) * 4 + reg;
      if (gr < M) {
        size_t rb = (size_t)gr * ldc;
        #pragma unroll
        for (int ni = 0; ni < 4; ++ni)
          C[rb + col0 + ni * 16] = f2bf(acc[mi][ni][reg] + bv[ni]);
      }
    }
  }
}

// ---- 256x256 MFMA GEMM, 4-phase/K-tile pipeline + counted vmcnt + LDS XOR-swizzle ----
// A[M,512] @ BT[Nn,512]^T -> C[M,ldc]; K=512 (8 K-tiles of 64).
// 8 waves (2Mx4N), per-wave C = 128x64. LDS 128 KiB: 2 bufs x (A 256x64 | B 256x64) bf16.
// Swizzle: 16B-chunk index ^= (row & 7) on gload SOURCE and ds_read (involution).
// Per K-tile kt (dbuf kt&1):
//  P1: vmcnt(8) bar | 24 ds_read (ALL frags) | lgkm(0) bar | stage u0(kt+2) | prio 16-MFMA
//  P2..P4: bar | stage u1..u3(kt+2) | prio 16-MFMA
// Race-safety: after P1's lgkm(0)+bar nobody reads dbuf[kt&1] again this tile, so
// staging kt+2 into it is safe; vmcnt(8) at P1 (8 newest = tile kt+1's loads)
// guarantees tile kt fully resident. MFMA order per-acc identical to 2-phase version.
__global__ __launch_bounds__(512, 2) void gemm256(const u16* __restrict__ A,
                                                  const u16* __restrict__ BT,
                                                  const u16* __restrict__ bias,
                                                  u16* __restrict__ C,
                                                  int M, int ldc, int nb) {
  __shared__ u16 lds[65536];           // 128 KiB
  const int t = threadIdx.x;
  const int w = t >> 6, l = t & 63;
  const int wr = w >> 2, wc = w & 3;

  // XCD-bijective swizzle (m204), bn-fastest so one XCD walks a bm-panel across all bn
  const int nwg = gridDim.x;
  const int q = nwg >> 3, r = nwg & 7;
  const int xcd = blockIdx.x & 7, loc = blockIdx.x >> 3;
  const int wg = (xcd < r ? xcd * (q + 1) : r * (q + 1) + (xcd - r) * q) + loc;
  const int bn = (wg % nb) * 256;
  const int bm = (wg / nb) * 256;

  // staging addresses: lane l covers row w*8+(l>>3) (+64*i), swizzled source chunk
  const int lrow = l >> 3, lc8 = l & 7;
  const int csrc = ((lc8 ^ lrow) << 3);                 // element offset in 64-col K-tile
  const u16* Ag = A  + (size_t)(bm + w * 8 + lrow) * 512 + csrc;
  const u16* Bg = BT + (size_t)(bn + w * 8 + lrow) * 512 + csrc;

  // stage unit u of tile kt into dbuf buf: u = {0:A-half0, 1:B-half0, 2:A-half1, 3:B-half1}
  auto stage_unit = [&](int kt, int buf, int u) {
    const size_t ko = (size_t)kt * 64;
    const int isB = u & 1, half = u >> 1;
    const u16* G = isB ? Bg : Ag;
    u16* L = &lds[buf * 32768 + isB * 16384 + half * 8192];
    #pragma unroll
    for (int i = 0; i < 2; ++i)
      gl_lds16(G + (size_t)(half * 128 + i * 64) * 512 + ko, &L[i * 4096 + w * 512]);
  };

  // fragment-read offsets (u16 units), with matching XOR swizzle
  const int rl = l & 15, rh = l >> 4;                   // rh in 0..3
  const int key = l & 7;                                // row_local & 7
  const int aoff = (wr * 128 + rl) * 64;
  const int boff = (wc * 64  + rl) * 64;
  const int c0 = ((rh)     ^ key) << 3;                 // kk=0 chunk
  const int c1 = ((4 + rh) ^ key) << 3;                 // kk=1 chunk

  f32x4 acc[8][4] = {};

  // prologue: tiles 0 and 1 (4 units each, in unit order)
  #pragma unroll
  for (int u = 0; u < 4; ++u) stage_unit(0, 0, u);
  #pragma unroll
  for (int u = 0; u < 4; ++u) stage_unit(1, 1, u);

  #pragma unroll
  for (int kt = 0; kt < 8; ++kt) {
    // ---- P1: tile kt resident; read everything; free the buffer ----
    if (kt == 7) asm volatile("s_waitcnt vmcnt(0)" ::: "memory");
    else         asm volatile("s_waitcnt vmcnt(8)" ::: "memory");
    __builtin_amdgcn_s_barrier();
    asm volatile("" ::: "memory");

    const u16* Ab = &lds[(kt & 1) * 32768];
    const u16* Bb = Ab + 16384;
    bf16x8 a0[8], a1[8], b0[4], b1[4];
    #pragma unroll
    for (int mt = 0; mt < 8; ++mt) {
      a0[mt] = *(const bf16x8*)&Ab[aoff + mt * 1024 + c0];
      a1[mt] = *(const bf16x8*)&Ab[aoff + mt * 1024 + c1];
    }
    #pragma unroll
    for (int nt = 0; nt < 4; ++nt) {
      b0[nt] = *(const bf16x8*)&Bb[boff + nt * 1024 + c0];
      b1[nt] = *(const bf16x8*)&Bb[boff + nt * 1024 + c1];
    }
    asm volatile("s_waitcnt lgkmcnt(0)" ::: "memory");
    __builtin_amdgcn_s_barrier();
    asm volatile("" ::: "memory");

    if (kt < 6) stage_unit(kt + 2, kt & 1, 0);
    __builtin_amdgcn_s_setprio(1);
    #pragma unroll
    for (int mt = 0; mt < 4; ++mt)
      #pragma unroll
      for (int nt = 0; nt < 4; ++nt)
        acc[mt][nt] = __builtin_amdgcn_mfma_f32_16x16x32_bf16(a0[mt], b0[nt], acc[mt][nt], 0, 0, 0);
    __builtin_amdgcn_s_setprio(0);

    // ---- P2 ----
    __builtin_amdgcn_s_barrier();
    asm volatile("" ::: "memory");
    if (kt < 6) stage_unit(kt + 2, kt & 1, 1);
    __builtin_amdgcn_s_setprio(1);
    #pragma unroll
    for (int mt = 4; mt < 8; ++mt)
      #pragma unroll
      for (int nt = 0; nt < 4; ++nt)
        acc[mt][nt] = __builtin_amdgcn_mfma_f32_16x16x32_bf16(a0[mt], b0[nt], acc[mt][nt], 0, 0, 0);
    __builtin_amdgcn_s_setprio(0);

    // ---- P3 ----
    __builtin_amdgcn_s_barrier();
    asm volatile("" ::: "memory");
    if (kt < 6) stage_unit(kt + 2, kt & 1, 2);
    __builtin_amdgcn_s_setprio(1);
    #pragma unroll
    for (int mt = 0; mt < 4; ++mt)
      #pragma unroll
      for (int nt = 0; nt < 4; ++nt)
        acc[mt][nt] = __builtin_amdgcn_mfma_f32_16x16x32_bf16(a1[mt], b1[nt], acc[mt][nt], 0, 0, 0);
    __builtin_amdgcn_s_setprio(0);

    // ---- P4 ----
    __builtin_amdgcn_s_barrier();
    asm volatile("" ::: "memory");
    if (kt < 6) stage_unit(kt + 2, kt & 1, 3);
    __builtin_amdgcn_s_setprio(1);
    #pragma unroll
    for (int mt = 4; mt < 8; ++mt)
      #pragma unroll
      for (int nt = 0; nt < 4; ++nt)
        acc[mt][nt] = __builtin_amdgcn_mfma_f32_16x16x32_bf16(a1[mt], b1[nt], acc[mt][nt], 0, 0, 0);
    __builtin_amdgcn_s_setprio(0);
  }

  // ---- vectorized epilogue: per-wave 4 KiB LDS f32 transpose -> 8B stores ----
  // Safe: all ds_reads drained at kt=7 P1 (lgkm(0)+bar); all gloads drained (vmcnt(0));
  // epilogue regions are per-wave private.
  float bv[4] = {0.f, 0.f, 0.f, 0.f};
  if (bias) {
    #pragma unroll
    for (int nt = 0; nt < 4; ++nt) bv[nt] = bf2f(bias[bn + wc * 64 + nt * 16 + rl]);
  }
  float* F = (float*)&lds[(size_t)w * 2048];   // [16][64] f32 per wave
  #pragma unroll
  for (int mt = 0; mt < 8; ++mt) {
    #pragma unroll
    for (int nt = 0; nt < 4; ++nt) {
      const int colw = (nt * 16 + rl) ^ ((rh & 1) << 4);
      #pragma unroll
      for (int reg = 0; reg < 4; ++reg)
        F[(rh * 4 + reg) * 64 + colw] = acc[mt][nt][reg] + bv[nt];
    }
    #pragma unroll
    for (int j = 0; j < 4; ++j) {
      const int row = rh + 4 * j;
      const int chunk = rl ^ ((j & 1) << 2);
      f32x4 vv = *(const f32x4*)&F[row * 64 + chunk * 4];
      u32 lo = (u32)f2bf(vv[0]) | ((u32)f2bf(vv[1]) << 16);
      u32 hi = (u32)f2bf(vv[2]) | ((u32)f2bf(vv[3]) << 16);
      const int gr = bm + wr * 128 + mt * 16 + row;
      if (gr < M) {
        uint2 pk; pk.x = lo; pk.y = hi;
        *(uint2*)&C[(size_t)gr * ldc + bn + wc * 64 + rl * 4] = pk;
      }
    }
  }
}

// ---- fused epilogue v2: wave-per-node, 16B loads ----
__global__ __launch_bounds__(256) void agg3_ln(const u16* __restrict__ fb,
                                               const int* __restrict__ src_r,
                                               const u32* __restrict__ ptr,
                                               const u32* __restrict__ eidx,
                                               const float* __restrict__ dors,
                                               const float* __restrict__ dirs,
                                               const float* __restrict__ alpha,
                                               const float* __restrict__ sx,
                                               const u16* __restrict__ bc,  const u16* __restrict__ gc,  const u16* __restrict__ bec,
                                               const u16* __restrict__ bg,  const u16* __restrict__ gg,  const u16* __restrict__ beg,
                                               const u16* __restrict__ bs,  const u16* __restrict__ gs,  const u16* __restrict__ bes,
                                               u16* __restrict__ out) {
  const int l  = threadIdx.x & 63;
  const int d  = blockIdx.x * 4 + (threadIdx.x >> 6);
  const int c0 = l * 8;          // 8 cols, within one head (head = l>>3)
  const int hd = l >> 3;
  float sxv = sx[d * 8 + hd];
  float inv = (sxv > 0.f) ? 1.0f / sxv : 1.0f;
  const float dird = dirs[d];

  float cv[8] = {0,0,0,0,0,0,0,0}, gv[8] = {0,0,0,0,0,0,0,0};
  const u32 p0 = ptr[d], p1 = ptr[d + 1];
  for (u32 i = p0; i < p1; ++i) {
    u32 e = eidx[i];
    int s = src_r[e];
    float sc = dors[s] * dird;
    float wg = alpha[e * 8 + hd] * inv;
    const u16* xr = fb + (size_t)s * 1536 + c0;
    float a[8], b[8];
    ld8(xr, a); ld8(xr + 512, b);
    #pragma unroll
    for (int j = 0; j < 8; ++j) {
      cv[j] = fmaf(a[j], sc, cv[j]);
      gv[j] = fmaf(b[j], wg, gv[j]);
    }
  }
  float sv[8];
  ld8(fb + (size_t)d * 1536 + 1024 + c0, sv);
  float t8[8];
  ld8(bc + c0, t8);
  #pragma unroll
  for (int j = 0; j < 8; ++j) cv[j] += t8[j];
  ld8(bg + c0, t8);
  #pragma unroll
  for (int j = 0; j < 8; ++j) gv[j] += t8[j];
  ld8(bs + c0, t8);
  #pragma unroll
  for (int j = 0; j < 8; ++j) sv[j] += t8[j];

  float s;
  s = 0.f;
  #pragma unroll
  for (int j = 0; j < 8; ++j) s += cv[j];
  float mc = wsumb(s) * (1.0f / 512.0f);
  s = 0.f;
  #pragma unroll
  for (int j = 0; j < 8; ++j) { cv[j] -= mc; s += cv[j] * cv[j]; }
  float rc = rsqrtf(wsumb(s) * (1.0f / 512.0f) + 1e-12f);

  s = 0.f;
  #pragma unroll
  for (int j = 0; j < 8; ++j) s += gv[j];
  float mg = wsumb(s) * (1.0f / 512.0f);
  s = 0.f;
  #pragma unroll
  for (int j = 0; j < 8; ++j) { gv[j] -= mg; s += gv[j] * gv[j]; }
  float rg = rsqrtf(wsumb(s) * (1.0f / 512.0f) + 1e-12f);

  s = 0.f;
  #pragma unroll
  for (int j = 0; j < 8; ++j) s += sv[j];
  float ms = wsumb(s) * (1.0f / 512.0f);
  s = 0.f;
  #pragma unroll
  for (int j = 0; j < 8; ++j) { sv[j] -= ms; s += sv[j] * sv[j]; }
  float rs = rsqrtf(wsumb(s) * (1.0f / 512.0f) + 1e-12f);

  float o8[8];
  float ga[8], be8[8];
  ld8(gc + c0, ga); ld8(bec + c0, be8);
  #pragma unroll
  for (int j = 0; j < 8; ++j) {
    float y = ga[j] * cv[j] * rc + be8[j];
    o8[j] = (y > 0.f) ? y : expm1f(y);
  }
  ld8(gg + c0, ga); ld8(beg + c0, be8);
  #pragma unroll
  for (int j = 0; j < 8; ++j) {
    float y = ga[j] * gv[j] * rg + be8[j];
    o8[j] += (y > 0.f) ? y : expm1f(y);
  }
  ld8(gs + c0, ga); ld8(bes + c0, be8);
  #pragma unroll
  for (int j = 0; j < 8; ++j) {
    float y = ga[j] * sv[j] * rs + be8[j];
    o8[j] += (y > 0.f) ? y : expm1f(y);
  }
  uint4 o;
  u32 wpk[4];
  #pragma unroll
  for (int j = 0; j < 4; ++j)
    wpk[j] = (u32)f2bf(o8[2 * j]) | ((u32)f2bf(o8[2 * j + 1]) << 16);
  o.x = wpk[0]; o.y = wpk[1]; o.z = wpk[2]; o.w = wpk[3];
  *(uint4*)(out + (size_t)d * 1536 + c0) = o;
}

// ---------------- GAT edge softmax ----------------
__global__ __launch_bounds__(256) void gat_el_er(const u16* __restrict__ f, int fstride,
                                                 const u16* __restrict__ al,
                                                 const u16* __restrict__ ar,
                                                 float* __restrict__ el,
                                                 float* __restrict__ er,
                                                 float* __restrict__ sx) {
  int idx = blockIdx.x * blockDim.x + threadIdx.x;
  if (idx >= N_ * HEADS_) return;
  int n = idx >> 3, hd = idx & 7;
  const u16* fr = f + (size_t)n * fstride + hd * 64;
  const u16* alr = al + hd * 64;
  const u16* arr = ar + hd * 64;
  float a = 0.f, b = 0.f;
  for (int d0 = 0; d0 < 64; d0 += 8) {
    float fv[8], av[8], bv[8];
    ld8(fr + d0, fv); ld8(alr + d0, av); ld8(arr + d0, bv);
    #pragma unroll
    for (int j = 0; j < 8; ++j) {
      a = fmaf(fv[j], av[j], a);
      b = fmaf(fv[j], bv[j], b);
    }
  }
  el[idx] = a; er[idx] = b;
  sx[idx] = 0.f;
}

__global__ __launch_bounds__(256) void gat_edge(const int* __restrict__ src,
                                                const int* __restrict__ dst,
                                                const float* __restrict__ el,
                                                const float* __restrict__ er,
                                                float* __restrict__ alpha,
                                                float* __restrict__ sx) {
  int idx = blockIdx.x * blockDim.x + threadIdx.x;
  if (idx >= E_ * HEADS_) return;
  int e = idx >> 3, hd = idx & 7;
  int s = src[e], d = dst[e];
  float v = el[s * 8 + hd] + er[d * 8 + hd];
  v = (v > 0.f) ? v : 0.2f * v;
  float ex = expf(fminf(v, 60.0f));
  alpha[idx] = ex;
  atomicAdd(&sx[d * 8 + hd], ex);
}

// ---------------- fused relation MHA over QKV[row=(n*3+r)][q|k|v 512 each] ----------------
__global__ __launch_bounds__(256) void mha_fused(const u16* __restrict__ QKV,
                                                 u16* __restrict__ hout, int C) {
  int idx = blockIdx.x * blockDim.x + threadIdx.x;
  if (idx >= C * HEADS_) return;
  int n = idx >> 3, hd = idx & 7;
  const u16* b0 = QKV + (size_t)n * 4608 + hd * 64;
  float sc[9] = {0.f,0.f,0.f,0.f,0.f,0.f,0.f,0.f,0.f};
  for (int d0 = 0; d0 < 64; d0 += 8) {
    float q0[8], q1[8], q2[8], k0[8], k1[8], k2[8];
    ld8(b0 + d0, q0);        ld8(b0 + 1536 + d0, q1); ld8(b0 + 3072 + d0, q2);
    ld8(b0 + 512 + d0, k0);  ld8(b0 + 2048 + d0, k1); ld8(b0 + 3584 + d0, k2);
    #pragma unroll
    for (int j = 0; j < 8; ++j) {
      sc[0] = fmaf(q0[j], k0[j], sc[0]); sc[1] = fmaf(q0[j], k1[j], sc[1]); sc[2] = fmaf(q0[j], k2[j], sc[2]);
      sc[3] = fmaf(q1[j], k0[j], sc[3]); sc[4] = fmaf(q1[j], k1[j], sc[4]); sc[5] = fmaf(q1[j], k2[j], sc[5]);
      sc[6] = fmaf(q2[j], k0[j], sc[6]); sc[7] = fmaf(q2[j], k1[j], sc[7]); sc[8] = fmaf(q2[j], k2[j], sc[8]);
    }
  }
  float wp0 = 0.f, wp1 = 0.f, wp2 = 0.f;
  #pragma unroll
  for (int r = 0; r < 3; ++r) {
    float a = sc[r * 3 + 0] * 0.125f;
    float b = sc[r * 3 + 1] * 0.125f;
    float c = sc[r * 3 + 2] * 0.125f;
    float m = fmaxf(a, fmaxf(b, c));
    float ea = expf(a - m), eb = expf(b - m), ec = expf(c - m);
    float inv = 1.0f / (ea + eb + ec);
    wp0 += ea * inv; wp1 += eb * inv; wp2 += ec * inv;
  }
  wp0 *= (1.0f / 3.0f); wp1 *= (1.0f / 3.0f); wp2 *= (1.0f / 3.0f);
  u16* ho = hout + (size_t)n * 512 + hd * 64;
  for (int d0 = 0; d0 < 64; d0 += 8) {
    float v0[8], v1[8], v2[8];
    ld8(b0 + 1024 + d0, v0); ld8(b0 + 2560 + d0, v1); ld8(b0 + 4096 + d0, v2);
    uint4 o;
    u32 w[4];
    #pragma unroll
    for (int j = 0; j < 4; ++j) {
      u16 lo = f2bf(wp0 * v0[2*j]   + wp1 * v1[2*j]   + wp2 * v2[2*j]);
      u16 hi = f2bf(wp0 * v0[2*j+1] + wp1 * v1[2*j+1] + wp2 * v2[2*j+1]);
      w[j] = (u32)lo | ((u32)hi << 16);
    }
    o.x = w[0]; o.y = w[1]; o.z = w[2]; o.w = w[3];
    *(uint4*)(ho + d0) = o;
  }
}

// ---------------- classifier store: clsbuf[N,128] -> d_out[N,23] ----------------
__global__ __launch_bounds__(256) void cls_store(const u16* __restrict__ clsbuf,
                                                 void* __restrict__ out,
                                                 const int* __restrict__ flag) {
  int idx = blockIdx.x * blockDim.x + threadIdx.x;
  if (idx >= N_ * NCLS_) return;
  int n = idx / NCLS_, c = idx - n * NCLS_;
  float s = bf2f(clsbuf[(size_t)n * 128 + c]);
  if (!(s == s)) s = 12345.0f;   // NaN sentinel
  if (*flag) ((u16*)out)[idx] = f2bf(s);
  else       ((float*)out)[idx] = s;
}

static inline int cdiv(long long a, long long b) { return (int)((a + b - 1) / b); }

extern "C" void kernel_launch(void* const* d_in, const int* in_sizes, int n_in,
                              void* d_out, int out_size, void* d_ws, size_t ws_size,
                              hipStream_t stream) {
  // ---- workspace plan (bytes, 256-aligned) ----
  size_t off = 0;
  auto take = [&](size_t bytes) { size_t o = off; off += (bytes + 255) & ~(size_t)255; return o; };
  const size_t o_flag    = take(256);
  const size_t o_stacked = take((size_t)N_ * 1536 * 2);            // 153.6 MB bf16
  const size_t o_h       = take((size_t)N_ * 512 * 2);             //  51.2 MB (feature alias)
  const size_t o_trans   = take((size_t)N_ * 1536 * 2);            // 153.6 MB fbuf / qkv / clsbuf
  const size_t o_el    = take((size_t)N_ * HEADS_ * 4);
  const size_t o_er    = take((size_t)N_ * HEADS_ * 4);
  const size_t o_sx    = take((size_t)N_ * HEADS_ * 4);
  const size_t o_alpha = take((size_t)E_ * HEADS_ * 4);
  const size_t o_deg   = take((size_t)2 * R_ * N_ * 4);
  const size_t o_csrp  = take((size_t)R_ * (N_ + 1) * 4);
  const size_t o_eidx  = take((size_t)R_ * E_ * 4);
  const size_t o_fill  = take((size_t)R_ * N_ * 4);
  const size_t o_part  = take((size_t)R_ * SCNB_ * 4);             // scan partials
  const size_t o_wts   = take((size_t)6500000 * 2);                // staged bf16 weights
  const size_t need = off;

  if (ws_size < need) {
    write_const<<<cdiv(out_size, 256), 256, 0, stream>>>((u16*)d_out, out_size,
                                                         (float)(ws_size >> 20));
    return;
  }

  char* base = (char*)d_ws;
  int*   flag    = (int*)(base + o_flag);
  u16*   stacked = (u16*)(base + o_stacked);
  u16*   h       = (u16*)(base + o_h);
  u16*   fbuf    = (u16*)(base + o_trans);     // [N,1536] fused branch GEMM out
  u16*   qkv     = (u16*)(base + o_trans);     // [CHUNK*3,1536] (aliases, disjoint in time)
  u16*   clsbuf  = (u16*)(base + o_trans);     // [N,128]       (aliases, disjoint in time)
  float* el    = (float*)(base + o_el);
  float* er    = (float*)(base + o_er);
  float* sx    = (float*)(base + o_sx);
  float* alpha = (float*)(base + o_alpha);
  float* degout = (float*)(base + o_deg);
  float* degin  = degout + (size_t)R_ * N_;
  u32*   csrp  = (u32*)(base + o_csrp);
  u32*   eidx  = (u32*)(base + o_eidx);
  u32*   fill  = (u32*)(base + o_fill);
  u32*   part  = (u32*)(base + o_part);

  const int* src = (const int*)d_in[1];
  const int* dst = (const int*)d_in[2];

  // ---- dtype probe ----
  detect_dtype<<<1, 256, 0, stream>>>(d_in[3], flag);

  // ---- staged weight layout (elements within o_wts) ----
  u16* wts   = (u16*)(base + o_wts);
  u16* wbrT  = wts;                              // [6][1536n][512k]: Wc | Wg | Wsk rows
  u16* wqkvT = wbrT + 6 * 786432;                // [2][1536n][512k] (q|k|v)
  u16* bqkv  = wqkvT + 2 * 786432;               // [2][1536]
  u16* wclsT = bqkv + 2 * 1536;                  // [128][512]
  u16* bcls  = wclsT + 128 * 512;                // [128]
  u16* cur   = bcls + 128;
  auto sv = [&](int idx) -> u16* {
    u16* p = cur; cur += in_sizes[idx];
    stage_bf16<<<cdiv(in_sizes[idx], 256), 256, 0, stream>>>(d_in[idx], 0, p, in_sizes[idx], flag);
    return p;
  };

  stage_bf16<<<cdiv(N_ * 512, 256), 256, 0, stream>>>(d_in[0], 0, h, N_ * 512, flag);
  dim3 tb(32, 8);
  stageT<<<dim3(16, 16, 6), tb, 0, stream>>>(d_in[3],  0, 262144, wbrT,          786432, flag);
  stageT<<<dim3(16, 16, 6), tb, 0, stream>>>(d_in[7],  0, 262144, wbrT + 262144, 786432, flag);
  stageT<<<dim3(16, 16, 6), tb, 0, stream>>>(d_in[13], 0, 262144, wbrT + 524288, 786432, flag);
  stageT<<<dim3(16, 16, 2), tb, 0, stream>>>(d_in[17], 0, 262144, wqkvT,          786432, flag);
  stageT<<<dim3(16, 16, 2), tb, 0, stream>>>(d_in[19], 0, 262144, wqkvT + 262144, 786432, flag);
  stageT<<<dim3(16, 16, 2), tb, 0, stream>>>(d_in[21], 0, 262144, wqkvT + 524288, 786432, flag);
  stage_wclsT<<<cdiv(128 * 512, 256), 256, 0, stream>>>(d_in[23], wclsT, flag);
  stage_bcls<<<1, 128, 0, stream>>>(d_in[24], bcls, flag);
  for (int l = 0; l < 2; ++l) {
    stage_bf16<<<2, 256, 0, stream>>>(d_in[18], (size_t)l * 512, bqkv + l * 1536,        512, flag);
    stage_bf16<<<2, 256, 0, stream>>>(d_in[20], (size_t)l * 512, bqkv + l * 1536 + 512,  512, flag);
    stage_bf16<<<2, 256, 0, stream>>>(d_in[22], (size_t)l * 512, bqkv + l * 1536 + 1024, 512, flag);
  }
  const u16 *bc = sv(4),  *gc = sv(5),  *bec = sv(6);
  const u16 *bg = sv(8),  *al = sv(9),  *ar = sv(10), *gg = sv(11), *beg = sv(12);
  const u16 *bs = sv(14), *gs = sv(15), *bes = sv(16);

  // ---- degrees + CSR (parallel 3-phase scan) ----
  hipMemsetAsync(degout, 0, (size_t)2 * R_ * N_ * sizeof(float), stream);
  deg_count<<<cdiv((long long)R_ * E_, 256), 256, 0, stream>>>(src, dst, degout, degin);
  scan_blksum<<<dim3(SCNB_, R_), 256, 0, stream>>>(degin, part);
  scan_partials<<<R_, 64, 0, stream>>>(part, csrp);
  scan_write<<<dim3(SCNB_, R_), 256, 0, stream>>>(degin, part, csrp);
  deg_fin<<<cdiv((long long)2 * R_ * N_, 256), 256, 0, stream>>>(degout);
  hipMemsetAsync(fill, 0, (size_t)R_ * N_ * sizeof(u32), stream);
  csr_scatter<<<cdiv((long long)R_ * E_, 256), 256, 0, stream>>>(dst, csrp, fill, eidx);

  const int mbBR = cdiv(N_, 256);                    // 196 -> grid 1176
  const int mbQ  = cdiv((long long)CHUNK_ * 3, 256); // 147 -> grid 882
  const dim3 gridCLS(cdiv(N_, 128), 1);              // [50000,512] @ [512,128] (legacy kernel)

  for (int l = 0; l < 2; ++l) {
    for (int r = 0; r < 3; ++r) {
      int lr = l * 3 + r;
      const int* sr = src + r * E_;
      const u32* pr = csrp + (size_t)r * (N_ + 1);
      const u32* er_idx = eidx + (size_t)r * E_;
      // fused conv|gat|skip GEMM (256^2 pipelined, 4-phase)
      gemm256<<<mbBR * 6, 512, 0, stream>>>(h, wbrT + (size_t)lr * 786432, nullptr, fbuf, N_, 1536, 6);
      // GAT edge softmax (single pass, no max shift)
      gat_el_er<<<cdiv(N_ * HEADS_, 256), 256, 0, stream>>>(fbuf + 512, 1536,
                                                            al + lr * 512, ar + lr * 512,
                                                            el, er, sx);
      gat_edge<<<cdiv((long long)E_ * HEADS_, 256), 256, 0, stream>>>(sr, dst + r * E_, el, er, alpha, sx);
      // fused CSR aggregation + 3x LN+ELU + sum -> stacked[:,r,:]
      agg3_ln<<<cdiv(N_, 4), 256, 0, stream>>>(fbuf, sr, pr, er_idx,
                                               degout + r * N_, degin + r * N_, alpha, sx,
                                               bc + lr * 512, gc + lr * 512, bec + lr * 512,
                                               bg + lr * 512, gg + lr * 512, beg + lr * 512,
                                               bs + lr * 512, gs + lr * 512, bes + lr * 512,
                                               stacked + r * 512);
    }
    // fused QKV + relation MHA (chunked; qkv aliases fbuf region)
    for (int c = 0; c < N_ / CHUNK_; ++c) {
      gemm256<<<mbQ * 6, 512, 0, stream>>>(stacked + (size_t)c * CHUNK_ * 1536,
                                           wqkvT + (size_t)l * 786432, bqkv + l * 1536,
                                           qkv, CHUNK_ * 3, 1536, 6);
      mha_fused<<<cdiv(CHUNK_ * HEADS_, 256), 256, 0, stream>>>(qkv, h + (size_t)c * CHUNK_ * 512,
                                                                CHUNK_);
    }
  }
  // classifier: MFMA GEMM into padded [N,128] + store
  gemm_mfma<<<gridCLS, 256, 0, stream>>>(h, wclsT, bcls, clsbuf, N_, 128);
  cls_store<<<cdiv((long long)N_ * NCLS_, 256), 256, 0, stream>>>(clsbuf, d_out, flag);
}

// Round 5
// 3201.990 us; speedup vs baseline: 1.0346x; 1.0346x over previous
//
#include <hip/hip_runtime.h>

#define N_     50000
#define E_     150000
#define R_     3
#define H_     512
#define HEADS_ 8
#define DH_    64
#define NCLS_  23
#define CHUNK_ 12500   // nodes per QKV/MHA chunk (N_/4)
#define SCNB_  49      // ceil(N_/1024) scan blocks per relation

typedef unsigned short u16;
typedef unsigned int   u32;
typedef __attribute__((ext_vector_type(8))) short bf16x8;
typedef __attribute__((ext_vector_type(4))) float f32x4;

__device__ __forceinline__ float bf2f(u16 u) {
  union { u32 i; float f; } v; v.i = ((u32)u) << 16; return v.f;
}
__device__ __forceinline__ u16 f2bf(float f) {
  u32 u = __float_as_uint(f);
  u += 0x7fffu + ((u >> 16) & 1u);   // round-to-nearest-even
  return (u16)(u >> 16);
}

__device__ __forceinline__ void unp8(uint4 v, float o[8]) {
  o[0] = bf2f((u16)(v.x & 0xffff)); o[1] = bf2f((u16)(v.x >> 16));
  o[2] = bf2f((u16)(v.y & 0xffff)); o[3] = bf2f((u16)(v.y >> 16));
  o[4] = bf2f((u16)(v.z & 0xffff)); o[5] = bf2f((u16)(v.z >> 16));
  o[6] = bf2f((u16)(v.w & 0xffff)); o[7] = bf2f((u16)(v.w >> 16));
}
// 8 bf16 -> 8 fp32 via one 16B load
__device__ __forceinline__ void ld8(const u16* __restrict__ p, float o[8]) {
  unp8(*(const uint4*)p, o);
}

// wave-wide sum, result broadcast to all 64 lanes
__device__ __forceinline__ float wsumb(float v) {
  #pragma unroll
  for (int o = 32; o > 0; o >>= 1) v += __shfl_down(v, o, 64);
  return __shfl(v, 0, 64);
}

// async global->LDS, 16B per lane
__device__ __forceinline__ void gl_lds16(const u16* g, u16* l) {
  __builtin_amdgcn_global_load_lds(
      (const __attribute__((address_space(1))) unsigned int*)g,
      (__attribute__((address_space(3))) unsigned int*)l, 16, 0, 0);
}

// ---------------- ws-size probe fallback ----------------
__global__ __launch_bounds__(256) void write_const(u16* __restrict__ out, int n, float v) {
  int i = blockIdx.x * blockDim.x + threadIdx.x;
  if (i < n) out[i] = f2bf(v);
}

// ---------------- dtype probe ----------------
__global__ void detect_dtype(const void* __restrict__ wc, int* __restrict__ flag) {
  __shared__ int cnt;
  if (threadIdx.x == 0) cnt = 0;
  __syncthreads();
  const u16* p = (const u16*)wc;
  int ok = 0;
  for (int i = threadIdx.x; i < 2048; i += 256) {
    float a = fabsf(bf2f(p[i]));
    if (a <= 4.0f) ok++;
  }
  atomicAdd(&cnt, ok);
  __syncthreads();
  if (threadIdx.x == 0) *flag = (cnt >= 2000) ? 1 : 0;   // 1=bf16, 0=fp32
}

// stage float tensor -> bf16 ws
__global__ __launch_bounds__(256) void stage_bf16(const void* __restrict__ in, size_t off,
                                                  u16* __restrict__ out, int n,
                                                  const int* __restrict__ flag) {
  int i = blockIdx.x * blockDim.x + threadIdx.x;
  if (i >= n) return;
  out[i] = (*flag) ? ((const u16*)in)[off + i] : f2bf(((const float*)in)[off + i]);
}

// batched staging of the 11 small [3072] parameter tensors in one dispatch
struct P11 { const void* p[11]; };
__global__ __launch_bounds__(256) void stage_p11(P11 srcs, u16* __restrict__ out,
                                                 const int* __restrict__ flag) {
  int idx = blockIdx.x * blockDim.x + threadIdx.x;
  if (idx >= 11 * 3072) return;
  int ti = idx / 3072, off = idx - ti * 3072;
  const void* in = srcs.p[ti];
  out[idx] = (*flag) ? ((const u16*)in)[off] : f2bf(((const float*)in)[off]);
}

// bqkv: out[l][q|k|v] (2x1536) from 3 tensors of [2][512]
__global__ __launch_bounds__(256) void stage_bqkv(const void* __restrict__ q,
                                                  const void* __restrict__ k,
                                                  const void* __restrict__ v,
                                                  u16* __restrict__ out,
                                                  const int* __restrict__ flag) {
  int idx = blockIdx.x * blockDim.x + threadIdx.x;
  if (idx >= 2 * 1536) return;
  int l = idx / 1536, c = idx - l * 1536;
  const void* in = (c < 512) ? q : (c < 1024) ? k : v;
  int off = l * 512 + (c & 511);
  out[idx] = (*flag) ? ((const u16*)in)[off] : f2bf(((const float*)in)[off]);
}

// stage 512x512 weight slices TRANSPOSED: out[n][k] = in[k][n]; grid.z = matrix idx
__global__ __launch_bounds__(256) void stageT(const void* __restrict__ in, size_t in_off,
                                              size_t in_mstride, u16* __restrict__ out,
                                              size_t out_mstride, const int* __restrict__ flag) {
  __shared__ u16 tile[32][33];
  const int m = blockIdx.z;
  const size_t ib = in_off + (size_t)m * in_mstride;
  const size_t ob = (size_t)m * out_mstride;
  const int kb = blockIdx.x * 32, nb = blockIdx.y * 32;
  const int tx = threadIdx.x, ty = threadIdx.y;
  const bool isbf = (*flag != 0);
  #pragma unroll
  for (int i = 0; i < 32; i += 8) {
    size_t si = ib + (size_t)(kb + ty + i) * 512 + nb + tx;
    tile[ty + i][tx] = isbf ? ((const u16*)in)[si] : f2bf(((const float*)in)[si]);
  }
  __syncthreads();
  #pragma unroll
  for (int i = 0; i < 32; i += 8)
    out[ob + (size_t)(nb + ty + i) * 512 + kb + tx] = tile[tx][ty + i];
}

// stage Wout transposed + zero-padded to [128][512]
__global__ __launch_bounds__(256) void stage_wclsT(const void* __restrict__ in,
                                                   u16* __restrict__ out,
                                                   const int* __restrict__ flag) {
  int i = blockIdx.x * blockDim.x + threadIdx.x;
  if (i >= 128 * 512) return;
  int c = i >> 9, k = i & 511;
  u16 v = 0;
  if (c < NCLS_) {
    size_t si = (size_t)k * NCLS_ + c;
    v = (*flag) ? ((const u16*)in)[si] : f2bf(((const float*)in)[si]);
  }
  out[i] = v;
}
__global__ void stage_bcls(const void* __restrict__ in, u16* __restrict__ out,
                           const int* __restrict__ flag) {
  int i = threadIdx.x;
  if (i >= 128) return;
  u16 v = 0;
  if (i < NCLS_) v = (*flag) ? ((const u16*)in)[i] : f2bf(((const float*)in)[i]);
  out[i] = v;
}

// ---------------- degrees ----------------
__global__ __launch_bounds__(256) void deg_count(const int* __restrict__ src,
                                                 const int* __restrict__ dst,
                                                 float* __restrict__ degout,
                                                 float* __restrict__ degin) {
  int idx = blockIdx.x * blockDim.x + threadIdx.x;
  if (idx >= R_ * E_) return;
  int r = idx / E_;
  atomicAdd(&degout[r * N_ + src[idx]], 1.0f);
  atomicAdd(&degin [r * N_ + dst[idx]], 1.0f);
}
__global__ __launch_bounds__(256) void deg_fin(float* __restrict__ deg) {
  int idx = blockIdx.x * blockDim.x + threadIdx.x;
  if (idx >= 2 * R_ * N_) return;
  deg[idx] = rsqrtf(fmaxf(deg[idx], 1.0f));
}

// ---------------- CSR build: parallel 3-phase exclusive scan ----------------
__global__ __launch_bounds__(256) void scan_blksum(const float* __restrict__ cnt,
                                                   u32* __restrict__ partial) {
  const int r = blockIdx.y, b = blockIdx.x;
  const int base = b * 1024;
  const float* c = cnt + (size_t)r * N_;
  const int t = threadIdx.x;
  u32 s = 0;
  #pragma unroll
  for (int k = 0; k < 4; ++k) {
    int i = base + t * 4 + k;
    if (i < N_) s += (u32)c[i];
  }
  #pragma unroll
  for (int o = 32; o > 0; o >>= 1) s += __shfl_down(s, o, 64);
  __shared__ u32 ws[4];
  if ((t & 63) == 0) ws[t >> 6] = s;
  __syncthreads();
  if (t == 0) partial[r * SCNB_ + b] = ws[0] + ws[1] + ws[2] + ws[3];
}

__global__ void scan_partials(u32* __restrict__ partial, u32* __restrict__ ptr) {
  const int r = blockIdx.x;
  u32* p = partial + r * SCNB_;
  const int l = threadIdx.x;           // 64 threads = 1 wave
  u32 v = (l < SCNB_) ? p[l] : 0u;
  u32 s = v;
  #pragma unroll
  for (int o = 1; o < 64; o <<= 1) {
    u32 n = __shfl_up(s, o, 64);
    if (l >= o) s += n;
  }
  if (l < SCNB_) p[l] = s - v;         // exclusive
  if (l == 63) ptr[(size_t)r * (N_ + 1) + N_] = s;   // grand total
}

__global__ __launch_bounds__(256) void scan_write(const float* __restrict__ cnt,
                                                  const u32* __restrict__ partial,
                                                  u32* __restrict__ ptr) {
  const int r = blockIdx.y, b = blockIdx.x;
  const int base = b * 1024;
  const float* c = cnt + (size_t)r * N_;
  u32* p = ptr + (size_t)r * (N_ + 1);
  const int t = threadIdx.x, lane = t & 63, w = t >> 6;
  u32 v[4]; u32 ts = 0;
  #pragma unroll
  for (int k = 0; k < 4; ++k) {
    int i = base + t * 4 + k;
    v[k] = (i < N_) ? (u32)c[i] : 0u;
    ts += v[k];
  }
  u32 s = ts;
  #pragma unroll
  for (int o = 1; o < 64; o <<= 1) {
    u32 n = __shfl_up(s, o, 64);
    if (lane >= o) s += n;
  }
  __shared__ u32 ws[4];
  if (lane == 63) ws[w] = s;
  __syncthreads();
  u32 off = partial[r * SCNB_ + b];
  for (int k = 0; k < w; ++k) off += ws[k];
  off += s - ts;                        // exclusive offset of this thread
  u32 run = 0;
  #pragma unroll
  for (int k = 0; k < 4; ++k) {
    int i = base + t * 4 + k;
    if (i < N_) p[i] = off + run;
    run += v[k];
  }
}

__global__ __launch_bounds__(256) void csr_scatter(const int* __restrict__ dst,
                                                   const u32* __restrict__ ptr,
                                                   u32* __restrict__ fill,
                                                   u32* __restrict__ eidx) {
  int idx = blockIdx.x * blockDim.x + threadIdx.x;
  if (idx >= R_ * E_) return;
  int r = idx / E_, e = idx - r * E_;
  int d = dst[idx];
  u32 pos = ptr[(size_t)r * (N_ + 1) + d] + atomicAdd(&fill[(size_t)r * N_ + d], 1u);
  eidx[(size_t)r * E_ + pos] = (u32)e;
}

// ---- legacy 128x128 MFMA GEMM (kept for the small classifier GEMM) ----
__global__ __launch_bounds__(256, 2) void gemm_mfma(const u16* __restrict__ A,
                                                    const u16* __restrict__ BT,
                                                    const u16* __restrict__ bias,
                                                    u16* __restrict__ C,
                                                    int M, int ldc) {
  __shared__ u16 As[128 * 32];
  __shared__ u16 Bs[128 * 32];
  const int t = threadIdx.x;
  const int w = t >> 6, l = t & 63;
  const int bm = blockIdx.x * 128, bn = blockIdx.y * 128;
  const int wm = (w & 1) * 64, wn = (w >> 1) * 64;
  const int srow = w * 16 + (l >> 2);
  const int scol = (l & 3) * 8;
  f32x4 acc[4][4] = {};

  for (int k0 = 0; k0 < 512; k0 += 32) {
    #pragma unroll
    for (int p = 0; p < 2; ++p) {
      gl_lds16(A  + (size_t)(bm + p * 64 + srow) * 512 + k0 + scol, &As[(p * 64 + w * 16) * 32]);
      gl_lds16(BT + (size_t)(bn + p * 64 + srow) * 512 + k0 + scol, &Bs[(p * 64 + w * 16) * 32]);
    }
    __syncthreads();
    bf16x8 af[4], bfr[4];
    #pragma unroll
    for (int i = 0; i < 4; ++i) {
      af[i]  = *(const bf16x8*)&As[(wm + i * 16 + (l & 15)) * 32 + (l >> 4) * 8];
      bfr[i] = *(const bf16x8*)&Bs[(wn + i * 16 + (l & 15)) * 32 + (l >> 4) * 8];
    }
    #pragma unroll
    for (int mi = 0; mi < 4; ++mi)
      #pragma unroll
      for (int ni = 0; ni < 4; ++ni)
        acc[mi][ni] = __builtin_amdgcn_mfma_f32_16x16x32_bf16(af[mi], bfr[ni], acc[mi][ni], 0, 0, 0);
    __syncthreads();
  }

  float bv[4] = {0.f, 0.f, 0.f, 0.f};
  if (bias) {
    #pragma unroll
    for (int ni = 0; ni < 4; ++ni) bv[ni] = bf2f(bias[bn + wn + ni * 16 + (l & 15)]);
  }
  const int col0 = bn + wn + (l & 15);
  #pragma unroll
  for (int mi = 0; mi < 4; ++mi) {
    #pragma unroll
    for (int reg = 0; reg < 4; ++reg) {
      int gr = bm + wm + mi * 16 + (l >> 4) * 4 + reg;
      if (gr < M) {
        size_t rb = (size_t)gr * ldc;
        #pragma unroll
        for (int ni = 0; ni < 4; ++ni)
          C[rb + col0 + ni * 16] = f2bf(acc[mi][ni][reg] + bv[ni]);
      }
    }
  }
}

// ---- 128x128 MFMA GEMM, 2-phase counted-vmcnt dbuf + LDS XOR-swizzle, 2 blocks/CU ----
// A[M,512] @ BT[Nn,512]^T -> C[M,ldc]; K=512 (8 K-tiles of 64).
// 4 waves (2x2), per-wave C = 64x64. LDS 64 KiB: 2 bufs x (A 128x64 | B 128x64) bf16
// -> 2 independent blocks/CU (two barrier domains; cross-block overlap hides drains).
// Swizzle: 16B-chunk ^= (row&7) on gload SOURCE and ds_read (involution; 2-way = free).
// Per K-tile: vmcnt(8)+bar (tile kt resident; kt+1 in flight, never drains) ->
// kk0 reads+MFMA -> kk1 reads -> lgkm(0)+bar (buffer free) -> stage kt+2 -> kk1 MFMA.
__global__ __launch_bounds__(256, 2) void gemm256(const u16* __restrict__ A,
                                                  const u16* __restrict__ BT,
                                                  const u16* __restrict__ bias,
                                                  u16* __restrict__ C,
                                                  int M, int ldc, int nb) {
  __shared__ u16 lds[32768];           // 64 KiB
  const int t = threadIdx.x;
  const int w = t >> 6, l = t & 63;
  const int wrB = (w >> 1) * 64;       // row panel (0/64)
  const int wcn = (w & 1) * 64;        // col panel (0/64)

  // XCD-bijective swizzle (m204), bn-fastest so one XCD walks a bm-panel across all bn
  const int nwg = gridDim.x;
  const int q = nwg >> 3, r = nwg & 7;
  const int xcd = blockIdx.x & 7, loc = blockIdx.x >> 3;
  const int wg = (xcd < r ? xcd * (q + 1) : r * (q + 1) + (xcd - r) * q) + loc;
  const int bn = (wg % nb) * 128;
  const int bm = (wg / nb) * 128;

  // staging: round i covers rows i*32..+32; thread t: row = i*32 + w*8 + (l>>3),
  // chunk l&7, swizzled source chunk (l&7)^(row&7) = (l&7)^(l>>3)
  const int csrc = (((l & 7) ^ (l >> 3)) << 3);         // element offset in 64-col K-tile
  const u16* Ag = A  + (size_t)(bm + w * 8 + (l >> 3)) * 512 + csrc;
  const u16* Bg = BT + (size_t)(bn + w * 8 + (l >> 3)) * 512 + csrc;

  auto stage = [&](int kt, int buf) {
    const size_t ko = (size_t)kt * 64;
    #pragma unroll
    for (int i = 0; i < 4; ++i)
      gl_lds16(Ag + (size_t)(i * 32) * 512 + ko, &lds[buf * 16384 + i * 2048 + w * 512]);
    #pragma unroll
    for (int i = 0; i < 4; ++i)
      gl_lds16(Bg + (size_t)(i * 32) * 512 + ko, &lds[buf * 16384 + 8192 + i * 2048 + w * 512]);
  };

  // fragment-read offsets (u16 units), with matching XOR swizzle
  const int rl = l & 15, rh = l >> 4;                   // rh in 0..3
  const int key = l & 7;                                // row & 7 (wrB, mt*16 are mult of 8)
  const int c0 = ((rh)     ^ key) << 3;                 // kk=0 chunk
  const int c1 = ((4 + rh) ^ key) << 3;                 // kk=1 chunk

  f32x4 acc[4][4] = {};

  stage(0, 0);
  stage(1, 1);

  #pragma unroll
  for (int kt = 0; kt < 8; ++kt) {
    // tile kt fully resident after this wait (8 loads/tile/thread, 1 tile ahead in flight)
    if (kt == 7) asm volatile("s_waitcnt vmcnt(0)" ::: "memory");
    else         asm volatile("s_waitcnt vmcnt(8)" ::: "memory");
    __builtin_amdgcn_s_barrier();
    asm volatile("" ::: "memory");

    const u16* Ab = &lds[(kt & 1) * 16384];
    const u16* Bb = Ab + 8192;

    bf16x8 a0[4], b0[4];
    #pragma unroll
    for (int mt = 0; mt < 4; ++mt) a0[mt] = *(const bf16x8*)&Ab[(wrB + mt * 16 + rl) * 64 + c0];
    #pragma unroll
    for (int nt = 0; nt < 4; ++nt) b0[nt] = *(const bf16x8*)&Bb[(wcn + nt * 16 + rl) * 64 + c0];

    #pragma unroll
    for (int mt = 0; mt < 4; ++mt)
      #pragma unroll
      for (int nt = 0; nt < 4; ++nt)
        acc[mt][nt] = __builtin_amdgcn_mfma_f32_16x16x32_bf16(a0[mt], b0[nt], acc[mt][nt], 0, 0, 0);

    bf16x8 a1[4], b1[4];
    #pragma unroll
    for (int mt = 0; mt < 4; ++mt) a1[mt] = *(const bf16x8*)&Ab[(wrB + mt * 16 + rl) * 64 + c1];
    #pragma unroll
    for (int nt = 0; nt < 4; ++nt) b1[nt] = *(const bf16x8*)&Bb[(wcn + nt * 16 + rl) * 64 + c1];

    // all reads of buf[kt&1] done -> safe for everyone to overwrite it
    asm volatile("s_waitcnt lgkmcnt(0)" ::: "memory");
    __builtin_amdgcn_s_barrier();
    asm volatile("" ::: "memory");

    if (kt < 6) stage(kt + 2, kt & 1);

    #pragma unroll
    for (int mt = 0; mt < 4; ++mt)
      #pragma unroll
      for (int nt = 0; nt < 4; ++nt)
        acc[mt][nt] = __builtin_amdgcn_mfma_f32_16x16x32_bf16(a1[mt], b1[nt], acc[mt][nt], 0, 0, 0);
  }

  // ---- vectorized epilogue: per-wave 4 KiB LDS f32 transpose -> 8B stores ----
  // Safe: all ds_reads drained at kt=7 (lgkm(0)+bar), all gloads drained (vmcnt(0));
  // per-wave private regions.
  float bv[4] = {0.f, 0.f, 0.f, 0.f};
  if (bias) {
    #pragma unroll
    for (int nt = 0; nt < 4; ++nt) bv[nt] = bf2f(bias[bn + wcn + nt * 16 + rl]);
  }
  float* F = (float*)&lds[(size_t)w * 2048];   // [16][64] f32 per wave
  #pragma unroll
  for (int mt = 0; mt < 4; ++mt) {
    #pragma unroll
    for (int nt = 0; nt < 4; ++nt) {
      const int colw = (nt * 16 + rl) ^ ((rh & 1) << 4);
      #pragma unroll
      for (int reg = 0; reg < 4; ++reg)
        F[(rh * 4 + reg) * 64 + colw] = acc[mt][nt][reg] + bv[nt];
    }
    #pragma unroll
    for (int j = 0; j < 4; ++j) {
      const int row = rh + 4 * j;
      const int chunk = rl ^ ((j & 1) << 2);
      f32x4 vv = *(const f32x4*)&F[row * 64 + chunk * 4];
      u32 lo = (u32)f2bf(vv[0]) | ((u32)f2bf(vv[1]) << 16);
      u32 hi = (u32)f2bf(vv[2]) | ((u32)f2bf(vv[3]) << 16);
      const int gr = bm + wrB + mt * 16 + row;
      if (gr < M) {
        uint2 pk; pk.x = lo; pk.y = hi;
        *(uint2*)&C[(size_t)gr * ldc + bn + wcn + rl * 4] = pk;
      }
    }
  }
}

// ---- fused epilogue: wave-per-node, 16B loads, 1-deep edge prefetch ----
__global__ __launch_bounds__(256) void agg3_ln(const u16* __restrict__ fb,
                                               const int* __restrict__ src_r,
                                               const u32* __restrict__ ptr,
                                               const u32* __restrict__ eidx,
                                               const float* __restrict__ dors,
                                               const float* __restrict__ dirs,
                                               const float* __restrict__ alpha,
                                               const float* __restrict__ sx,
                                               const u16* __restrict__ bc,  const u16* __restrict__ gc,  const u16* __restrict__ bec,
                                               const u16* __restrict__ bg,  const u16* __restrict__ gg,  const u16* __restrict__ beg,
                                               const u16* __restrict__ bs,  const u16* __restrict__ gs,  const u16* __restrict__ bes,
                                               u16* __restrict__ out) {
  const int l  = threadIdx.x & 63;
  const int d  = blockIdx.x * 4 + (threadIdx.x >> 6);
  const int c0 = l * 8;          // 8 cols, within one head (head = l>>3)
  const int hd = l >> 3;
  float sxv = sx[d * 8 + hd];
  float inv = (sxv > 0.f) ? 1.0f / sxv : 1.0f;
  const float dird = dirs[d];

  float cv[8] = {0,0,0,0,0,0,0,0}, gv[8] = {0,0,0,0,0,0,0,0};
  const u32 p0 = ptr[d], p1 = ptr[d + 1];
  if (p1 > p0) {
    // software-pipelined edge loop (FP accumulation order identical to serial)
    u32 e = eidx[p0];
    int s = src_r[e];
    float sc = dors[s] * dird;
    float wg = alpha[e * 8 + hd] * inv;
    const u16* xr = fb + (size_t)s * 1536 + c0;
    uint4 va = *(const uint4*)xr;
    uint4 vb = *(const uint4*)(xr + 512);
    for (u32 i = p0 + 1; i < p1; ++i) {
      u32 e2 = eidx[i];
      int s2 = src_r[e2];
      float sc2 = dors[s2] * dird;
      float wg2 = alpha[e2 * 8 + hd] * inv;
      const u16* xr2 = fb + (size_t)s2 * 1536 + c0;
      uint4 na = *(const uint4*)xr2;
      uint4 nb4 = *(const uint4*)(xr2 + 512);
      float a[8], b[8];
      unp8(va, a); unp8(vb, b);
      #pragma unroll
      for (int j = 0; j < 8; ++j) {
        cv[j] = fmaf(a[j], sc, cv[j]);
        gv[j] = fmaf(b[j], wg, gv[j]);
      }
      va = na; vb = nb4; sc = sc2; wg = wg2;
    }
    float a[8], b[8];
    unp8(va, a); unp8(vb, b);
    #pragma unroll
    for (int j = 0; j < 8; ++j) {
      cv[j] = fmaf(a[j], sc, cv[j]);
      gv[j] = fmaf(b[j], wg, gv[j]);
    }
  }
  float sv[8];
  ld8(fb + (size_t)d * 1536 + 1024 + c0, sv);
  float t8[8];
  ld8(bc + c0, t8);
  #pragma unroll
  for (int j = 0; j < 8; ++j) cv[j] += t8[j];
  ld8(bg + c0, t8);
  #pragma unroll
  for (int j = 0; j < 8; ++j) gv[j] += t8[j];
  ld8(bs + c0, t8);
  #pragma unroll
  for (int j = 0; j < 8; ++j) sv[j] += t8[j];

  float s;
  s = 0.f;
  #pragma unroll
  for (int j = 0; j < 8; ++j) s += cv[j];
  float mc = wsumb(s) * (1.0f / 512.0f);
  s = 0.f;
  #pragma unroll
  for (int j = 0; j < 8; ++j) { cv[j] -= mc; s += cv[j] * cv[j]; }
  float rc = rsqrtf(wsumb(s) * (1.0f / 512.0f) + 1e-12f);

  s = 0.f;
  #pragma unroll
  for (int j = 0; j < 8; ++j) s += gv[j];
  float mg = wsumb(s) * (1.0f / 512.0f);
  s = 0.f;
  #pragma unroll
  for (int j = 0; j < 8; ++j) { gv[j] -= mg; s += gv[j] * gv[j]; }
  float rg = rsqrtf(wsumb(s) * (1.0f / 512.0f) + 1e-12f);

  s = 0.f;
  #pragma unroll
  for (int j = 0; j < 8; ++j) s += sv[j];
  float ms = wsumb(s) * (1.0f / 512.0f);
  s = 0.f;
  #pragma unroll
  for (int j = 0; j < 8; ++j) { sv[j] -= ms; s += sv[j] * sv[j]; }
  float rs = rsqrtf(wsumb(s) * (1.0f / 512.0f) + 1e-12f);

  float o8[8];
  float ga[8], be8[8];
  ld8(gc + c0, ga); ld8(bec + c0, be8);
  #pragma unroll
  for (int j = 0; j < 8; ++j) {
    float y = ga[j] * cv[j] * rc + be8[j];
    o8[j] = (y > 0.f) ? y : expm1f(y);
  }
  ld8(gg + c0, ga); ld8(beg + c0, be8);
  #pragma unroll
  for (int j = 0; j < 8; ++j) {
    float y = ga[j] * gv[j] * rg + be8[j];
    o8[j] += (y > 0.f) ? y : expm1f(y);
  }
  ld8(gs + c0, ga); ld8(bes + c0, be8);
  #pragma unroll
  for (int j = 0; j < 8; ++j) {
    float y = ga[j] * sv[j] * rs + be8[j];
    o8[j] += (y > 0.f) ? y : expm1f(y);
  }
  uint4 o;
  u32 wpk[4];
  #pragma unroll
  for (int j = 0; j < 4; ++j)
    wpk[j] = (u32)f2bf(o8[2 * j]) | ((u32)f2bf(o8[2 * j + 1]) << 16);
  o.x = wpk[0]; o.y = wpk[1]; o.z = wpk[2]; o.w = wpk[3];
  *(uint4*)(out + (size_t)d * 1536 + c0) = o;
}

// ---------------- GAT edge softmax ----------------
__global__ __launch_bounds__(256) void gat_el_er(const u16* __restrict__ f, int fstride,
                                                 const u16* __restrict__ al,
                                                 const u16* __restrict__ ar,
                                                 float* __restrict__ el,
                                                 float* __restrict__ er,
                                                 float* __restrict__ sx) {
  int idx = blockIdx.x * blockDim.x + threadIdx.x;
  if (idx >= N_ * HEADS_) return;
  int n = idx >> 3, hd = idx & 7;
  const u16* fr = f + (size_t)n * fstride + hd * 64;
  const u16* alr = al + hd * 64;
  const u16* arr = ar + hd * 64;
  float a = 0.f, b = 0.f;
  for (int d0 = 0; d0 < 64; d0 += 8) {
    float fv[8], av[8], bv[8];
    ld8(fr + d0, fv); ld8(alr + d0, av); ld8(arr + d0, bv);
    #pragma unroll
    for (int j = 0; j < 8; ++j) {
      a = fmaf(fv[j], av[j], a);
      b = fmaf(fv[j], bv[j], b);
    }
  }
  el[idx] = a; er[idx] = b;
  sx[idx] = 0.f;
}

__global__ __launch_bounds__(256) void gat_edge(const int* __restrict__ src,
                                                const int* __restrict__ dst,
                                                const float* __restrict__ el,
                                                const float* __restrict__ er,
                                                float* __restrict__ alpha,
                                                float* __restrict__ sx) {
  int idx = blockIdx.x * blockDim.x + threadIdx.x;
  if (idx >= E_ * HEADS_) return;
  int e = idx >> 3, hd = idx & 7;
  int s = src[e], d = dst[e];
  float v = el[s * 8 + hd] + er[d * 8 + hd];
  v = (v > 0.f) ? v : 0.2f * v;
  float ex = expf(fminf(v, 60.0f));
  alpha[idx] = ex;
  atomicAdd(&sx[d * 8 + hd], ex);
}

// ---------------- fused relation MHA over QKV[row=(n*3+r)][q|k|v 512 each] ----------------
__global__ __launch_bounds__(256) void mha_fused(const u16* __restrict__ QKV,
                                                 u16* __restrict__ hout, int C) {
  int idx = blockIdx.x * blockDim.x + threadIdx.x;
  if (idx >= C * HEADS_) return;
  int n = idx >> 3, hd = idx & 7;
  const u16* b0 = QKV + (size_t)n * 4608 + hd * 64;
  float sc[9] = {0.f,0.f,0.f,0.f,0.f,0.f,0.f,0.f,0.f};
  for (int d0 = 0; d0 < 64; d0 += 8) {
    float q0[8], q1[8], q2[8], k0[8], k1[8], k2[8];
    ld8(b0 + d0, q0);        ld8(b0 + 1536 + d0, q1); ld8(b0 + 3072 + d0, q2);
    ld8(b0 + 512 + d0, k0);  ld8(b0 + 2048 + d0, k1); ld8(b0 + 3584 + d0, k2);
    #pragma unroll
    for (int j = 0; j < 8; ++j) {
      sc[0] = fmaf(q0[j], k0[j], sc[0]); sc[1] = fmaf(q0[j], k1[j], sc[1]); sc[2] = fmaf(q0[j], k2[j], sc[2]);
      sc[3] = fmaf(q1[j], k0[j], sc[3]); sc[4] = fmaf(q1[j], k1[j], sc[4]); sc[5] = fmaf(q1[j], k2[j], sc[5]);
      sc[6] = fmaf(q2[j], k0[j], sc[6]); sc[7] = fmaf(q2[j], k1[j], sc[7]); sc[8] = fmaf(q2[j], k2[j], sc[8]);
    }
  }
  float wp0 = 0.f, wp1 = 0.f, wp2 = 0.f;
  #pragma unroll
  for (int r = 0; r < 3; ++r) {
    float a = sc[r * 3 + 0] * 0.125f;
    float b = sc[r * 3 + 1] * 0.125f;
    float c = sc[r * 3 + 2] * 0.125f;
    float m = fmaxf(a, fmaxf(b, c));
    float ea = expf(a - m), eb = expf(b - m), ec = expf(c - m);
    float inv = 1.0f / (ea + eb + ec);
    wp0 += ea * inv; wp1 += eb * inv; wp2 += ec * inv;
  }
  wp0 *= (1.0f / 3.0f); wp1 *= (1.0f / 3.0f); wp2 *= (1.0f / 3.0f);
  u16* ho = hout + (size_t)n * 512 + hd * 64;
  for (int d0 = 0; d0 < 64; d0 += 8) {
    float v0[8], v1[8], v2[8];
    ld8(b0 + 1024 + d0, v0); ld8(b0 + 2560 + d0, v1); ld8(b0 + 4096 + d0, v2);
    uint4 o;
    u32 w[4];
    #pragma unroll
    for (int j = 0; j < 4; ++j) {
      u16 lo = f2bf(wp0 * v0[2*j]   + wp1 * v1[2*j]   + wp2 * v2[2*j]);
      u16 hi = f2bf(wp0 * v0[2*j+1] + wp1 * v1[2*j+1] + wp2 * v2[2*j+1]);
      w[j] = (u32)lo | ((u32)hi << 16);
    }
    o.x = w[0]; o.y = w[1]; o.z = w[2]; o.w = w[3];
    *(uint4*)(ho + d0) = o;
  }
}

// ---------------- classifier store: clsbuf[N,128] -> d_out[N,23] ----------------
__global__ __launch_bounds__(256) void cls_store(const u16* __restrict__ clsbuf,
                                                 void* __restrict__ out,
                                                 const int* __restrict__ flag) {
  int idx = blockIdx.x * blockDim.x + threadIdx.x;
  if (idx >= N_ * NCLS_) return;
  int n = idx / NCLS_, c = idx - n * NCLS_;
  float s = bf2f(clsbuf[(size_t)n * 128 + c]);
  if (!(s == s)) s = 12345.0f;   // NaN sentinel
  if (*flag) ((u16*)out)[idx] = f2bf(s);
  else       ((float*)out)[idx] = s;
}

static inline int cdiv(long long a, long long b) { return (int)((a + b - 1) / b); }

extern "C" void kernel_launch(void* const* d_in, const int* in_sizes, int n_in,
                              void* d_out, int out_size, void* d_ws, size_t ws_size,
                              hipStream_t stream) {
  // ---- workspace plan (bytes, 256-aligned) ----
  size_t off = 0;
  auto take = [&](size_t bytes) { size_t o = off; off += (bytes + 255) & ~(size_t)255; return o; };
  const size_t o_flag    = take(256);
  const size_t o_stacked = take((size_t)N_ * 1536 * 2);            // 153.6 MB bf16
  const size_t o_h       = take((size_t)N_ * 512 * 2);             //  51.2 MB (feature alias)
  const size_t o_trans   = take((size_t)N_ * 1536 * 2);            // 153.6 MB fbuf / qkv / clsbuf
  const size_t o_el    = take((size_t)N_ * HEADS_ * 4);
  const size_t o_er    = take((size_t)N_ * HEADS_ * 4);
  const size_t o_sx    = take((size_t)N_ * HEADS_ * 4);
  const size_t o_alpha = take((size_t)E_ * HEADS_ * 4);
  const size_t o_deg   = take((size_t)2 * R_ * N_ * 4);
  const size_t o_csrp  = take((size_t)R_ * (N_ + 1) * 4);
  const size_t o_eidx  = take((size_t)R_ * E_ * 4);
  const size_t o_fill  = take((size_t)R_ * N_ * 4);
  const size_t o_part  = take((size_t)R_ * SCNB_ * 4);             // scan partials
  const size_t o_wts   = take((size_t)6500000 * 2);                // staged bf16 weights
  const size_t need = off;

  if (ws_size < need) {
    write_const<<<cdiv(out_size, 256), 256, 0, stream>>>((u16*)d_out, out_size,
                                                         (float)(ws_size >> 20));
    return;
  }

  char* base = (char*)d_ws;
  int*   flag    = (int*)(base + o_flag);
  u16*   stacked = (u16*)(base + o_stacked);
  u16*   h       = (u16*)(base + o_h);
  u16*   fbuf    = (u16*)(base + o_trans);     // [N,1536] fused branch GEMM out
  u16*   qkv     = (u16*)(base + o_trans);     // [CHUNK*3,1536] (aliases, disjoint in time)
  u16*   clsbuf  = (u16*)(base + o_trans);     // [N,128]       (aliases, disjoint in time)
  float* el    = (float*)(base + o_el);
  float* er    = (float*)(base + o_er);
  float* sx    = (float*)(base + o_sx);
  float* alpha = (float*)(base + o_alpha);
  float* degout = (float*)(base + o_deg);
  float* degin  = degout + (size_t)R_ * N_;
  u32*   csrp  = (u32*)(base + o_csrp);
  u32*   eidx  = (u32*)(base + o_eidx);
  u32*   fill  = (u32*)(base + o_fill);
  u32*   part  = (u32*)(base + o_part);

  const int* src = (const int*)d_in[1];
  const int* dst = (const int*)d_in[2];

  // ---- dtype probe ----
  detect_dtype<<<1, 256, 0, stream>>>(d_in[3], flag);

  // ---- staged weight layout (elements within o_wts) ----
  u16* wts   = (u16*)(base + o_wts);
  u16* wbrT  = wts;                              // [6][1536n][512k]: Wc | Wg | Wsk rows
  u16* wqkvT = wbrT + 6 * 786432;                // [2][1536n][512k] (q|k|v)
  u16* bqkv  = wqkvT + 2 * 786432;               // [2][1536]
  u16* wclsT = bqkv + 2 * 1536;                  // [128][512]
  u16* bcls  = wclsT + 128 * 512;                // [128]
  u16* prm   = bcls + 128;                       // 11 x [3072] small params

  stage_bf16<<<cdiv(N_ * 512, 256), 256, 0, stream>>>(d_in[0], 0, h, N_ * 512, flag);
  dim3 tb(32, 8);
  stageT<<<dim3(16, 16, 6), tb, 0, stream>>>(d_in[3],  0, 262144, wbrT,          786432, flag);
  stageT<<<dim3(16, 16, 6), tb, 0, stream>>>(d_in[7],  0, 262144, wbrT + 262144, 786432, flag);
  stageT<<<dim3(16, 16, 6), tb, 0, stream>>>(d_in[13], 0, 262144, wbrT + 524288, 786432, flag);
  stageT<<<dim3(16, 16, 2), tb, 0, stream>>>(d_in[17], 0, 262144, wqkvT,          786432, flag);
  stageT<<<dim3(16, 16, 2), tb, 0, stream>>>(d_in[19], 0, 262144, wqkvT + 262144, 786432, flag);
  stageT<<<dim3(16, 16, 2), tb, 0, stream>>>(d_in[21], 0, 262144, wqkvT + 524288, 786432, flag);
  stage_wclsT<<<cdiv(128 * 512, 256), 256, 0, stream>>>(d_in[23], wclsT, flag);
  stage_bcls<<<1, 128, 0, stream>>>(d_in[24], bcls, flag);
  stage_bqkv<<<cdiv(2 * 1536, 256), 256, 0, stream>>>(d_in[18], d_in[20], d_in[22], bqkv, flag);

  P11 p11;
  p11.p[0] = d_in[4];  p11.p[1] = d_in[5];  p11.p[2]  = d_in[6];
  p11.p[3] = d_in[8];  p11.p[4] = d_in[9];  p11.p[5]  = d_in[10];
  p11.p[6] = d_in[11]; p11.p[7] = d_in[12]; p11.p[8]  = d_in[14];
  p11.p[9] = d_in[15]; p11.p[10] = d_in[16];
  stage_p11<<<cdiv(11 * 3072, 256), 256, 0, stream>>>(p11, prm, flag);
  const u16 *bc  = prm,            *gc  = prm + 3072,  *bec = prm + 2 * 3072;
  const u16 *bg  = prm + 3 * 3072, *al  = prm + 4 * 3072, *ar = prm + 5 * 3072;
  const u16 *gg  = prm + 6 * 3072, *beg = prm + 7 * 3072;
  const u16 *bs  = prm + 8 * 3072, *gs  = prm + 9 * 3072, *bes = prm + 10 * 3072;

  // ---- degrees + CSR (parallel 3-phase scan) ----
  hipMemsetAsync(degout, 0, (size_t)2 * R_ * N_ * sizeof(float), stream);
  deg_count<<<cdiv((long long)R_ * E_, 256), 256, 0, stream>>>(src, dst, degout, degin);
  scan_blksum<<<dim3(SCNB_, R_), 256, 0, stream>>>(degin, part);
  scan_partials<<<R_, 64, 0, stream>>>(part, csrp);
  scan_write<<<dim3(SCNB_, R_), 256, 0, stream>>>(degin, part, csrp);
  deg_fin<<<cdiv((long long)2 * R_ * N_, 256), 256, 0, stream>>>(degout);
  hipMemsetAsync(fill, 0, (size_t)R_ * N_ * sizeof(u32), stream);
  csr_scatter<<<cdiv((long long)R_ * E_, 256), 256, 0, stream>>>(dst, csrp, fill, eidx);

  const int mbBR = cdiv(N_, 128);                    // 391 row-blocks, nb=12 -> 4692 wgs
  const int mbQ  = cdiv((long long)CHUNK_ * 3, 128); // 293 -> 3516 wgs
  const dim3 gridCLS(cdiv(N_, 128), 1);              // [50000,512] @ [512,128] (legacy kernel)

  for (int l = 0; l < 2; ++l) {
    for (int r = 0; r < 3; ++r) {
      int lr = l * 3 + r;
      const int* sr = src + r * E_;
      const u32* pr = csrp + (size_t)r * (N_ + 1);
      const u32* er_idx = eidx + (size_t)r * E_;
      // fused conv|gat|skip GEMM (128^2, 2 blocks/CU, counted vmcnt)
      gemm256<<<mbBR * 12, 256, 0, stream>>>(h, wbrT + (size_t)lr * 786432, nullptr, fbuf, N_, 1536, 12);
      // GAT edge softmax (single pass, no max shift)
      gat_el_er<<<cdiv(N_ * HEADS_, 256), 256, 0, stream>>>(fbuf + 512, 1536,
                                                            al + lr * 512, ar + lr * 512,
                                                            el, er, sx);
      gat_edge<<<cdiv((long long)E_ * HEADS_, 256), 256, 0, stream>>>(sr, dst + r * E_, el, er, alpha, sx);
      // fused CSR aggregation + 3x LN+ELU + sum -> stacked[:,r,:]
      agg3_ln<<<cdiv(N_, 4), 256, 0, stream>>>(fbuf, sr, pr, er_idx,
                                               degout + r * N_, degin + r * N_, alpha, sx,
                                               bc + lr * 512, gc + lr * 512, bec + lr * 512,
                                               bg + lr * 512, gg + lr * 512, beg + lr * 512,
                                               bs + lr * 512, gs + lr * 512, bes + lr * 512,
                                               stacked + r * 512);
    }
    // fused QKV + relation MHA (chunked; qkv aliases fbuf region)
    for (int c = 0; c < N_ / CHUNK_; ++c) {
      gemm256<<<mbQ * 12, 256, 0, stream>>>(stacked + (size_t)c * CHUNK_ * 1536,
                                            wqkvT + (size_t)l * 786432, bqkv + l * 1536,
                                            qkv, CHUNK_ * 3, 1536, 12);
      mha_fused<<<cdiv(CHUNK_ * HEADS_, 256), 256, 0, stream>>>(qkv, h + (size_t)c * CHUNK_ * 512,
                                                                CHUNK_);
    }
  }
  // classifier: MFMA GEMM into padded [N,128] + store
  gemm_mfma<<<gridCLS, 256, 0, stream>>>(h, wclsT, bcls, clsbuf, N_, 128);
  cls_store<<<cdiv((long long)N_ * NCLS_, 256), 256, 0, stream>>>(clsbuf, d_out, flag);
}

// Round 6
// 3190.773 us; speedup vs baseline: 1.0382x; 1.0035x over previous
//
#include <hip/hip_runtime.h>

#define N_     50000
#define E_     150000
#define R_     3
#define H_     512
#define HEADS_ 8
#define DH_    64
#define NCLS_  23
#define CHUNK_ 12500   // nodes per QKV/MHA chunk (N_/4)
#define SCNB_  49      // ceil(N_/1024) scan blocks per relation

typedef unsigned short u16;
typedef unsigned int   u32;
typedef __attribute__((ext_vector_type(8))) short bf16x8;
typedef __attribute__((ext_vector_type(4))) float f32x4;

__device__ __forceinline__ float bf2f(u16 u) {
  union { u32 i; float f; } v; v.i = ((u32)u) << 16; return v.f;
}
__device__ __forceinline__ u16 f2bf(float f) {
  u32 u = __float_as_uint(f);
  u += 0x7fffu + ((u >> 16) & 1u);   // round-to-nearest-even
  return (u16)(u >> 16);
}

__device__ __forceinline__ void unp8(uint4 v, float o[8]) {
  o[0] = bf2f((u16)(v.x & 0xffff)); o[1] = bf2f((u16)(v.x >> 16));
  o[2] = bf2f((u16)(v.y & 0xffff)); o[3] = bf2f((u16)(v.y >> 16));
  o[4] = bf2f((u16)(v.z & 0xffff)); o[5] = bf2f((u16)(v.z >> 16));
  o[6] = bf2f((u16)(v.w & 0xffff)); o[7] = bf2f((u16)(v.w >> 16));
}
// 8 bf16 -> 8 fp32 via one 16B load
__device__ __forceinline__ void ld8(const u16* __restrict__ p, float o[8]) {
  unp8(*(const uint4*)p, o);
}

// wave-wide sum, result broadcast to all 64 lanes
__device__ __forceinline__ float wsumb(float v) {
  #pragma unroll
  for (int o = 32; o > 0; o >>= 1) v += __shfl_down(v, o, 64);
  return __shfl(v, 0, 64);
}

// async global->LDS, 16B per lane
__device__ __forceinline__ void gl_lds16(const u16* g, u16* l) {
  __builtin_amdgcn_global_load_lds(
      (const __attribute__((address_space(1))) unsigned int*)g,
      (__attribute__((address_space(3))) unsigned int*)l, 16, 0, 0);
}

// ---------------- ws-size probe fallback ----------------
__global__ __launch_bounds__(256) void write_const(u16* __restrict__ out, int n, float v) {
  int i = blockIdx.x * blockDim.x + threadIdx.x;
  if (i < n) out[i] = f2bf(v);
}

// ---------------- dtype probe ----------------
__global__ void detect_dtype(const void* __restrict__ wc, int* __restrict__ flag) {
  __shared__ int cnt;
  if (threadIdx.x == 0) cnt = 0;
  __syncthreads();
  const u16* p = (const u16*)wc;
  int ok = 0;
  for (int i = threadIdx.x; i < 2048; i += 256) {
    float a = fabsf(bf2f(p[i]));
    if (a <= 4.0f) ok++;
  }
  atomicAdd(&cnt, ok);
  __syncthreads();
  if (threadIdx.x == 0) *flag = (cnt >= 2000) ? 1 : 0;   // 1=bf16, 0=fp32
}

// stage float tensor -> bf16 ws
__global__ __launch_bounds__(256) void stage_bf16(const void* __restrict__ in, size_t off,
                                                  u16* __restrict__ out, int n,
                                                  const int* __restrict__ flag) {
  int i = blockIdx.x * blockDim.x + threadIdx.x;
  if (i >= n) return;
  out[i] = (*flag) ? ((const u16*)in)[off + i] : f2bf(((const float*)in)[off + i]);
}

// batched staging of the 11 small [3072] parameter tensors in one dispatch
struct P11 { const void* p[11]; };
__global__ __launch_bounds__(256) void stage_p11(P11 srcs, u16* __restrict__ out,
                                                 const int* __restrict__ flag) {
  int idx = blockIdx.x * blockDim.x + threadIdx.x;
  if (idx >= 11 * 3072) return;
  int ti = idx / 3072, off = idx - ti * 3072;
  const void* in = srcs.p[ti];
  out[idx] = (*flag) ? ((const u16*)in)[off] : f2bf(((const float*)in)[off]);
}

// bqkv: out[l][q|k|v] (2x1536) from 3 tensors of [2][512]
__global__ __launch_bounds__(256) void stage_bqkv(const void* __restrict__ q,
                                                  const void* __restrict__ k,
                                                  const void* __restrict__ v,
                                                  u16* __restrict__ out,
                                                  const int* __restrict__ flag) {
  int idx = blockIdx.x * blockDim.x + threadIdx.x;
  if (idx >= 2 * 1536) return;
  int l = idx / 1536, c = idx - l * 1536;
  const void* in = (c < 512) ? q : (c < 1024) ? k : v;
  int off = l * 512 + (c & 511);
  out[idx] = (*flag) ? ((const u16*)in)[off] : f2bf(((const float*)in)[off]);
}

// stage 512x512 weight slices TRANSPOSED: out[n][k] = in[k][n]; grid.z = matrix idx
__global__ __launch_bounds__(256) void stageT(const void* __restrict__ in, size_t in_off,
                                              size_t in_mstride, u16* __restrict__ out,
                                              size_t out_mstride, const int* __restrict__ flag) {
  __shared__ u16 tile[32][33];
  const int m = blockIdx.z;
  const size_t ib = in_off + (size_t)m * in_mstride;
  const size_t ob = (size_t)m * out_mstride;
  const int kb = blockIdx.x * 32, nb = blockIdx.y * 32;
  const int tx = threadIdx.x, ty = threadIdx.y;
  const bool isbf = (*flag != 0);
  #pragma unroll
  for (int i = 0; i < 32; i += 8) {
    size_t si = ib + (size_t)(kb + ty + i) * 512 + nb + tx;
    tile[ty + i][tx] = isbf ? ((const u16*)in)[si] : f2bf(((const float*)in)[si]);
  }
  __syncthreads();
  #pragma unroll
  for (int i = 0; i < 32; i += 8)
    out[ob + (size_t)(nb + ty + i) * 512 + kb + tx] = tile[tx][ty + i];
}

// stage Wout transposed + zero-padded to [128][512]
__global__ __launch_bounds__(256) void stage_wclsT(const void* __restrict__ in,
                                                   u16* __restrict__ out,
                                                   const int* __restrict__ flag) {
  int i = blockIdx.x * blockDim.x + threadIdx.x;
  if (i >= 128 * 512) return;
  int c = i >> 9, k = i & 511;
  u16 v = 0;
  if (c < NCLS_) {
    size_t si = (size_t)k * NCLS_ + c;
    v = (*flag) ? ((const u16*)in)[si] : f2bf(((const float*)in)[si]);
  }
  out[i] = v;
}
__global__ void stage_bcls(const void* __restrict__ in, u16* __restrict__ out,
                           const int* __restrict__ flag) {
  int i = threadIdx.x;
  if (i >= 128) return;
  u16 v = 0;
  if (i < NCLS_) v = (*flag) ? ((const u16*)in)[i] : f2bf(((const float*)in)[i]);
  out[i] = v;
}

// ---------------- degrees ----------------
__global__ __launch_bounds__(256) void deg_count(const int* __restrict__ src,
                                                 const int* __restrict__ dst,
                                                 float* __restrict__ degout,
                                                 float* __restrict__ degin) {
  int idx = blockIdx.x * blockDim.x + threadIdx.x;
  if (idx >= R_ * E_) return;
  int r = idx / E_;
  atomicAdd(&degout[r * N_ + src[idx]], 1.0f);
  atomicAdd(&degin [r * N_ + dst[idx]], 1.0f);
}
__global__ __launch_bounds__(256) void deg_fin(float* __restrict__ deg) {
  int idx = blockIdx.x * blockDim.x + threadIdx.x;
  if (idx >= 2 * R_ * N_) return;
  deg[idx] = rsqrtf(fmaxf(deg[idx], 1.0f));
}

// ---------------- CSR build: parallel 3-phase exclusive scan ----------------
__global__ __launch_bounds__(256) void scan_blksum(const float* __restrict__ cnt,
                                                   u32* __restrict__ partial) {
  const int r = blockIdx.y, b = blockIdx.x;
  const int base = b * 1024;
  const float* c = cnt + (size_t)r * N_;
  const int t = threadIdx.x;
  u32 s = 0;
  #pragma unroll
  for (int k = 0; k < 4; ++k) {
    int i = base + t * 4 + k;
    if (i < N_) s += (u32)c[i];
  }
  #pragma unroll
  for (int o = 32; o > 0; o >>= 1) s += __shfl_down(s, o, 64);
  __shared__ u32 ws[4];
  if ((t & 63) == 0) ws[t >> 6] = s;
  __syncthreads();
  if (t == 0) partial[r * SCNB_ + b] = ws[0] + ws[1] + ws[2] + ws[3];
}

__global__ void scan_partials(u32* __restrict__ partial, u32* __restrict__ ptr) {
  const int r = blockIdx.x;
  u32* p = partial + r * SCNB_;
  const int l = threadIdx.x;           // 64 threads = 1 wave
  u32 v = (l < SCNB_) ? p[l] : 0u;
  u32 s = v;
  #pragma unroll
  for (int o = 1; o < 64; o <<= 1) {
    u32 n = __shfl_up(s, o, 64);
    if (l >= o) s += n;
  }
  if (l < SCNB_) p[l] = s - v;         // exclusive
  if (l == 63) ptr[(size_t)r * (N_ + 1) + N_] = s;   // grand total
}

__global__ __launch_bounds__(256) void scan_write(const float* __restrict__ cnt,
                                                  const u32* __restrict__ partial,
                                                  u32* __restrict__ ptr) {
  const int r = blockIdx.y, b = blockIdx.x;
  const int base = b * 1024;
  const float* c = cnt + (size_t)r * N_;
  u32* p = ptr + (size_t)r * (N_ + 1);
  const int t = threadIdx.x, lane = t & 63, w = t >> 6;
  u32 v[4]; u32 ts = 0;
  #pragma unroll
  for (int k = 0; k < 4; ++k) {
    int i = base + t * 4 + k;
    v[k] = (i < N_) ? (u32)c[i] : 0u;
    ts += v[k];
  }
  u32 s = ts;
  #pragma unroll
  for (int o = 1; o < 64; o <<= 1) {
    u32 n = __shfl_up(s, o, 64);
    if (lane >= o) s += n;
  }
  __shared__ u32 ws[4];
  if (lane == 63) ws[w] = s;
  __syncthreads();
  u32 off = partial[r * SCNB_ + b];
  for (int k = 0; k < w; ++k) off += ws[k];
  off += s - ts;                        // exclusive offset of this thread
  u32 run = 0;
  #pragma unroll
  for (int k = 0; k < 4; ++k) {
    int i = base + t * 4 + k;
    if (i < N_) p[i] = off + run;
    run += v[k];
  }
}

__global__ __launch_bounds__(256) void csr_scatter(const int* __restrict__ dst,
                                                   const u32* __restrict__ ptr,
                                                   u32* __restrict__ fill,
                                                   u32* __restrict__ eidx) {
  int idx = blockIdx.x * blockDim.x + threadIdx.x;
  if (idx >= R_ * E_) return;
  int r = idx / E_, e = idx - r * E_;
  int d = dst[idx];
  u32 pos = ptr[(size_t)r * (N_ + 1) + d] + atomicAdd(&fill[(size_t)r * N_ + d], 1u);
  eidx[(size_t)r * E_ + pos] = (u32)e;
}

// ---- legacy 128x128 MFMA GEMM (kept for the small classifier GEMM) ----
__global__ __launch_bounds__(256, 2) void gemm_mfma(const u16* __restrict__ A,
                                                    const u16* __restrict__ BT,
                                                    const u16* __restrict__ bias,
                                                    u16* __restrict__ C,
                                                    int M, int ldc) {
  __shared__ u16 As[128 * 32];
  __shared__ u16 Bs[128 * 32];
  const int t = threadIdx.x;
  const int w = t >> 6, l = t & 63;
  const int bm = blockIdx.x * 128, bn = blockIdx.y * 128;
  const int wm = (w & 1) * 64, wn = (w >> 1) * 64;
  const int srow = w * 16 + (l >> 2);
  const int scol = (l & 3) * 8;
  f32x4 acc[4][4] = {};

  for (int k0 = 0; k0 < 512; k0 += 32) {
    #pragma unroll
    for (int p = 0; p < 2; ++p) {
      gl_lds16(A  + (size_t)(bm + p * 64 + srow) * 512 + k0 + scol, &As[(p * 64 + w * 16) * 32]);
      gl_lds16(BT + (size_t)(bn + p * 64 + srow) * 512 + k0 + scol, &Bs[(p * 64 + w * 16) * 32]);
    }
    __syncthreads();
    bf16x8 af[4], bfr[4];
    #pragma unroll
    for (int i = 0; i < 4; ++i) {
      af[i]  = *(const bf16x8*)&As[(wm + i * 16 + (l & 15)) * 32 + (l >> 4) * 8];
      bfr[i] = *(const bf16x8*)&Bs[(wn + i * 16 + (l & 15)) * 32 + (l >> 4) * 8];
    }
    #pragma unroll
    for (int mi = 0; mi < 4; ++mi)
      #pragma unroll
      for (int ni = 0; ni < 4; ++ni)
        acc[mi][ni] = __builtin_amdgcn_mfma_f32_16x16x32_bf16(af[mi], bfr[ni], acc[mi][ni], 0, 0, 0);
    __syncthreads();
  }

  float bv[4] = {0.f, 0.f, 0.f, 0.f};
  if (bias) {
    #pragma unroll
    for (int ni = 0; ni < 4; ++ni) bv[ni] = bf2f(bias[bn + wn + ni * 16 + (l & 15)]);
  }
  const int col0 = bn + wn + (l & 15);
  #pragma unroll
  for (int mi = 0; mi < 4; ++mi) {
    #pragma unroll
    for (int reg = 0; reg < 4; ++reg) {
      int gr = bm + wm + mi * 16 + (l >> 4) * 4 + reg;
      if (gr < M) {
        size_t rb = (size_t)gr * ldc;
        #pragma unroll
        for (int ni = 0; ni < 4; ++ni)
          C[rb + col0 + ni * 16] = f2bf(acc[mi][ni][reg] + bv[ni]);
      }
    }
  }
}

// ---- 256x256 MFMA GEMM, 2-phase counted-vmcnt dbuf + LDS XOR-swizzle (R3, 114 us) ----
// A[M,512] @ BT[Nn,512]^T -> C[M,ldc]; K=512 (8 K-tiles of 64).
// 8 waves (2Mx4N), per-wave C = 128x64. LDS 128 KiB: 2 bufs x (A 256x64 | B 256x64) bf16.
// Swizzle: 16B-chunk index ^= (row & 7), applied on gload SOURCE and ds_read (involution).
__global__ __launch_bounds__(512, 2) void gemm256(const u16* __restrict__ A,
                                                  const u16* __restrict__ BT,
                                                  const u16* __restrict__ bias,
                                                  u16* __restrict__ C,
                                                  int M, int ldc, int nb) {
  __shared__ u16 lds[65536];           // 128 KiB
  const int t = threadIdx.x;
  const int w = t >> 6, l = t & 63;
  const int wr = w >> 2, wc = w & 3;

  // XCD-bijective swizzle (m204), bn-fastest so one XCD walks a bm-panel across all bn
  const int nwg = gridDim.x;
  const int q = nwg >> 3, r = nwg & 7;
  const int xcd = blockIdx.x & 7, loc = blockIdx.x >> 3;
  const int wg = (xcd < r ? xcd * (q + 1) : r * (q + 1) + (xcd - r) * q) + loc;
  const int bn = (wg % nb) * 256;
  const int bm = (wg / nb) * 256;

  // staging addresses: lane l covers row w*8+(l>>3) (+i*64), swizzled source chunk
  const int lrow = l >> 3, lc8 = l & 7;
  const int csrc = ((lc8 ^ lrow) << 3);                 // element offset in 64-col K-tile
  const u16* Ag = A  + (size_t)(bm + w * 8 + lrow) * 512 + csrc;
  const u16* Bg = BT + (size_t)(bn + w * 8 + lrow) * 512 + csrc;

  auto stage = [&](int kt, int buf) {
    const size_t ko = (size_t)kt * 64;
    #pragma unroll
    for (int i = 0; i < 4; ++i)
      gl_lds16(Ag + (size_t)(i * 64) * 512 + ko, &lds[buf * 32768 + i * 4096 + w * 512]);
    #pragma unroll
    for (int i = 0; i < 4; ++i)
      gl_lds16(Bg + (size_t)(i * 64) * 512 + ko, &lds[buf * 32768 + 16384 + i * 4096 + w * 512]);
  };

  // fragment-read offsets (u16 units), with matching XOR swizzle
  const int rl = l & 15, rh = l >> 4;                   // rh in 0..3
  const int key = l & 7;                                // row_local & 7
  const int aoff = (wr * 128 + rl) * 64;
  const int boff = (wc * 64  + rl) * 64;
  const int c0 = ((rh)     ^ key) << 3;                 // kk=0 chunk
  const int c1 = ((4 + rh) ^ key) << 3;                 // kk=1 chunk

  f32x4 acc[8][4] = {};

  stage(0, 0);
  stage(1, 1);

  #pragma unroll
  for (int kt = 0; kt < 8; ++kt) {
    // tile kt fully resident after this wait (per-wave 8 loads/tile, 2 tiles in flight)
    if (kt == 7) asm volatile("s_waitcnt vmcnt(0)" ::: "memory");
    else         asm volatile("s_waitcnt vmcnt(8)" ::: "memory");
    __builtin_amdgcn_s_barrier();
    asm volatile("" ::: "memory");

    const u16* Ab = &lds[(kt & 1) * 32768];
    const u16* Bb = Ab + 16384;

    bf16x8 a0[8], b0[4];
    #pragma unroll
    for (int mt = 0; mt < 8; ++mt) a0[mt] = *(const bf16x8*)&Ab[aoff + mt * 1024 + c0];
    #pragma unroll
    for (int nt = 0; nt < 4; ++nt) b0[nt] = *(const bf16x8*)&Bb[boff + nt * 1024 + c0];

    #pragma unroll
    for (int mt = 0; mt < 8; ++mt)
      #pragma unroll
      for (int nt = 0; nt < 4; ++nt)
        acc[mt][nt] = __builtin_amdgcn_mfma_f32_16x16x32_bf16(a0[mt], b0[nt], acc[mt][nt], 0, 0, 0);

    bf16x8 a1[8], b1[4];
    #pragma unroll
    for (int mt = 0; mt < 8; ++mt) a1[mt] = *(const bf16x8*)&Ab[aoff + mt * 1024 + c1];
    #pragma unroll
    for (int nt = 0; nt < 4; ++nt) b1[nt] = *(const bf16x8*)&Bb[boff + nt * 1024 + c1];

    // all reads of buf[kt&1] done -> safe for everyone to overwrite it
    asm volatile("s_waitcnt lgkmcnt(0)" ::: "memory");
    __builtin_amdgcn_s_barrier();
    asm volatile("" ::: "memory");

    if (kt < 6) stage(kt + 2, kt & 1);

    #pragma unroll
    for (int mt = 0; mt < 8; ++mt)
      #pragma unroll
      for (int nt = 0; nt < 4; ++nt)
        acc[mt][nt] = __builtin_amdgcn_mfma_f32_16x16x32_bf16(a1[mt], b1[nt], acc[mt][nt], 0, 0, 0);
  }

  // ---- vectorized epilogue: per-wave 4 KiB LDS f32 transpose -> 8B stores ----
  float bv[4] = {0.f, 0.f, 0.f, 0.f};
  if (bias) {
    #pragma unroll
    for (int nt = 0; nt < 4; ++nt) bv[nt] = bf2f(bias[bn + wc * 64 + nt * 16 + rl]);
  }
  float* F = (float*)&lds[(size_t)w * 2048];   // [16][64] f32 per wave
  #pragma unroll
  for (int mt = 0; mt < 8; ++mt) {
    #pragma unroll
    for (int nt = 0; nt < 4; ++nt) {
      const int colw = (nt * 16 + rl) ^ ((rh & 1) << 4);
      #pragma unroll
      for (int reg = 0; reg < 4; ++reg)
        F[(rh * 4 + reg) * 64 + colw] = acc[mt][nt][reg] + bv[nt];
    }
    #pragma unroll
    for (int j = 0; j < 4; ++j) {
      const int row = rh + 4 * j;
      const int chunk = rl ^ ((j & 1) << 2);
      f32x4 vv = *(const f32x4*)&F[row * 64 + chunk * 4];
      u32 lo = (u32)f2bf(vv[0]) | ((u32)f2bf(vv[1]) << 16);
      u32 hi = (u32)f2bf(vv[2]) | ((u32)f2bf(vv[3]) << 16);
      const int gr = bm + wr * 128 + mt * 16 + row;
      if (gr < M) {
        uint2 pk; pk.x = lo; pk.y = hi;
        *(uint2*)&C[(size_t)gr * ldc + bn + wc * 64 + rl * 4] = pk;
      }
    }
  }
}

// ---- fused epilogue: wave-per-node, in-kernel edge softmax (no gat_edge kernel) ----
// pass1: CSR walk computing softmax denom from el/er; pass2: prefetched gather-FMA.
__global__ __launch_bounds__(256) void agg3_ln(const u16* __restrict__ fb,
                                               const int* __restrict__ src_r,
                                               const u32* __restrict__ ptr,
                                               const u32* __restrict__ eidx,
                                               const float* __restrict__ dors,
                                               const float* __restrict__ dirs,
                                               const float* __restrict__ el,
                                               const float* __restrict__ er,
                                               const u16* __restrict__ bc,  const u16* __restrict__ gc,  const u16* __restrict__ bec,
                                               const u16* __restrict__ bg,  const u16* __restrict__ gg,  const u16* __restrict__ beg,
                                               const u16* __restrict__ bs,  const u16* __restrict__ gs,  const u16* __restrict__ bes,
                                               u16* __restrict__ out) {
  const int l  = threadIdx.x & 63;
  const int d  = blockIdx.x * 4 + (threadIdx.x >> 6);
  const int c0 = l * 8;          // 8 cols, within one head (head = l>>3)
  const int hd = l >> 3;
  const float dird = dirs[d];
  const float erd = er[d * 8 + hd];
  const u32 p0 = ptr[d], p1 = ptr[d + 1];

  // pass 1: edge-softmax denominator (exp identical to old gat_edge; CSR-ordered sum)
  float sxv = 0.f;
  for (u32 i = p0; i < p1; ++i) {
    int s = src_r[eidx[i]];
    float v = el[s * 8 + hd] + erd;
    v = (v > 0.f) ? v : 0.2f * v;
    sxv += expf(fminf(v, 60.0f));
  }
  const float inv = (sxv > 0.f) ? 1.0f / sxv : 1.0f;

  float cv[8] = {0,0,0,0,0,0,0,0}, gv[8] = {0,0,0,0,0,0,0,0};
  if (p1 > p0) {
    // pass 2: software-pipelined gather (FP accumulation order identical to serial)
    int s = src_r[eidx[p0]];
    float sc = dors[s] * dird;
    float v0 = el[s * 8 + hd] + erd;
    v0 = (v0 > 0.f) ? v0 : 0.2f * v0;
    float wg = expf(fminf(v0, 60.0f)) * inv;
    const u16* xr = fb + (size_t)s * 1536 + c0;
    uint4 va = *(const uint4*)xr;
    uint4 vb = *(const uint4*)(xr + 512);
    for (u32 i = p0 + 1; i < p1; ++i) {
      int s2 = src_r[eidx[i]];
      float sc2 = dors[s2] * dird;
      float v2 = el[s2 * 8 + hd] + erd;
      v2 = (v2 > 0.f) ? v2 : 0.2f * v2;
      float wg2 = expf(fminf(v2, 60.0f)) * inv;
      const u16* xr2 = fb + (size_t)s2 * 1536 + c0;
      uint4 na = *(const uint4*)xr2;
      uint4 nb4 = *(const uint4*)(xr2 + 512);
      float a[8], b[8];
      unp8(va, a); unp8(vb, b);
      #pragma unroll
      for (int j = 0; j < 8; ++j) {
        cv[j] = fmaf(a[j], sc, cv[j]);
        gv[j] = fmaf(b[j], wg, gv[j]);
      }
      va = na; vb = nb4; sc = sc2; wg = wg2;
    }
    float a[8], b[8];
    unp8(va, a); unp8(vb, b);
    #pragma unroll
    for (int j = 0; j < 8; ++j) {
      cv[j] = fmaf(a[j], sc, cv[j]);
      gv[j] = fmaf(b[j], wg, gv[j]);
    }
  }
  float sv[8];
  ld8(fb + (size_t)d * 1536 + 1024 + c0, sv);
  float t8[8];
  ld8(bc + c0, t8);
  #pragma unroll
  for (int j = 0; j < 8; ++j) cv[j] += t8[j];
  ld8(bg + c0, t8);
  #pragma unroll
  for (int j = 0; j < 8; ++j) gv[j] += t8[j];
  ld8(bs + c0, t8);
  #pragma unroll
  for (int j = 0; j < 8; ++j) sv[j] += t8[j];

  float s;
  s = 0.f;
  #pragma unroll
  for (int j = 0; j < 8; ++j) s += cv[j];
  float mc = wsumb(s) * (1.0f / 512.0f);
  s = 0.f;
  #pragma unroll
  for (int j = 0; j < 8; ++j) { cv[j] -= mc; s += cv[j] * cv[j]; }
  float rc = rsqrtf(wsumb(s) * (1.0f / 512.0f) + 1e-12f);

  s = 0.f;
  #pragma unroll
  for (int j = 0; j < 8; ++j) s += gv[j];
  float mg = wsumb(s) * (1.0f / 512.0f);
  s = 0.f;
  #pragma unroll
  for (int j = 0; j < 8; ++j) { gv[j] -= mg; s += gv[j] * gv[j]; }
  float rg = rsqrtf(wsumb(s) * (1.0f / 512.0f) + 1e-12f);

  s = 0.f;
  #pragma unroll
  for (int j = 0; j < 8; ++j) s += sv[j];
  float ms = wsumb(s) * (1.0f / 512.0f);
  s = 0.f;
  #pragma unroll
  for (int j = 0; j < 8; ++j) { sv[j] -= ms; s += sv[j] * sv[j]; }
  float rs = rsqrtf(wsumb(s) * (1.0f / 512.0f) + 1e-12f);

  float o8[8];
  float ga[8], be8[8];
  ld8(gc + c0, ga); ld8(bec + c0, be8);
  #pragma unroll
  for (int j = 0; j < 8; ++j) {
    float y = ga[j] * cv[j] * rc + be8[j];
    o8[j] = (y > 0.f) ? y : expm1f(y);
  }
  ld8(gg + c0, ga); ld8(beg + c0, be8);
  #pragma unroll
  for (int j = 0; j < 8; ++j) {
    float y = ga[j] * gv[j] * rg + be8[j];
    o8[j] += (y > 0.f) ? y : expm1f(y);
  }
  ld8(gs + c0, ga); ld8(bes + c0, be8);
  #pragma unroll
  for (int j = 0; j < 8; ++j) {
    float y = ga[j] * sv[j] * rs + be8[j];
    o8[j] += (y > 0.f) ? y : expm1f(y);
  }
  uint4 o;
  u32 wpk[4];
  #pragma unroll
  for (int j = 0; j < 4; ++j)
    wpk[j] = (u32)f2bf(o8[2 * j]) | ((u32)f2bf(o8[2 * j + 1]) << 16);
  o.x = wpk[0]; o.y = wpk[1]; o.z = wpk[2]; o.w = wpk[3];
  *(uint4*)(out + (size_t)d * 1536 + c0) = o;
}

// ---------------- GAT el/er per node-head ----------------
__global__ __launch_bounds__(256) void gat_el_er(const u16* __restrict__ f, int fstride,
                                                 const u16* __restrict__ al,
                                                 const u16* __restrict__ ar,
                                                 float* __restrict__ el,
                                                 float* __restrict__ er) {
  int idx = blockIdx.x * blockDim.x + threadIdx.x;
  if (idx >= N_ * HEADS_) return;
  int n = idx >> 3, hd = idx & 7;
  const u16* fr = f + (size_t)n * fstride + hd * 64;
  const u16* alr = al + hd * 64;
  const u16* arr = ar + hd * 64;
  float a = 0.f, b = 0.f;
  for (int d0 = 0; d0 < 64; d0 += 8) {
    float fv[8], av[8], bv[8];
    ld8(fr + d0, fv); ld8(alr + d0, av); ld8(arr + d0, bv);
    #pragma unroll
    for (int j = 0; j < 8; ++j) {
      a = fmaf(fv[j], av[j], a);
      b = fmaf(fv[j], bv[j], b);
    }
  }
  el[idx] = a; er[idx] = b;
}

// ---------------- fused relation MHA over QKV[row=(n*3+r)][q|k|v 512 each] ----------------
__global__ __launch_bounds__(256) void mha_fused(const u16* __restrict__ QKV,
                                                 u16* __restrict__ hout, int C) {
  int idx = blockIdx.x * blockDim.x + threadIdx.x;
  if (idx >= C * HEADS_) return;
  int n = idx >> 3, hd = idx & 7;
  const u16* b0 = QKV + (size_t)n * 4608 + hd * 64;
  float sc[9] = {0.f,0.f,0.f,0.f,0.f,0.f,0.f,0.f,0.f};
  for (int d0 = 0; d0 < 64; d0 += 8) {
    float q0[8], q1[8], q2[8], k0[8], k1[8], k2[8];
    ld8(b0 + d0, q0);        ld8(b0 + 1536 + d0, q1); ld8(b0 + 3072 + d0, q2);
    ld8(b0 + 512 + d0, k0);  ld8(b0 + 2048 + d0, k1); ld8(b0 + 3584 + d0, k2);
    #pragma unroll
    for (int j = 0; j < 8; ++j) {
      sc[0] = fmaf(q0[j], k0[j], sc[0]); sc[1] = fmaf(q0[j], k1[j], sc[1]); sc[2] = fmaf(q0[j], k2[j], sc[2]);
      sc[3] = fmaf(q1[j], k0[j], sc[3]); sc[4] = fmaf(q1[j], k1[j], sc[4]); sc[5] = fmaf(q1[j], k2[j], sc[5]);
      sc[6] = fmaf(q2[j], k0[j], sc[6]); sc[7] = fmaf(q2[j], k1[j], sc[7]); sc[8] = fmaf(q2[j], k2[j], sc[8]);
    }
  }
  float wp0 = 0.f, wp1 = 0.f, wp2 = 0.f;
  #pragma unroll
  for (int r = 0; r < 3; ++r) {
    float a = sc[r * 3 + 0] * 0.125f;
    float b = sc[r * 3 + 1] * 0.125f;
    float c = sc[r * 3 + 2] * 0.125f;
    float m = fmaxf(a, fmaxf(b, c));
    float ea = expf(a - m), eb = expf(b - m), ec = expf(c - m);
    float inv = 1.0f / (ea + eb + ec);
    wp0 += ea * inv; wp1 += eb * inv; wp2 += ec * inv;
  }
  wp0 *= (1.0f / 3.0f); wp1 *= (1.0f / 3.0f); wp2 *= (1.0f / 3.0f);
  u16* ho = hout + (size_t)n * 512 + hd * 64;
  for (int d0 = 0; d0 < 64; d0 += 8) {
    float v0[8], v1[8], v2[8];
    ld8(b0 + 1024 + d0, v0); ld8(b0 + 2560 + d0, v1); ld8(b0 + 4096 + d0, v2);
    uint4 o;
    u32 w[4];
    #pragma unroll
    for (int j = 0; j < 4; ++j) {
      u16 lo = f2bf(wp0 * v0[2*j]   + wp1 * v1[2*j]   + wp2 * v2[2*j]);
      u16 hi = f2bf(wp0 * v0[2*j+1] + wp1 * v1[2*j+1] + wp2 * v2[2*j+1]);
      w[j] = (u32)lo | ((u32)hi << 16);
    }
    o.x = w[0]; o.y = w[1]; o.z = w[2]; o.w = w[3];
    *(uint4*)(ho + d0) = o;
  }
}

// ---------------- classifier store: clsbuf[N,128] -> d_out[N,23] ----------------
__global__ __launch_bounds__(256) void cls_store(const u16* __restrict__ clsbuf,
                                                 void* __restrict__ out,
                                                 const int* __restrict__ flag) {
  int idx = blockIdx.x * blockDim.x + threadIdx.x;
  if (idx >= N_ * NCLS_) return;
  int n = idx / NCLS_, c = idx - n * NCLS_;
  float s = bf2f(clsbuf[(size_t)n * 128 + c]);
  if (!(s == s)) s = 12345.0f;   // NaN sentinel
  if (*flag) ((u16*)out)[idx] = f2bf(s);
  else       ((float*)out)[idx] = s;
}

static inline int cdiv(long long a, long long b) { return (int)((a + b - 1) / b); }

extern "C" void kernel_launch(void* const* d_in, const int* in_sizes, int n_in,
                              void* d_out, int out_size, void* d_ws, size_t ws_size,
                              hipStream_t stream) {
  // ---- workspace plan (bytes, 256-aligned) ----
  size_t off = 0;
  auto take = [&](size_t bytes) { size_t o = off; off += (bytes + 255) & ~(size_t)255; return o; };
  const size_t o_flag    = take(256);
  const size_t o_stacked = take((size_t)N_ * 1536 * 2);            // 153.6 MB bf16
  const size_t o_h       = take((size_t)N_ * 512 * 2);             //  51.2 MB (feature alias)
  const size_t o_trans   = take((size_t)N_ * 1536 * 2);            // 153.6 MB fbuf / qkv / clsbuf
  const size_t o_el    = take((size_t)N_ * HEADS_ * 4);
  const size_t o_er    = take((size_t)N_ * HEADS_ * 4);
  const size_t o_deg   = take((size_t)2 * R_ * N_ * 4);
  const size_t o_csrp  = take((size_t)R_ * (N_ + 1) * 4);
  const size_t o_eidx  = take((size_t)R_ * E_ * 4);
  const size_t o_fill  = take((size_t)R_ * N_ * 4);
  const size_t o_part  = take((size_t)R_ * SCNB_ * 4);             // scan partials
  const size_t o_wts   = take((size_t)6500000 * 2);                // staged bf16 weights
  const size_t need = off;

  if (ws_size < need) {
    write_const<<<cdiv(out_size, 256), 256, 0, stream>>>((u16*)d_out, out_size,
                                                         (float)(ws_size >> 20));
    return;
  }

  char* base = (char*)d_ws;
  int*   flag    = (int*)(base + o_flag);
  u16*   stacked = (u16*)(base + o_stacked);
  u16*   h       = (u16*)(base + o_h);
  u16*   fbuf    = (u16*)(base + o_trans);     // [N,1536] fused branch GEMM out
  u16*   qkv     = (u16*)(base + o_trans);     // [CHUNK*3,1536] (aliases, disjoint in time)
  u16*   clsbuf  = (u16*)(base + o_trans);     // [N,128]       (aliases, disjoint in time)
  float* el    = (float*)(base + o_el);
  float* er    = (float*)(base + o_er);
  float* degout = (float*)(base + o_deg);
  float* degin  = degout + (size_t)R_ * N_;
  u32*   csrp  = (u32*)(base + o_csrp);
  u32*   eidx  = (u32*)(base + o_eidx);
  u32*   fill  = (u32*)(base + o_fill);
  u32*   part  = (u32*)(base + o_part);

  const int* src = (const int*)d_in[1];
  const int* dst = (const int*)d_in[2];

  // ---- dtype probe ----
  detect_dtype<<<1, 256, 0, stream>>>(d_in[3], flag);

  // ---- staged weight layout (elements within o_wts) ----
  u16* wts   = (u16*)(base + o_wts);
  u16* wbrT  = wts;                              // [6][1536n][512k]: Wc | Wg | Wsk rows
  u16* wqkvT = wbrT + 6 * 786432;                // [2][1536n][512k] (q|k|v)
  u16* bqkv  = wqkvT + 2 * 786432;               // [2][1536]
  u16* wclsT = bqkv + 2 * 1536;                  // [128][512]
  u16* bcls  = wclsT + 128 * 512;                // [128]
  u16* prm   = bcls + 128;                       // 11 x [3072] small params

  stage_bf16<<<cdiv(N_ * 512, 256), 256, 0, stream>>>(d_in[0], 0, h, N_ * 512, flag);
  dim3 tb(32, 8);
  stageT<<<dim3(16, 16, 6), tb, 0, stream>>>(d_in[3],  0, 262144, wbrT,          786432, flag);
  stageT<<<dim3(16, 16, 6), tb, 0, stream>>>(d_in[7],  0, 262144, wbrT + 262144, 786432, flag);
  stageT<<<dim3(16, 16, 6), tb, 0, stream>>>(d_in[13], 0, 262144, wbrT + 524288, 786432, flag);
  stageT<<<dim3(16, 16, 2), tb, 0, stream>>>(d_in[17], 0, 262144, wqkvT,          786432, flag);
  stageT<<<dim3(16, 16, 2), tb, 0, stream>>>(d_in[19], 0, 262144, wqkvT + 262144, 786432, flag);
  stageT<<<dim3(16, 16, 2), tb, 0, stream>>>(d_in[21], 0, 262144, wqkvT + 524288, 786432, flag);
  stage_wclsT<<<cdiv(128 * 512, 256), 256, 0, stream>>>(d_in[23], wclsT, flag);
  stage_bcls<<<1, 128, 0, stream>>>(d_in[24], bcls, flag);
  stage_bqkv<<<cdiv(2 * 1536, 256), 256, 0, stream>>>(d_in[18], d_in[20], d_in[22], bqkv, flag);

  P11 p11;
  p11.p[0] = d_in[4];  p11.p[1] = d_in[5];  p11.p[2]  = d_in[6];
  p11.p[3] = d_in[8];  p11.p[4] = d_in[9];  p11.p[5]  = d_in[10];
  p11.p[6] = d_in[11]; p11.p[7] = d_in[12]; p11.p[8]  = d_in[14];
  p11.p[9] = d_in[15]; p11.p[10] = d_in[16];
  stage_p11<<<cdiv(11 * 3072, 256), 256, 0, stream>>>(p11, prm, flag);
  const u16 *bc  = prm,            *gc  = prm + 3072,  *bec = prm + 2 * 3072;
  const u16 *bg  = prm + 3 * 3072, *al  = prm + 4 * 3072, *ar = prm + 5 * 3072;
  const u16 *gg  = prm + 6 * 3072, *beg = prm + 7 * 3072;
  const u16 *bs  = prm + 8 * 3072, *gs  = prm + 9 * 3072, *bes = prm + 10 * 3072;

  // ---- degrees + CSR (parallel 3-phase scan) ----
  hipMemsetAsync(degout, 0, (size_t)2 * R_ * N_ * sizeof(float), stream);
  deg_count<<<cdiv((long long)R_ * E_, 256), 256, 0, stream>>>(src, dst, degout, degin);
  scan_blksum<<<dim3(SCNB_, R_), 256, 0, stream>>>(degin, part);
  scan_partials<<<R_, 64, 0, stream>>>(part, csrp);
  scan_write<<<dim3(SCNB_, R_), 256, 0, stream>>>(degin, part, csrp);
  deg_fin<<<cdiv((long long)2 * R_ * N_, 256), 256, 0, stream>>>(degout);
  hipMemsetAsync(fill, 0, (size_t)R_ * N_ * sizeof(u32), stream);
  csr_scatter<<<cdiv((long long)R_ * E_, 256), 256, 0, stream>>>(dst, csrp, fill, eidx);

  const int mbBR = cdiv(N_, 256);                    // 196 -> grid 1176
  const int mbQ  = cdiv((long long)CHUNK_ * 3, 256); // 147 -> grid 882
  const dim3 gridCLS(cdiv(N_, 128), 1);              // [50000,512] @ [512,128] (legacy kernel)

  for (int l = 0; l < 2; ++l) {
    for (int r = 0; r < 3; ++r) {
      int lr = l * 3 + r;
      const int* sr = src + r * E_;
      const u32* pr = csrp + (size_t)r * (N_ + 1);
      const u32* er_idx = eidx + (size_t)r * E_;
      // fused conv|gat|skip GEMM (256^2 pipelined, R3 structure)
      gemm256<<<mbBR * 6, 512, 0, stream>>>(h, wbrT + (size_t)lr * 786432, nullptr, fbuf, N_, 1536, 6);
      // GAT el/er per node-head (edge softmax is fused into agg3_ln)
      gat_el_er<<<cdiv(N_ * HEADS_, 256), 256, 0, stream>>>(fbuf + 512, 1536,
                                                            al + lr * 512, ar + lr * 512,
                                                            el, er);
      // fused edge-softmax + CSR aggregation + 3x LN+ELU + sum -> stacked[:,r,:]
      agg3_ln<<<cdiv(N_, 4), 256, 0, stream>>>(fbuf, sr, pr, er_idx,
                                               degout + r * N_, degin + r * N_, el, er,
                                               bc + lr * 512, gc + lr * 512, bec + lr * 512,
                                               bg + lr * 512, gg + lr * 512, beg + lr * 512,
                                               bs + lr * 512, gs + lr * 512, bes + lr * 512,
                                               stacked + r * 512);
    }
    // fused QKV + relation MHA (chunked; qkv aliases fbuf region)
    for (int c = 0; c < N_ / CHUNK_; ++c) {
      gemm256<<<mbQ * 6, 512, 0, stream>>>(stacked + (size_t)c * CHUNK_ * 1536,
                                           wqkvT + (size_t)l * 786432, bqkv + l * 1536,
                                           qkv, CHUNK_ * 3, 1536, 6);
      mha_fused<<<cdiv(CHUNK_ * HEADS_, 256), 256, 0, stream>>>(qkv, h + (size_t)c * CHUNK_ * 512,
                                                                CHUNK_);
    }
  }
  // classifier: MFMA GEMM into padded [N,128] + store
  gemm_mfma<<<gridCLS, 256, 0, stream>>>(h, wclsT, bcls, clsbuf, N_, 128);
  cls_store<<<cdiv((long long)N_ * NCLS_, 256), 256, 0, stream>>>(clsbuf, d_out, flag);
}

// Round 7
// 2500.455 us; speedup vs baseline: 1.3248x; 1.2761x over previous
//
#include <hip/hip_runtime.h>

#define N_     50000
#define E_     150000
#define R_     3
#define H_     512
#define HEADS_ 8
#define DH_    64
#define NCLS_  23
#define CHUNK_ 12500   // nodes per QKV/MHA chunk (N_/4)
#define SCNB_  49      // ceil(N_/1024) scan blocks per relation

typedef unsigned short u16;
typedef unsigned int   u32;
typedef __attribute__((ext_vector_type(8))) short bf16x8;
typedef __attribute__((ext_vector_type(4))) float f32x4;

__device__ __forceinline__ float bf2f(u16 u) {
  union { u32 i; float f; } v; v.i = ((u32)u) << 16; return v.f;
}
__device__ __forceinline__ u16 f2bf(float f) {
  u32 u = __float_as_uint(f);
  u += 0x7fffu + ((u >> 16) & 1u);   // round-to-nearest-even
  return (u16)(u >> 16);
}

__device__ __forceinline__ void unp8(uint4 v, float o[8]) {
  o[0] = bf2f((u16)(v.x & 0xffff)); o[1] = bf2f((u16)(v.x >> 16));
  o[2] = bf2f((u16)(v.y & 0xffff)); o[3] = bf2f((u16)(v.y >> 16));
  o[4] = bf2f((u16)(v.z & 0xffff)); o[5] = bf2f((u16)(v.z >> 16));
  o[6] = bf2f((u16)(v.w & 0xffff)); o[7] = bf2f((u16)(v.w >> 16));
}
// 8 bf16 -> 8 fp32 via one 16B load
__device__ __forceinline__ void ld8(const u16* __restrict__ p, float o[8]) {
  unp8(*(const uint4*)p, o);
}

// wave-wide sum, result broadcast to all 64 lanes
__device__ __forceinline__ float wsumb(float v) {
  #pragma unroll
  for (int o = 32; o > 0; o >>= 1) v += __shfl_down(v, o, 64);
  return __shfl(v, 0, 64);
}

// async global->LDS, 16B per lane
__device__ __forceinline__ void gl_lds16(const u16* g, u16* l) {
  __builtin_amdgcn_global_load_lds(
      (const __attribute__((address_space(1))) unsigned int*)g,
      (__attribute__((address_space(3))) unsigned int*)l, 16, 0, 0);
}

// ---------------- ws-size probe fallback ----------------
__global__ __launch_bounds__(256) void write_const(u16* __restrict__ out, int n, float v) {
  int i = blockIdx.x * blockDim.x + threadIdx.x;
  if (i < n) out[i] = f2bf(v);
}

// ---------------- dtype probe ----------------
__global__ void detect_dtype(const void* __restrict__ wc, int* __restrict__ flag) {
  __shared__ int cnt;
  if (threadIdx.x == 0) cnt = 0;
  __syncthreads();
  const u16* p = (const u16*)wc;
  int ok = 0;
  for (int i = threadIdx.x; i < 2048; i += 256) {
    float a = fabsf(bf2f(p[i]));
    if (a <= 4.0f) ok++;
  }
  atomicAdd(&cnt, ok);
  __syncthreads();
  if (threadIdx.x == 0) *flag = (cnt >= 2000) ? 1 : 0;   // 1=bf16, 0=fp32
}

// stage float tensor -> bf16 ws
__global__ __launch_bounds__(256) void stage_bf16(const void* __restrict__ in, size_t off,
                                                  u16* __restrict__ out, int n,
                                                  const int* __restrict__ flag) {
  int i = blockIdx.x * blockDim.x + threadIdx.x;
  if (i >= n) return;
  out[i] = (*flag) ? ((const u16*)in)[off + i] : f2bf(((const float*)in)[off + i]);
}

// batched staging of the 11 small [3072] parameter tensors in one dispatch
struct P11 { const void* p[11]; };
__global__ __launch_bounds__(256) void stage_p11(P11 srcs, u16* __restrict__ out,
                                                 const int* __restrict__ flag) {
  int idx = blockIdx.x * blockDim.x + threadIdx.x;
  if (idx >= 11 * 3072) return;
  int ti = idx / 3072, off = idx - ti * 3072;
  const void* in = srcs.p[ti];
  out[idx] = (*flag) ? ((const u16*)in)[off] : f2bf(((const float*)in)[off]);
}

// bqkv: out[l][q|k|v] (2x1536) from 3 tensors of [2][512]
__global__ __launch_bounds__(256) void stage_bqkv(const void* __restrict__ q,
                                                  const void* __restrict__ k,
                                                  const void* __restrict__ v,
                                                  u16* __restrict__ out,
                                                  const int* __restrict__ flag) {
  int idx = blockIdx.x * blockDim.x + threadIdx.x;
  if (idx >= 2 * 1536) return;
  int l = idx / 1536, c = idx - l * 1536;
  const void* in = (c < 512) ? q : (c < 1024) ? k : v;
  int off = l * 512 + (c & 511);
  out[idx] = (*flag) ? ((const u16*)in)[off] : f2bf(((const float*)in)[off]);
}

// stage 512x512 weight slices TRANSPOSED: out[n][k] = in[k][n]; grid.z = matrix idx
__global__ __launch_bounds__(256) void stageT(const void* __restrict__ in, size_t in_off,
                                              size_t in_mstride, u16* __restrict__ out,
                                              size_t out_mstride, const int* __restrict__ flag) {
  __shared__ u16 tile[32][33];
  const int m = blockIdx.z;
  const size_t ib = in_off + (size_t)m * in_mstride;
  const size_t ob = (size_t)m * out_mstride;
  const int kb = blockIdx.x * 32, nb = blockIdx.y * 32;
  const int tx = threadIdx.x, ty = threadIdx.y;
  const bool isbf = (*flag != 0);
  #pragma unroll
  for (int i = 0; i < 32; i += 8) {
    size_t si = ib + (size_t)(kb + ty + i) * 512 + nb + tx;
    tile[ty + i][tx] = isbf ? ((const u16*)in)[si] : f2bf(((const float*)in)[si]);
  }
  __syncthreads();
  #pragma unroll
  for (int i = 0; i < 32; i += 8)
    out[ob + (size_t)(nb + ty + i) * 512 + kb + tx] = tile[tx][ty + i];
}

// stage Wout transposed + zero-padded to [128][512]
__global__ __launch_bounds__(256) void stage_wclsT(const void* __restrict__ in,
                                                   u16* __restrict__ out,
                                                   const int* __restrict__ flag) {
  int i = blockIdx.x * blockDim.x + threadIdx.x;
  if (i >= 128 * 512) return;
  int c = i >> 9, k = i & 511;
  u16 v = 0;
  if (c < NCLS_) {
    size_t si = (size_t)k * NCLS_ + c;
    v = (*flag) ? ((const u16*)in)[si] : f2bf(((const float*)in)[si]);
  }
  out[i] = v;
}
__global__ void stage_bcls(const void* __restrict__ in, u16* __restrict__ out,
                           const int* __restrict__ flag) {
  int i = threadIdx.x;
  if (i >= 128) return;
  u16 v = 0;
  if (i < NCLS_) v = (*flag) ? ((const u16*)in)[i] : f2bf(((const float*)in)[i]);
  out[i] = v;
}

// ---------------- degrees ----------------
__global__ __launch_bounds__(256) void deg_count(const int* __restrict__ src,
                                                 const int* __restrict__ dst,
                                                 float* __restrict__ degout,
                                                 float* __restrict__ degin) {
  int idx = blockIdx.x * blockDim.x + threadIdx.x;
  if (idx >= R_ * E_) return;
  int r = idx / E_;
  atomicAdd(&degout[r * N_ + src[idx]], 1.0f);
  atomicAdd(&degin [r * N_ + dst[idx]], 1.0f);
}
__global__ __launch_bounds__(256) void deg_fin(float* __restrict__ deg) {
  int idx = blockIdx.x * blockDim.x + threadIdx.x;
  if (idx >= 2 * R_ * N_) return;
  deg[idx] = rsqrtf(fmaxf(deg[idx], 1.0f));
}

// ---------------- CSR build: parallel 3-phase exclusive scan ----------------
__global__ __launch_bounds__(256) void scan_blksum(const float* __restrict__ cnt,
                                                   u32* __restrict__ partial) {
  const int r = blockIdx.y, b = blockIdx.x;
  const int base = b * 1024;
  const float* c = cnt + (size_t)r * N_;
  const int t = threadIdx.x;
  u32 s = 0;
  #pragma unroll
  for (int k = 0; k < 4; ++k) {
    int i = base + t * 4 + k;
    if (i < N_) s += (u32)c[i];
  }
  #pragma unroll
  for (int o = 32; o > 0; o >>= 1) s += __shfl_down(s, o, 64);
  __shared__ u32 ws[4];
  if ((t & 63) == 0) ws[t >> 6] = s;
  __syncthreads();
  if (t == 0) partial[r * SCNB_ + b] = ws[0] + ws[1] + ws[2] + ws[3];
}

__global__ void scan_partials(u32* __restrict__ partial, u32* __restrict__ ptr) {
  const int r = blockIdx.x;
  u32* p = partial + r * SCNB_;
  const int l = threadIdx.x;           // 64 threads = 1 wave
  u32 v = (l < SCNB_) ? p[l] : 0u;
  u32 s = v;
  #pragma unroll
  for (int o = 1; o < 64; o <<= 1) {
    u32 n = __shfl_up(s, o, 64);
    if (l >= o) s += n;
  }
  if (l < SCNB_) p[l] = s - v;         // exclusive
  if (l == 63) ptr[(size_t)r * (N_ + 1) + N_] = s;   // grand total
}

__global__ __launch_bounds__(256) void scan_write(const float* __restrict__ cnt,
                                                  const u32* __restrict__ partial,
                                                  u32* __restrict__ ptr) {
  const int r = blockIdx.y, b = blockIdx.x;
  const int base = b * 1024;
  const float* c = cnt + (size_t)r * N_;
  u32* p = ptr + (size_t)r * (N_ + 1);
  const int t = threadIdx.x, lane = t & 63, w = t >> 6;
  u32 v[4]; u32 ts = 0;
  #pragma unroll
  for (int k = 0; k < 4; ++k) {
    int i = base + t * 4 + k;
    v[k] = (i < N_) ? (u32)c[i] : 0u;
    ts += v[k];
  }
  u32 s = ts;
  #pragma unroll
  for (int o = 1; o < 64; o <<= 1) {
    u32 n = __shfl_up(s, o, 64);
    if (lane >= o) s += n;
  }
  __shared__ u32 ws[4];
  if (lane == 63) ws[w] = s;
  __syncthreads();
  u32 off = partial[r * SCNB_ + b];
  for (int k = 0; k < w; ++k) off += ws[k];
  off += s - ts;                        // exclusive offset of this thread
  u32 run = 0;
  #pragma unroll
  for (int k = 0; k < 4; ++k) {
    int i = base + t * 4 + k;
    if (i < N_) p[i] = off + run;
    run += v[k];
  }
}

__global__ __launch_bounds__(256) void csr_scatter(const int* __restrict__ dst,
                                                   const u32* __restrict__ ptr,
                                                   u32* __restrict__ fill,
                                                   u32* __restrict__ eidx) {
  int idx = blockIdx.x * blockDim.x + threadIdx.x;
  if (idx >= R_ * E_) return;
  int r = idx / E_, e = idx - r * E_;
  int d = dst[idx];
  u32 pos = ptr[(size_t)r * (N_ + 1) + d] + atomicAdd(&fill[(size_t)r * N_ + d], 1u);
  eidx[(size_t)r * E_ + pos] = (u32)e;
}

// ---- legacy 128x128 MFMA GEMM (kept for the small classifier GEMM) ----
__global__ __launch_bounds__(256, 2) void gemm_mfma(const u16* __restrict__ A,
                                                    const u16* __restrict__ BT,
                                                    const u16* __restrict__ bias,
                                                    u16* __restrict__ C,
                                                    int M, int ldc) {
  __shared__ u16 As[128 * 32];
  __shared__ u16 Bs[128 * 32];
  const int t = threadIdx.x;
  const int w = t >> 6, l = t & 63;
  const int bm = blockIdx.x * 128, bn = blockIdx.y * 128;
  const int wm = (w & 1) * 64, wn = (w >> 1) * 64;
  const int srow = w * 16 + (l >> 2);
  const int scol = (l & 3) * 8;
  f32x4 acc[4][4] = {};

  for (int k0 = 0; k0 < 512; k0 += 32) {
    #pragma unroll
    for (int p = 0; p < 2; ++p) {
      gl_lds16(A  + (size_t)(bm + p * 64 + srow) * 512 + k0 + scol, &As[(p * 64 + w * 16) * 32]);
      gl_lds16(BT + (size_t)(bn + p * 64 + srow) * 512 + k0 + scol, &Bs[(p * 64 + w * 16) * 32]);
    }
    __syncthreads();
    bf16x8 af[4], bfr[4];
    #pragma unroll
    for (int i = 0; i < 4; ++i) {
      af[i]  = *(const bf16x8*)&As[(wm + i * 16 + (l & 15)) * 32 + (l >> 4) * 8];
      bfr[i] = *(const bf16x8*)&Bs[(wn + i * 16 + (l & 15)) * 32 + (l >> 4) * 8];
    }
    #pragma unroll
    for (int mi = 0; mi < 4; ++mi)
      #pragma unroll
      for (int ni = 0; ni < 4; ++ni)
        acc[mi][ni] = __builtin_amdgcn_mfma_f32_16x16x32_bf16(af[mi], bfr[ni], acc[mi][ni], 0, 0, 0);
    __syncthreads();
  }

  float bv[4] = {0.f, 0.f, 0.f, 0.f};
  if (bias) {
    #pragma unroll
    for (int ni = 0; ni < 4; ++ni) bv[ni] = bf2f(bias[bn + wn + ni * 16 + (l & 15)]);
  }
  const int col0 = bn + wn + (l & 15);
  #pragma unroll
  for (int mi = 0; mi < 4; ++mi) {
    #pragma unroll
    for (int reg = 0; reg < 4; ++reg) {
      int gr = bm + wm + mi * 16 + (l >> 4) * 4 + reg;
      if (gr < M) {
        size_t rb = (size_t)gr * ldc;
        #pragma unroll
        for (int ni = 0; ni < 4; ++ni)
          C[rb + col0 + ni * 16] = f2bf(acc[mi][ni][reg] + bv[ni]);
      }
    }
  }
}

// ---- 256x256 MFMA GEMM, 2-phase counted-vmcnt dbuf + LDS XOR-swizzle (R3, 114 us) ----
// A[M,512] @ BT[Nn,512]^T -> C[M,ldc]; K=512 (8 K-tiles of 64).
// 8 waves (2Mx4N), per-wave C = 128x64. LDS 128 KiB: 2 bufs x (A 256x64 | B 256x64) bf16.
// Swizzle: 16B-chunk index ^= (row & 7), applied on gload SOURCE and ds_read (involution).
__global__ __launch_bounds__(512, 2) void gemm256(const u16* __restrict__ A,
                                                  const u16* __restrict__ BT,
                                                  const u16* __restrict__ bias,
                                                  u16* __restrict__ C,
                                                  int M, int ldc, int nb) {
  __shared__ u16 lds[65536];           // 128 KiB
  const int t = threadIdx.x;
  const int w = t >> 6, l = t & 63;
  const int wr = w >> 2, wc = w & 3;

  // XCD-bijective swizzle (m204), bn-fastest so one XCD walks a bm-panel across all bn
  const int nwg = gridDim.x;
  const int q = nwg >> 3, r = nwg & 7;
  const int xcd = blockIdx.x & 7, loc = blockIdx.x >> 3;
  const int wg = (xcd < r ? xcd * (q + 1) : r * (q + 1) + (xcd - r) * q) + loc;
  const int bn = (wg % nb) * 256;
  const int bm = (wg / nb) * 256;

  // staging addresses: lane l covers row w*8+(l>>3) (+i*64), swizzled source chunk
  const int lrow = l >> 3, lc8 = l & 7;
  const int csrc = ((lc8 ^ lrow) << 3);                 // element offset in 64-col K-tile
  const u16* Ag = A  + (size_t)(bm + w * 8 + lrow) * 512 + csrc;
  const u16* Bg = BT + (size_t)(bn + w * 8 + lrow) * 512 + csrc;

  auto stage = [&](int kt, int buf) {
    const size_t ko = (size_t)kt * 64;
    #pragma unroll
    for (int i = 0; i < 4; ++i)
      gl_lds16(Ag + (size_t)(i * 64) * 512 + ko, &lds[buf * 32768 + i * 4096 + w * 512]);
    #pragma unroll
    for (int i = 0; i < 4; ++i)
      gl_lds16(Bg + (size_t)(i * 64) * 512 + ko, &lds[buf * 32768 + 16384 + i * 4096 + w * 512]);
  };

  // fragment-read offsets (u16 units), with matching XOR swizzle
  const int rl = l & 15, rh = l >> 4;                   // rh in 0..3
  const int key = l & 7;                                // row_local & 7
  const int aoff = (wr * 128 + rl) * 64;
  const int boff = (wc * 64  + rl) * 64;
  const int c0 = ((rh)     ^ key) << 3;                 // kk=0 chunk
  const int c1 = ((4 + rh) ^ key) << 3;                 // kk=1 chunk

  f32x4 acc[8][4] = {};

  stage(0, 0);
  stage(1, 1);

  #pragma unroll
  for (int kt = 0; kt < 8; ++kt) {
    // tile kt fully resident after this wait (per-wave 8 loads/tile, 2 tiles in flight)
    if (kt == 7) asm volatile("s_waitcnt vmcnt(0)" ::: "memory");
    else         asm volatile("s_waitcnt vmcnt(8)" ::: "memory");
    __builtin_amdgcn_s_barrier();
    asm volatile("" ::: "memory");

    const u16* Ab = &lds[(kt & 1) * 32768];
    const u16* Bb = Ab + 16384;

    bf16x8 a0[8], b0[4];
    #pragma unroll
    for (int mt = 0; mt < 8; ++mt) a0[mt] = *(const bf16x8*)&Ab[aoff + mt * 1024 + c0];
    #pragma unroll
    for (int nt = 0; nt < 4; ++nt) b0[nt] = *(const bf16x8*)&Bb[boff + nt * 1024 + c0];

    #pragma unroll
    for (int mt = 0; mt < 8; ++mt)
      #pragma unroll
      for (int nt = 0; nt < 4; ++nt)
        acc[mt][nt] = __builtin_amdgcn_mfma_f32_16x16x32_bf16(a0[mt], b0[nt], acc[mt][nt], 0, 0, 0);

    bf16x8 a1[8], b1[4];
    #pragma unroll
    for (int mt = 0; mt < 8; ++mt) a1[mt] = *(const bf16x8*)&Ab[aoff + mt * 1024 + c1];
    #pragma unroll
    for (int nt = 0; nt < 4; ++nt) b1[nt] = *(const bf16x8*)&Bb[boff + nt * 1024 + c1];

    // all reads of buf[kt&1] done -> safe for everyone to overwrite it
    asm volatile("s_waitcnt lgkmcnt(0)" ::: "memory");
    __builtin_amdgcn_s_barrier();
    asm volatile("" ::: "memory");

    if (kt < 6) stage(kt + 2, kt & 1);

    #pragma unroll
    for (int mt = 0; mt < 8; ++mt)
      #pragma unroll
      for (int nt = 0; nt < 4; ++nt)
        acc[mt][nt] = __builtin_amdgcn_mfma_f32_16x16x32_bf16(a1[mt], b1[nt], acc[mt][nt], 0, 0, 0);
  }

  // ---- vectorized epilogue: per-wave 4 KiB LDS f32 transpose -> 8B stores ----
  float bv[4] = {0.f, 0.f, 0.f, 0.f};
  if (bias) {
    #pragma unroll
    for (int nt = 0; nt < 4; ++nt) bv[nt] = bf2f(bias[bn + wc * 64 + nt * 16 + rl]);
  }
  float* F = (float*)&lds[(size_t)w * 2048];   // [16][64] f32 per wave
  #pragma unroll
  for (int mt = 0; mt < 8; ++mt) {
    #pragma unroll
    for (int nt = 0; nt < 4; ++nt) {
      const int colw = (nt * 16 + rl) ^ ((rh & 1) << 4);
      #pragma unroll
      for (int reg = 0; reg < 4; ++reg)
        F[(rh * 4 + reg) * 64 + colw] = acc[mt][nt][reg] + bv[nt];
    }
    #pragma unroll
    for (int j = 0; j < 4; ++j) {
      const int row = rh + 4 * j;
      const int chunk = rl ^ ((j & 1) << 2);
      f32x4 vv = *(const f32x4*)&F[row * 64 + chunk * 4];
      u32 lo = (u32)f2bf(vv[0]) | ((u32)f2bf(vv[1]) << 16);
      u32 hi = (u32)f2bf(vv[2]) | ((u32)f2bf(vv[3]) << 16);
      const int gr = bm + wr * 128 + mt * 16 + row;
      if (gr < M) {
        uint2 pk; pk.x = lo; pk.y = hi;
        *(uint2*)&C[(size_t)gr * ldc + bn + wc * 64 + rl * 4] = pk;
      }
    }
  }
}

// ---- fused epilogue: wave-per-node, in-kernel edge softmax (no gat_edge kernel) ----
// pass1: CSR walk computing softmax denom from el/er; pass2: prefetched gather-FMA.
__global__ __launch_bounds__(256) void agg3_ln(const u16* __restrict__ fb,
                                               const int* __restrict__ src_r,
                                               const u32* __restrict__ ptr,
                                               const u32* __restrict__ eidx,
                                               const float* __restrict__ dors,
                                               const float* __restrict__ dirs,
                                               const float* __restrict__ el,
                                               const float* __restrict__ er,
                                               const u16* __restrict__ bc,  const u16* __restrict__ gc,  const u16* __restrict__ bec,
                                               const u16* __restrict__ bg,  const u16* __restrict__ gg,  const u16* __restrict__ beg,
                                               const u16* __restrict__ bs,  const u16* __restrict__ gs,  const u16* __restrict__ bes,
                                               u16* __restrict__ out) {
  const int l  = threadIdx.x & 63;
  const int d  = blockIdx.x * 4 + (threadIdx.x >> 6);
  const int c0 = l * 8;          // 8 cols, within one head (head = l>>3)
  const int hd = l >> 3;
  const float dird = dirs[d];
  const float erd = er[d * 8 + hd];
  const u32 p0 = ptr[d], p1 = ptr[d + 1];

  // pass 1: edge-softmax denominator (exp identical to old gat_edge; CSR-ordered sum)
  float sxv = 0.f;
  for (u32 i = p0; i < p1; ++i) {
    int s = src_r[eidx[i]];
    float v = el[s * 8 + hd] + erd;
    v = (v > 0.f) ? v : 0.2f * v;
    sxv += expf(fminf(v, 60.0f));
  }
  const float inv = (sxv > 0.f) ? 1.0f / sxv : 1.0f;

  float cv[8] = {0,0,0,0,0,0,0,0}, gv[8] = {0,0,0,0,0,0,0,0};
  if (p1 > p0) {
    // pass 2: software-pipelined gather (FP accumulation order identical to serial)
    int s = src_r[eidx[p0]];
    float sc = dors[s] * dird;
    float v0 = el[s * 8 + hd] + erd;
    v0 = (v0 > 0.f) ? v0 : 0.2f * v0;
    float wg = expf(fminf(v0, 60.0f)) * inv;
    const u16* xr = fb + (size_t)s * 1536 + c0;
    uint4 va = *(const uint4*)xr;
    uint4 vb = *(const uint4*)(xr + 512);
    for (u32 i = p0 + 1; i < p1; ++i) {
      int s2 = src_r[eidx[i]];
      float sc2 = dors[s2] * dird;
      float v2 = el[s2 * 8 + hd] + erd;
      v2 = (v2 > 0.f) ? v2 : 0.2f * v2;
      float wg2 = expf(fminf(v2, 60.0f)) * inv;
      const u16* xr2 = fb + (size_t)s2 * 1536 + c0;
      uint4 na = *(const uint4*)xr2;
      uint4 nb4 = *(const uint4*)(xr2 + 512);
      float a[8], b[8];
      unp8(va, a); unp8(vb, b);
      #pragma unroll
      for (int j = 0; j < 8; ++j) {
        cv[j] = fmaf(a[j], sc, cv[j]);
        gv[j] = fmaf(b[j], wg, gv[j]);
      }
      va = na; vb = nb4; sc = sc2; wg = wg2;
    }
    float a[8], b[8];
    unp8(va, a); unp8(vb, b);
    #pragma unroll
    for (int j = 0; j < 8; ++j) {
      cv[j] = fmaf(a[j], sc, cv[j]);
      gv[j] = fmaf(b[j], wg, gv[j]);
    }
  }
  float sv[8];
  ld8(fb + (size_t)d * 1536 + 1024 + c0, sv);
  float t8[8];
  ld8(bc + c0, t8);
  #pragma unroll
  for (int j = 0; j < 8; ++j) cv[j] += t8[j];
  ld8(bg + c0, t8);
  #pragma unroll
  for (int j = 0; j < 8; ++j) gv[j] += t8[j];
  ld8(bs + c0, t8);
  #pragma unroll
  for (int j = 0; j < 8; ++j) sv[j] += t8[j];

  float s;
  s = 0.f;
  #pragma unroll
  for (int j = 0; j < 8; ++j) s += cv[j];
  float mc = wsumb(s) * (1.0f / 512.0f);
  s = 0.f;
  #pragma unroll
  for (int j = 0; j < 8; ++j) { cv[j] -= mc; s += cv[j] * cv[j]; }
  float rc = rsqrtf(wsumb(s) * (1.0f / 512.0f) + 1e-12f);

  s = 0.f;
  #pragma unroll
  for (int j = 0; j < 8; ++j) s += gv[j];
  float mg = wsumb(s) * (1.0f / 512.0f);
  s = 0.f;
  #pragma unroll
  for (int j = 0; j < 8; ++j) { gv[j] -= mg; s += gv[j] * gv[j]; }
  float rg = rsqrtf(wsumb(s) * (1.0f / 512.0f) + 1e-12f);

  s = 0.f;
  #pragma unroll
  for (int j = 0; j < 8; ++j) s += sv[j];
  float ms = wsumb(s) * (1.0f / 512.0f);
  s = 0.f;
  #pragma unroll
  for (int j = 0; j < 8; ++j) { sv[j] -= ms; s += sv[j] * sv[j]; }
  float rs = rsqrtf(wsumb(s) * (1.0f / 512.0f) + 1e-12f);

  float o8[8];
  float ga[8], be8[8];
  ld8(gc + c0, ga); ld8(bec + c0, be8);
  #pragma unroll
  for (int j = 0; j < 8; ++j) {
    float y = ga[j] * cv[j] * rc + be8[j];
    o8[j] = (y > 0.f) ? y : expm1f(y);
  }
  ld8(gg + c0, ga); ld8(beg + c0, be8);
  #pragma unroll
  for (int j = 0; j < 8; ++j) {
    float y = ga[j] * gv[j] * rg + be8[j];
    o8[j] += (y > 0.f) ? y : expm1f(y);
  }
  ld8(gs + c0, ga); ld8(bes + c0, be8);
  #pragma unroll
  for (int j = 0; j < 8; ++j) {
    float y = ga[j] * sv[j] * rs + be8[j];
    o8[j] += (y > 0.f) ? y : expm1f(y);
  }
  uint4 o;
  u32 wpk[4];
  #pragma unroll
  for (int j = 0; j < 4; ++j)
    wpk[j] = (u32)f2bf(o8[2 * j]) | ((u32)f2bf(o8[2 * j + 1]) << 16);
  o.x = wpk[0]; o.y = wpk[1]; o.z = wpk[2]; o.w = wpk[3];
  *(uint4*)(out + (size_t)d * 1536 + c0) = o;
}

// ---------------- GAT el/er per node-head ----------------
__global__ __launch_bounds__(256) void gat_el_er(const u16* __restrict__ f, int fstride,
                                                 const u16* __restrict__ al,
                                                 const u16* __restrict__ ar,
                                                 float* __restrict__ el,
                                                 float* __restrict__ er) {
  int idx = blockIdx.x * blockDim.x + threadIdx.x;
  if (idx >= N_ * HEADS_) return;
  int n = idx >> 3, hd = idx & 7;
  const u16* fr = f + (size_t)n * fstride + hd * 64;
  const u16* alr = al + hd * 64;
  const u16* arr = ar + hd * 64;
  float a = 0.f, b = 0.f;
  for (int d0 = 0; d0 < 64; d0 += 8) {
    float fv[8], av[8], bv[8];
    ld8(fr + d0, fv); ld8(alr + d0, av); ld8(arr + d0, bv);
    #pragma unroll
    for (int j = 0; j < 8; ++j) {
      a = fmaf(fv[j], av[j], a);
      b = fmaf(fv[j], bv[j], b);
    }
  }
  el[idx] = a; er[idx] = b;
}

// ---- fused relation MHA, wave-per-node with coalesced LDS staging ----
// QKV[row=(n*3+r)][q|k|v 512 each]; wave loads node's 4608 u16 (9216B) fully
// coalesced via global_load_lds (per-wave private region, vmcnt-only sync).
// Lane l: head l>>3, dims (l&7)*8..+8. Scores reduced over 8-lane groups.
__global__ __launch_bounds__(256) void mha_fused(const u16* __restrict__ QKV,
                                                 u16* __restrict__ hout, int C) {
  __shared__ u16 buf[4 * 4608];        // 36864 B, per-wave 9216 B
  const int wv = threadIdx.x >> 6, l = threadIdx.x & 63;
  const int n = blockIdx.x * 4 + wv;
  if (n >= C) return;                  // wave-uniform
  u16* wbuf = &buf[wv * 4608];
  const u16* g = QKV + (size_t)n * 4608;

  // stage: 576 chunks of 8 u16; lane l takes chunk it*64+l -> LDS lane-contiguous
  #pragma unroll
  for (int it = 0; it < 9; ++it)
    gl_lds16(g + (size_t)(it * 64 + l) * 8, &wbuf[it * 512]);
  asm volatile("s_waitcnt vmcnt(0)" ::: "memory");

  // scores: q_r at r*1536 + l*8, k_r at r*1536+512 + l*8 (conflict-free ds_read_b128)
  float q[3][8], k[3][8];
  #pragma unroll
  for (int r = 0; r < 3; ++r) {
    ld8(&wbuf[r * 1536 + l * 8], q[r]);
    ld8(&wbuf[r * 1536 + 512 + l * 8], k[r]);
  }
  float sc[9];
  #pragma unroll
  for (int r = 0; r < 3; ++r)
    #pragma unroll
    for (int s2 = 0; s2 < 3; ++s2) {
      float a = 0.f;
      #pragma unroll
      for (int j = 0; j < 8; ++j) a = fmaf(q[r][j], k[s2][j], a);
      sc[r * 3 + s2] = a;
    }
  // reduce partial dots across the 8-lane group (lanes differ in bits 0..2)
  #pragma unroll
  for (int o = 1; o < 8; o <<= 1)
    #pragma unroll
    for (int i = 0; i < 9; ++i) sc[i] += __shfl_xor(sc[i], o, 64);

  float wp0 = 0.f, wp1 = 0.f, wp2 = 0.f;
  #pragma unroll
  for (int r = 0; r < 3; ++r) {
    float a = sc[r * 3 + 0] * 0.125f;
    float b = sc[r * 3 + 1] * 0.125f;
    float c = sc[r * 3 + 2] * 0.125f;
    float m = fmaxf(a, fmaxf(b, c));
    float ea = expf(a - m), eb = expf(b - m), ec = expf(c - m);
    float inv = 1.0f / (ea + eb + ec);
    wp0 += ea * inv; wp1 += eb * inv; wp2 += ec * inv;
  }
  wp0 *= (1.0f / 3.0f); wp1 *= (1.0f / 3.0f); wp2 *= (1.0f / 3.0f);

  float v0[8], v1[8], v2[8];
  ld8(&wbuf[1024 + l * 8], v0);
  ld8(&wbuf[1536 + 1024 + l * 8], v1);
  ld8(&wbuf[3072 + 1024 + l * 8], v2);
  uint4 o;
  u32 w4[4];
  #pragma unroll
  for (int j = 0; j < 4; ++j) {
    u16 lo = f2bf(wp0 * v0[2*j]   + wp1 * v1[2*j]   + wp2 * v2[2*j]);
    u16 hi = f2bf(wp0 * v0[2*j+1] + wp1 * v1[2*j+1] + wp2 * v2[2*j+1]);
    w4[j] = (u32)lo | ((u32)hi << 16);
  }
  o.x = w4[0]; o.y = w4[1]; o.z = w4[2]; o.w = w4[3];
  *(uint4*)(hout + (size_t)n * 512 + l * 8) = o;   // wave writes 1024B contiguous
}

// ---------------- classifier store: clsbuf[N,128] -> d_out[N,23] ----------------
__global__ __launch_bounds__(256) void cls_store(const u16* __restrict__ clsbuf,
                                                 void* __restrict__ out,
                                                 const int* __restrict__ flag) {
  int idx = blockIdx.x * blockDim.x + threadIdx.x;
  if (idx >= N_ * NCLS_) return;
  int n = idx / NCLS_, c = idx - n * NCLS_;
  float s = bf2f(clsbuf[(size_t)n * 128 + c]);
  if (!(s == s)) s = 12345.0f;   // NaN sentinel
  if (*flag) ((u16*)out)[idx] = f2bf(s);
  else       ((float*)out)[idx] = s;
}

static inline int cdiv(long long a, long long b) { return (int)((a + b - 1) / b); }

extern "C" void kernel_launch(void* const* d_in, const int* in_sizes, int n_in,
                              void* d_out, int out_size, void* d_ws, size_t ws_size,
                              hipStream_t stream) {
  // ---- workspace plan (bytes, 256-aligned) ----
  size_t off = 0;
  auto take = [&](size_t bytes) { size_t o = off; off += (bytes + 255) & ~(size_t)255; return o; };
  const size_t o_flag    = take(256);
  const size_t o_stacked = take((size_t)N_ * 1536 * 2);            // 153.6 MB bf16
  const size_t o_h       = take((size_t)N_ * 512 * 2);             //  51.2 MB (feature alias)
  const size_t o_trans   = take((size_t)N_ * 1536 * 2);            // 153.6 MB fbuf / qkv / clsbuf
  const size_t o_el    = take((size_t)N_ * HEADS_ * 4);
  const size_t o_er    = take((size_t)N_ * HEADS_ * 4);
  const size_t o_deg   = take((size_t)2 * R_ * N_ * 4);
  const size_t o_csrp  = take((size_t)R_ * (N_ + 1) * 4);
  const size_t o_eidx  = take((size_t)R_ * E_ * 4);
  const size_t o_fill  = take((size_t)R_ * N_ * 4);
  const size_t o_part  = take((size_t)R_ * SCNB_ * 4);             // scan partials
  const size_t o_wts   = take((size_t)6500000 * 2);                // staged bf16 weights
  const size_t need = off;

  if (ws_size < need) {
    write_const<<<cdiv(out_size, 256), 256, 0, stream>>>((u16*)d_out, out_size,
                                                         (float)(ws_size >> 20));
    return;
  }

  char* base = (char*)d_ws;
  int*   flag    = (int*)(base + o_flag);
  u16*   stacked = (u16*)(base + o_stacked);
  u16*   h       = (u16*)(base + o_h);
  u16*   fbuf    = (u16*)(base + o_trans);     // [N,1536] fused branch GEMM out
  u16*   qkv     = (u16*)(base + o_trans);     // [CHUNK*3,1536] (aliases, disjoint in time)
  u16*   clsbuf  = (u16*)(base + o_trans);     // [N,128]       (aliases, disjoint in time)
  float* el    = (float*)(base + o_el);
  float* er    = (float*)(base + o_er);
  float* degout = (float*)(base + o_deg);
  float* degin  = degout + (size_t)R_ * N_;
  u32*   csrp  = (u32*)(base + o_csrp);
  u32*   eidx  = (u32*)(base + o_eidx);
  u32*   fill  = (u32*)(base + o_fill);
  u32*   part  = (u32*)(base + o_part);

  const int* src = (const int*)d_in[1];
  const int* dst = (const int*)d_in[2];

  // ---- dtype probe ----
  detect_dtype<<<1, 256, 0, stream>>>(d_in[3], flag);

  // ---- staged weight layout (elements within o_wts) ----
  u16* wts   = (u16*)(base + o_wts);
  u16* wbrT  = wts;                              // [6][1536n][512k]: Wc | Wg | Wsk rows
  u16* wqkvT = wbrT + 6 * 786432;                // [2][1536n][512k] (q|k|v)
  u16* bqkv  = wqkvT + 2 * 786432;               // [2][1536]
  u16* wclsT = bqkv + 2 * 1536;                  // [128][512]
  u16* bcls  = wclsT + 128 * 512;                // [128]
  u16* prm   = bcls + 128;                       // 11 x [3072] small params

  stage_bf16<<<cdiv(N_ * 512, 256), 256, 0, stream>>>(d_in[0], 0, h, N_ * 512, flag);
  dim3 tb(32, 8);
  stageT<<<dim3(16, 16, 6), tb, 0, stream>>>(d_in[3],  0, 262144, wbrT,          786432, flag);
  stageT<<<dim3(16, 16, 6), tb, 0, stream>>>(d_in[7],  0, 262144, wbrT + 262144, 786432, flag);
  stageT<<<dim3(16, 16, 6), tb, 0, stream>>>(d_in[13], 0, 262144, wbrT + 524288, 786432, flag);
  stageT<<<dim3(16, 16, 2), tb, 0, stream>>>(d_in[17], 0, 262144, wqkvT,          786432, flag);
  stageT<<<dim3(16, 16, 2), tb, 0, stream>>>(d_in[19], 0, 262144, wqkvT + 262144, 786432, flag);
  stageT<<<dim3(16, 16, 2), tb, 0, stream>>>(d_in[21], 0, 262144, wqkvT + 524288, 786432, flag);
  stage_wclsT<<<cdiv(128 * 512, 256), 256, 0, stream>>>(d_in[23], wclsT, flag);
  stage_bcls<<<1, 128, 0, stream>>>(d_in[24], bcls, flag);
  stage_bqkv<<<cdiv(2 * 1536, 256), 256, 0, stream>>>(d_in[18], d_in[20], d_in[22], bqkv, flag);

  P11 p11;
  p11.p[0] = d_in[4];  p11.p[1] = d_in[5];  p11.p[2]  = d_in[6];
  p11.p[3] = d_in[8];  p11.p[4] = d_in[9];  p11.p[5]  = d_in[10];
  p11.p[6] = d_in[11]; p11.p[7] = d_in[12]; p11.p[8]  = d_in[14];
  p11.p[9] = d_in[15]; p11.p[10] = d_in[16];
  stage_p11<<<cdiv(11 * 3072, 256), 256, 0, stream>>>(p11, prm, flag);
  const u16 *bc  = prm,            *gc  = prm + 3072,  *bec = prm + 2 * 3072;
  const u16 *bg  = prm + 3 * 3072, *al  = prm + 4 * 3072, *ar = prm + 5 * 3072;
  const u16 *gg  = prm + 6 * 3072, *beg = prm + 7 * 3072;
  const u16 *bs  = prm + 8 * 3072, *gs  = prm + 9 * 3072, *bes = prm + 10 * 3072;

  // ---- degrees + CSR (parallel 3-phase scan) ----
  hipMemsetAsync(degout, 0, (size_t)2 * R_ * N_ * sizeof(float), stream);
  deg_count<<<cdiv((long long)R_ * E_, 256), 256, 0, stream>>>(src, dst, degout, degin);
  scan_blksum<<<dim3(SCNB_, R_), 256, 0, stream>>>(degin, part);
  scan_partials<<<R_, 64, 0, stream>>>(part, csrp);
  scan_write<<<dim3(SCNB_, R_), 256, 0, stream>>>(degin, part, csrp);
  deg_fin<<<cdiv((long long)2 * R_ * N_, 256), 256, 0, stream>>>(degout);
  hipMemsetAsync(fill, 0, (size_t)R_ * N_ * sizeof(u32), stream);
  csr_scatter<<<cdiv((long long)R_ * E_, 256), 256, 0, stream>>>(dst, csrp, fill, eidx);

  const int mbBR = cdiv(N_, 256);                    // 196 -> grid 1176
  const int mbQ  = cdiv((long long)CHUNK_ * 3, 256); // 147 -> grid 882
  const dim3 gridCLS(cdiv(N_, 128), 1);              // [50000,512] @ [512,128] (legacy kernel)

  for (int l = 0; l < 2; ++l) {
    for (int r = 0; r < 3; ++r) {
      int lr = l * 3 + r;
      const int* sr = src + r * E_;
      const u32* pr = csrp + (size_t)r * (N_ + 1);
      const u32* er_idx = eidx + (size_t)r * E_;
      // fused conv|gat|skip GEMM (256^2 pipelined, R3 structure)
      gemm256<<<mbBR * 6, 512, 0, stream>>>(h, wbrT + (size_t)lr * 786432, nullptr, fbuf, N_, 1536, 6);
      // GAT el/er per node-head (edge softmax is fused into agg3_ln)
      gat_el_er<<<cdiv(N_ * HEADS_, 256), 256, 0, stream>>>(fbuf + 512, 1536,
                                                            al + lr * 512, ar + lr * 512,
                                                            el, er);
      // fused edge-softmax + CSR aggregation + 3x LN+ELU + sum -> stacked[:,r,:]
      agg3_ln<<<cdiv(N_, 4), 256, 0, stream>>>(fbuf, sr, pr, er_idx,
                                               degout + r * N_, degin + r * N_, el, er,
                                               bc + lr * 512, gc + lr * 512, bec + lr * 512,
                                               bg + lr * 512, gg + lr * 512, beg + lr * 512,
                                               bs + lr * 512, gs + lr * 512, bes + lr * 512,
                                               stacked + r * 512);
    }
    // fused QKV + relation MHA (chunked; qkv aliases fbuf region)
    for (int c = 0; c < N_ / CHUNK_; ++c) {
      gemm256<<<mbQ * 6, 512, 0, stream>>>(stacked + (size_t)c * CHUNK_ * 1536,
                                           wqkvT + (size_t)l * 786432, bqkv + l * 1536,
                                           qkv, CHUNK_ * 3, 1536, 6);
      mha_fused<<<cdiv(CHUNK_, 4), 256, 0, stream>>>(qkv, h + (size_t)c * CHUNK_ * 512,
                                                     CHUNK_);
    }
  }
  // classifier: MFMA GEMM into padded [N,128] + store
  gemm_mfma<<<gridCLS, 256, 0, stream>>>(h, wclsT, bcls, clsbuf, N_, 128);
  cls_store<<<cdiv((long long)N_ * NCLS_, 256), 256, 0, stream>>>(clsbuf, d_out, flag);
}

// Round 9
// 2491.499 us; speedup vs baseline: 1.3296x; 1.0036x over previous
//
#include <hip/hip_runtime.h>

#define N_     50000
#define E_     150000
#define R_     3
#define H_     512
#define HEADS_ 8
#define DH_    64
#define NCLS_  23
#define CHUNK_ 12500   // nodes per QKV/MHA chunk (N_/4)
#define SCNB_  49      // ceil(N_/1024) scan blocks per relation

typedef unsigned short u16;
typedef unsigned int   u32;
typedef __attribute__((ext_vector_type(8))) short bf16x8;
typedef __attribute__((ext_vector_type(4))) float f32x4;

__device__ __forceinline__ float bf2f(u16 u) {
  union { u32 i; float f; } v; v.i = ((u32)u) << 16; return v.f;
}
__device__ __forceinline__ u16 f2bf(float f) {
  u32 u = __float_as_uint(f);
  u += 0x7fffu + ((u >> 16) & 1u);   // round-to-nearest-even
  return (u16)(u >> 16);
}

__device__ __forceinline__ void unp8(uint4 v, float o[8]) {
  o[0] = bf2f((u16)(v.x & 0xffff)); o[1] = bf2f((u16)(v.x >> 16));
  o[2] = bf2f((u16)(v.y & 0xffff)); o[3] = bf2f((u16)(v.y >> 16));
  o[4] = bf2f((u16)(v.z & 0xffff)); o[5] = bf2f((u16)(v.z >> 16));
  o[6] = bf2f((u16)(v.w & 0xffff)); o[7] = bf2f((u16)(v.w >> 16));
}
// 8 bf16 -> 8 fp32 via one 16B load
__device__ __forceinline__ void ld8(const u16* __restrict__ p, float o[8]) {
  unp8(*(const uint4*)p, o);
}

// wave-wide sum, result broadcast to all 64 lanes
__device__ __forceinline__ float wsumb(float v) {
  #pragma unroll
  for (int o = 32; o > 0; o >>= 1) v += __shfl_down(v, o, 64);
  return __shfl(v, 0, 64);
}

// async global->LDS, 16B per lane
__device__ __forceinline__ void gl_lds16(const u16* g, u16* l) {
  __builtin_amdgcn_global_load_lds(
      (const __attribute__((address_space(1))) unsigned int*)g,
      (__attribute__((address_space(3))) unsigned int*)l, 16, 0, 0);
}

// ---------------- ws-size probe fallback ----------------
__global__ __launch_bounds__(256) void write_const(u16* __restrict__ out, int n, float v) {
  int i = blockIdx.x * blockDim.x + threadIdx.x;
  if (i < n) out[i] = f2bf(v);
}

// ---------------- dtype probe ----------------
__global__ void detect_dtype(const void* __restrict__ wc, int* __restrict__ flag) {
  __shared__ int cnt;
  if (threadIdx.x == 0) cnt = 0;
  __syncthreads();
  const u16* p = (const u16*)wc;
  int ok = 0;
  for (int i = threadIdx.x; i < 2048; i += 256) {
    float a = fabsf(bf2f(p[i]));
    if (a <= 4.0f) ok++;
  }
  atomicAdd(&cnt, ok);
  __syncthreads();
  if (threadIdx.x == 0) *flag = (cnt >= 2000) ? 1 : 0;   // 1=bf16, 0=fp32
}

// stage float tensor -> bf16 ws
__global__ __launch_bounds__(256) void stage_bf16(const void* __restrict__ in, size_t off,
                                                  u16* __restrict__ out, int n,
                                                  const int* __restrict__ flag) {
  int i = blockIdx.x * blockDim.x + threadIdx.x;
  if (i >= n) return;
  out[i] = (*flag) ? ((const u16*)in)[off + i] : f2bf(((const float*)in)[off + i]);
}

// batched staging of the 11 small [3072] parameter tensors in one dispatch
struct P11 { const void* p[11]; };
__global__ __launch_bounds__(256) void stage_p11(P11 srcs, u16* __restrict__ out,
                                                 const int* __restrict__ flag) {
  int idx = blockIdx.x * blockDim.x + threadIdx.x;
  if (idx >= 11 * 3072) return;
  int ti = idx / 3072, off = idx - ti * 3072;
  const void* in = srcs.p[ti];
  out[idx] = (*flag) ? ((const u16*)in)[off] : f2bf(((const float*)in)[off]);
}

// bqkv: out[l][q|k|v] (2x1536) from 3 tensors of [2][512]
__global__ __launch_bounds__(256) void stage_bqkv(const void* __restrict__ q,
                                                  const void* __restrict__ k,
                                                  const void* __restrict__ v,
                                                  u16* __restrict__ out,
                                                  const int* __restrict__ flag) {
  int idx = blockIdx.x * blockDim.x + threadIdx.x;
  if (idx >= 2 * 1536) return;
  int l = idx / 1536, c = idx - l * 1536;
  const void* in = (c < 512) ? q : (c < 1024) ? k : v;
  int off = l * 512 + (c & 511);
  out[idx] = (*flag) ? ((const u16*)in)[off] : f2bf(((const float*)in)[off]);
}

// stage 512x512 weight slices TRANSPOSED: out[n][k] = in[k][n]; grid.z = matrix idx
__global__ __launch_bounds__(256) void stageT(const void* __restrict__ in, size_t in_off,
                                              size_t in_mstride, u16* __restrict__ out,
                                              size_t out_mstride, const int* __restrict__ flag) {
  __shared__ u16 tile[32][33];
  const int m = blockIdx.z;
  const size_t ib = in_off + (size_t)m * in_mstride;
  const size_t ob = (size_t)m * out_mstride;
  const int kb = blockIdx.x * 32, nb = blockIdx.y * 32;
  const int tx = threadIdx.x, ty = threadIdx.y;
  const bool isbf = (*flag != 0);
  #pragma unroll
  for (int i = 0; i < 32; i += 8) {
    size_t si = ib + (size_t)(kb + ty + i) * 512 + nb + tx;
    tile[ty + i][tx] = isbf ? ((const u16*)in)[si] : f2bf(((const float*)in)[si]);
  }
  __syncthreads();
  #pragma unroll
  for (int i = 0; i < 32; i += 8)
    out[ob + (size_t)(nb + ty + i) * 512 + kb + tx] = tile[tx][ty + i];
}

// stage Wout transposed + zero-padded to [128][512]
__global__ __launch_bounds__(256) void stage_wclsT(const void* __restrict__ in,
                                                   u16* __restrict__ out,
                                                   const int* __restrict__ flag) {
  int i = blockIdx.x * blockDim.x + threadIdx.x;
  if (i >= 128 * 512) return;
  int c = i >> 9, k = i & 511;
  u16 v = 0;
  if (c < NCLS_) {
    size_t si = (size_t)k * NCLS_ + c;
    v = (*flag) ? ((const u16*)in)[si] : f2bf(((const float*)in)[si]);
  }
  out[i] = v;
}
__global__ void stage_bcls(const void* __restrict__ in, u16* __restrict__ out,
                           const int* __restrict__ flag) {
  int i = threadIdx.x;
  if (i >= 128) return;
  u16 v = 0;
  if (i < NCLS_) v = (*flag) ? ((const u16*)in)[i] : f2bf(((const float*)in)[i]);
  out[i] = v;
}

// ---------------- degrees ----------------
__global__ __launch_bounds__(256) void deg_count(const int* __restrict__ src,
                                                 const int* __restrict__ dst,
                                                 float* __restrict__ degout,
                                                 float* __restrict__ degin) {
  int idx = blockIdx.x * blockDim.x + threadIdx.x;
  if (idx >= R_ * E_) return;
  int r = idx / E_;
  atomicAdd(&degout[r * N_ + src[idx]], 1.0f);
  atomicAdd(&degin [r * N_ + dst[idx]], 1.0f);
}
__global__ __launch_bounds__(256) void deg_fin(float* __restrict__ deg) {
  int idx = blockIdx.x * blockDim.x + threadIdx.x;
  if (idx >= 2 * R_ * N_) return;
  deg[idx] = rsqrtf(fmaxf(deg[idx], 1.0f));
}

// ---------------- CSR build: parallel 3-phase exclusive scan ----------------
__global__ __launch_bounds__(256) void scan_blksum(const float* __restrict__ cnt,
                                                   u32* __restrict__ partial) {
  const int r = blockIdx.y, b = blockIdx.x;
  const int base = b * 1024;
  const float* c = cnt + (size_t)r * N_;
  const int t = threadIdx.x;
  u32 s = 0;
  #pragma unroll
  for (int k = 0; k < 4; ++k) {
    int i = base + t * 4 + k;
    if (i < N_) s += (u32)c[i];
  }
  #pragma unroll
  for (int o = 32; o > 0; o >>= 1) s += __shfl_down(s, o, 64);
  __shared__ u32 ws[4];
  if ((t & 63) == 0) ws[t >> 6] = s;
  __syncthreads();
  if (t == 0) partial[r * SCNB_ + b] = ws[0] + ws[1] + ws[2] + ws[3];
}

__global__ void scan_partials(u32* __restrict__ partial, u32* __restrict__ ptr) {
  const int r = blockIdx.x;
  u32* p = partial + r * SCNB_;
  const int l = threadIdx.x;           // 64 threads = 1 wave
  u32 v = (l < SCNB_) ? p[l] : 0u;
  u32 s = v;
  #pragma unroll
  for (int o = 1; o < 64; o <<= 1) {
    u32 n = __shfl_up(s, o, 64);
    if (l >= o) s += n;
  }
  if (l < SCNB_) p[l] = s - v;         // exclusive
  if (l == 63) ptr[(size_t)r * (N_ + 1) + N_] = s;   // grand total
}

__global__ __launch_bounds__(256) void scan_write(const float* __restrict__ cnt,
                                                  const u32* __restrict__ partial,
                                                  u32* __restrict__ ptr) {
  const int r = blockIdx.y, b = blockIdx.x;
  const int base = b * 1024;
  const float* c = cnt + (size_t)r * N_;
  u32* p = ptr + (size_t)r * (N_ + 1);
  const int t = threadIdx.x, lane = t & 63, w = t >> 6;
  u32 v[4]; u32 ts = 0;
  #pragma unroll
  for (int k = 0; k < 4; ++k) {
    int i = base + t * 4 + k;
    v[k] = (i < N_) ? (u32)c[i] : 0u;
    ts += v[k];
  }
  u32 s = ts;
  #pragma unroll
  for (int o = 1; o < 64; o <<= 1) {
    u32 n = __shfl_up(s, o, 64);
    if (lane >= o) s += n;
  }
  __shared__ u32 ws[4];
  if (lane == 63) ws[w] = s;
  __syncthreads();
  u32 off = partial[r * SCNB_ + b];
  for (int k = 0; k < w; ++k) off += ws[k];
  off += s - ts;                        // exclusive offset of this thread
  u32 run = 0;
  #pragma unroll
  for (int k = 0; k < 4; ++k) {
    int i = base + t * 4 + k;
    if (i < N_) p[i] = off + run;
    run += v[k];
  }
}

// scatter: store SOURCE NODE ID in CSR order (agg3 needs src, not edge id)
__global__ __launch_bounds__(256) void csr_scatter(const int* __restrict__ src,
                                                   const int* __restrict__ dst,
                                                   const u32* __restrict__ ptr,
                                                   u32* __restrict__ fill,
                                                   u32* __restrict__ eidx) {
  int idx = blockIdx.x * blockDim.x + threadIdx.x;
  if (idx >= R_ * E_) return;
  int r = idx / E_;
  int d = dst[idx];
  u32 pos = ptr[(size_t)r * (N_ + 1) + d] + atomicAdd(&fill[(size_t)r * N_ + d], 1u);
  eidx[(size_t)r * E_ + pos] = (u32)src[idx];
}

// ---- legacy 128x128 MFMA GEMM (kept for the small classifier GEMM) ----
__global__ __launch_bounds__(256, 2) void gemm_mfma(const u16* __restrict__ A,
                                                    const u16* __restrict__ BT,
                                                    const u16* __restrict__ bias,
                                                    u16* __restrict__ C,
                                                    int M, int ldc) {
  __shared__ u16 As[128 * 32];
  __shared__ u16 Bs[128 * 32];
  const int t = threadIdx.x;
  const int w = t >> 6, l = t & 63;
  const int bm = blockIdx.x * 128, bn = blockIdx.y * 128;
  const int wm = (w & 1) * 64, wn = (w >> 1) * 64;
  const int srow = w * 16 + (l >> 2);
  const int scol = (l & 3) * 8;
  f32x4 acc[4][4] = {};

  for (int k0 = 0; k0 < 512; k0 += 32) {
    #pragma unroll
    for (int p = 0; p < 2; ++p) {
      gl_lds16(A  + (size_t)(bm + p * 64 + srow) * 512 + k0 + scol, &As[(p * 64 + w * 16) * 32]);
      gl_lds16(BT + (size_t)(bn + p * 64 + srow) * 512 + k0 + scol, &Bs[(p * 64 + w * 16) * 32]);
    }
    __syncthreads();
    bf16x8 af[4], bfr[4];
    #pragma unroll
    for (int i = 0; i < 4; ++i) {
      af[i]  = *(const bf16x8*)&As[(wm + i * 16 + (l & 15)) * 32 + (l >> 4) * 8];
      bfr[i] = *(const bf16x8*)&Bs[(wn + i * 16 + (l & 15)) * 32 + (l >> 4) * 8];
    }
    #pragma unroll
    for (int mi = 0; mi < 4; ++mi)
      #pragma unroll
      for (int ni = 0; ni < 4; ++ni)
        acc[mi][ni] = __builtin_amdgcn_mfma_f32_16x16x32_bf16(af[mi], bfr[ni], acc[mi][ni], 0, 0, 0);
    __syncthreads();
  }

  float bv[4] = {0.f, 0.f, 0.f, 0.f};
  if (bias) {
    #pragma unroll
    for (int ni = 0; ni < 4; ++ni) bv[ni] = bf2f(bias[bn + wn + ni * 16 + (l & 15)]);
  }
  const int col0 = bn + wn + (l & 15);
  #pragma unroll
  for (int mi = 0; mi < 4; ++mi) {
    #pragma unroll
    for (int reg = 0; reg < 4; ++reg) {
      int gr = bm + wm + mi * 16 + (l >> 4) * 4 + reg;
      if (gr < M) {
        size_t rb = (size_t)gr * ldc;
        #pragma unroll
        for (int ni = 0; ni < 4; ++ni)
          C[rb + col0 + ni * 16] = f2bf(acc[mi][ni][reg] + bv[ni]);
      }
    }
  }
}

// ---- 256x256 MFMA GEMM, 2-phase counted-vmcnt dbuf + LDS XOR-swizzle (R3, 114 us) ----
// A[M,512] @ BT[Nn,512]^T -> C[M,ldc]; K=512 (8 K-tiles of 64).
// 8 waves (2Mx4N), per-wave C = 128x64. LDS 128 KiB: 2 bufs x (A 256x64 | B 256x64) bf16.
// Swizzle: 16B-chunk index ^= (row & 7), applied on gload SOURCE and ds_read (involution).
__global__ __launch_bounds__(512, 2) void gemm256(const u16* __restrict__ A,
                                                  const u16* __restrict__ BT,
                                                  const u16* __restrict__ bias,
                                                  u16* __restrict__ C,
                                                  int M, int ldc, int nb) {
  __shared__ u16 lds[65536];           // 128 KiB
  const int t = threadIdx.x;
  const int w = t >> 6, l = t & 63;
  const int wr = w >> 2, wc = w & 3;

  // XCD-bijective swizzle (m204), bn-fastest so one XCD walks a bm-panel across all bn
  const int nwg = gridDim.x;
  const int q = nwg >> 3, r = nwg & 7;
  const int xcd = blockIdx.x & 7, loc = blockIdx.x >> 3;
  const int wg = (xcd < r ? xcd * (q + 1) : r * (q + 1) + (xcd - r) * q) + loc;
  const int bn = (wg % nb) * 256;
  const int bm = (wg / nb) * 256;

  // staging addresses: lane l covers row w*8+(l>>3) (+i*64), swizzled source chunk
  const int lrow = l >> 3, lc8 = l & 7;
  const int csrc = ((lc8 ^ lrow) << 3);                 // element offset in 64-col K-tile
  const u16* Ag = A  + (size_t)(bm + w * 8 + lrow) * 512 + csrc;
  const u16* Bg = BT + (size_t)(bn + w * 8 + lrow) * 512 + csrc;

  auto stage = [&](int kt, int buf) {
    const size_t ko = (size_t)kt * 64;
    #pragma unroll
    for (int i = 0; i < 4; ++i)
      gl_lds16(Ag + (size_t)(i * 64) * 512 + ko, &lds[buf * 32768 + i * 4096 + w * 512]);
    #pragma unroll
    for (int i = 0; i < 4; ++i)
      gl_lds16(Bg + (size_t)(i * 64) * 512 + ko, &lds[buf * 32768 + 16384 + i * 4096 + w * 512]);
  };

  // fragment-read offsets (u16 units), with matching XOR swizzle
  const int rl = l & 15, rh = l >> 4;                   // rh in 0..3
  const int key = l & 7;                                // row_local & 7
  const int aoff = (wr * 128 + rl) * 64;
  const int boff = (wc * 64  + rl) * 64;
  const int c0 = ((rh)     ^ key) << 3;                 // kk=0 chunk
  const int c1 = ((4 + rh) ^ key) << 3;                 // kk=1 chunk

  f32x4 acc[8][4] = {};

  stage(0, 0);
  stage(1, 1);

  #pragma unroll
  for (int kt = 0; kt < 8; ++kt) {
    // tile kt fully resident after this wait (per-wave 8 loads/tile, 2 tiles in flight)
    if (kt == 7) asm volatile("s_waitcnt vmcnt(0)" ::: "memory");
    else         asm volatile("s_waitcnt vmcnt(8)" ::: "memory");
    __builtin_amdgcn_s_barrier();
    asm volatile("" ::: "memory");

    const u16* Ab = &lds[(kt & 1) * 32768];
    const u16* Bb = Ab + 16384;

    bf16x8 a0[8], b0[4];
    #pragma unroll
    for (int mt = 0; mt < 8; ++mt) a0[mt] = *(const bf16x8*)&Ab[aoff + mt * 1024 + c0];
    #pragma unroll
    for (int nt = 0; nt < 4; ++nt) b0[nt] = *(const bf16x8*)&Bb[boff + nt * 1024 + c0];

    #pragma unroll
    for (int mt = 0; mt < 8; ++mt)
      #pragma unroll
      for (int nt = 0; nt < 4; ++nt)
        acc[mt][nt] = __builtin_amdgcn_mfma_f32_16x16x32_bf16(a0[mt], b0[nt], acc[mt][nt], 0, 0, 0);

    bf16x8 a1[8], b1[4];
    #pragma unroll
    for (int mt = 0; mt < 8; ++mt) a1[mt] = *(const bf16x8*)&Ab[aoff + mt * 1024 + c1];
    #pragma unroll
    for (int nt = 0; nt < 4; ++nt) b1[nt] = *(const bf16x8*)&Bb[boff + nt * 1024 + c1];

    // all reads of buf[kt&1] done -> safe for everyone to overwrite it
    asm volatile("s_waitcnt lgkmcnt(0)" ::: "memory");
    __builtin_amdgcn_s_barrier();
    asm volatile("" ::: "memory");

    if (kt < 6) stage(kt + 2, kt & 1);

    #pragma unroll
    for (int mt = 0; mt < 8; ++mt)
      #pragma unroll
      for (int nt = 0; nt < 4; ++nt)
        acc[mt][nt] = __builtin_amdgcn_mfma_f32_16x16x32_bf16(a1[mt], b1[nt], acc[mt][nt], 0, 0, 0);
  }

  // ---- vectorized epilogue: per-wave 4 KiB LDS f32 transpose -> 8B stores ----
  float bv[4] = {0.f, 0.f, 0.f, 0.f};
  if (bias) {
    #pragma unroll
    for (int nt = 0; nt < 4; ++nt) bv[nt] = bf2f(bias[bn + wc * 64 + nt * 16 + rl]);
  }
  float* F = (float*)&lds[(size_t)w * 2048];   // [16][64] f32 per wave
  #pragma unroll
  for (int mt = 0; mt < 8; ++mt) {
    #pragma unroll
    for (int nt = 0; nt < 4; ++nt) {
      const int colw = (nt * 16 + rl) ^ ((rh & 1) << 4);
      #pragma unroll
      for (int reg = 0; reg < 4; ++reg)
        F[(rh * 4 + reg) * 64 + colw] = acc[mt][nt][reg] + bv[nt];
    }
    #pragma unroll
    for (int j = 0; j < 4; ++j) {
      const int row = rh + 4 * j;
      const int chunk = rl ^ ((j & 1) << 2);
      f32x4 vv = *(const f32x4*)&F[row * 64 + chunk * 4];
      u32 lo = (u32)f2bf(vv[0]) | ((u32)f2bf(vv[1]) << 16);
      u32 hi = (u32)f2bf(vv[2]) | ((u32)f2bf(vv[3]) << 16);
      const int gr = bm + wr * 128 + mt * 16 + row;
      if (gr < M) {
        uint2 pk; pk.x = lo; pk.y = hi;
        *(uint2*)&C[(size_t)gr * ldc + bn + wc * 64 + rl * 4] = pk;
      }
    }
  }
}

// ---- fused epilogue: wave-per-node, in-kernel edge softmax ----
// eidx holds SOURCE NODE IDS in CSR order (one fewer dependent load/edge).
__global__ __launch_bounds__(256) void agg3_ln(const u16* __restrict__ fb,
                                               const u32* __restrict__ ptr,
                                               const u32* __restrict__ eidx,
                                               const float* __restrict__ dors,
                                               const float* __restrict__ dirs,
                                               const float* __restrict__ el,
                                               const float* __restrict__ er,
                                               const u16* __restrict__ bc,  const u16* __restrict__ gc,  const u16* __restrict__ bec,
                                               const u16* __restrict__ bg,  const u16* __restrict__ gg,  const u16* __restrict__ beg,
                                               const u16* __restrict__ bs,  const u16* __restrict__ gs,  const u16* __restrict__ bes,
                                               u16* __restrict__ out) {
  const int l  = threadIdx.x & 63;
  const int d  = blockIdx.x * 4 + (threadIdx.x >> 6);
  const int c0 = l * 8;          // 8 cols, within one head (head = l>>3)
  const int hd = l >> 3;
  const float dird = dirs[d];
  const float erd = er[d * 8 + hd];
  const u32 p0 = ptr[d], p1 = ptr[d + 1];

  // pass 1: edge-softmax denominator (exp identical to old gat_edge; CSR-ordered sum)
  float sxv = 0.f;
  for (u32 i = p0; i < p1; ++i) {
    int s = (int)eidx[i];
    float v = el[s * 8 + hd] + erd;
    v = (v > 0.f) ? v : 0.2f * v;
    sxv += expf(fminf(v, 60.0f));
  }
  const float inv = (sxv > 0.f) ? 1.0f / sxv : 1.0f;

  float cv[8] = {0,0,0,0,0,0,0,0}, gv[8] = {0,0,0,0,0,0,0,0};
  if (p1 > p0) {
    // pass 2: software-pipelined gather (FP accumulation order identical to serial)
    int s = (int)eidx[p0];
    float sc = dors[s] * dird;
    float v0 = el[s * 8 + hd] + erd;
    v0 = (v0 > 0.f) ? v0 : 0.2f * v0;
    float wg = expf(fminf(v0, 60.0f)) * inv;
    const u16* xr = fb + (size_t)s * 1536 + c0;
    uint4 va = *(const uint4*)xr;
    uint4 vb = *(const uint4*)(xr + 512);
    for (u32 i = p0 + 1; i < p1; ++i) {
      int s2 = (int)eidx[i];
      float sc2 = dors[s2] * dird;
      float v2 = el[s2 * 8 + hd] + erd;
      v2 = (v2 > 0.f) ? v2 : 0.2f * v2;
      float wg2 = expf(fminf(v2, 60.0f)) * inv;
      const u16* xr2 = fb + (size_t)s2 * 1536 + c0;
      uint4 na = *(const uint4*)xr2;
      uint4 nb4 = *(const uint4*)(xr2 + 512);
      float a[8], b[8];
      unp8(va, a); unp8(vb, b);
      #pragma unroll
      for (int j = 0; j < 8; ++j) {
        cv[j] = fmaf(a[j], sc, cv[j]);
        gv[j] = fmaf(b[j], wg, gv[j]);
      }
      va = na; vb = nb4; sc = sc2; wg = wg2;
    }
    float a[8], b[8];
    unp8(va, a); unp8(vb, b);
    #pragma unroll
    for (int j = 0; j < 8; ++j) {
      cv[j] = fmaf(a[j], sc, cv[j]);
      gv[j] = fmaf(b[j], wg, gv[j]);
    }
  }
  float sv[8];
  ld8(fb + (size_t)d * 1536 + 1024 + c0, sv);
  float t8[8];
  ld8(bc + c0, t8);
  #pragma unroll
  for (int j = 0; j < 8; ++j) cv[j] += t8[j];
  ld8(bg + c0, t8);
  #pragma unroll
  for (int j = 0; j < 8; ++j) gv[j] += t8[j];
  ld8(bs + c0, t8);
  #pragma unroll
  for (int j = 0; j < 8; ++j) sv[j] += t8[j];

  float s;
  s = 0.f;
  #pragma unroll
  for (int j = 0; j < 8; ++j) s += cv[j];
  float mc = wsumb(s) * (1.0f / 512.0f);
  s = 0.f;
  #pragma unroll
  for (int j = 0; j < 8; ++j) { cv[j] -= mc; s += cv[j] * cv[j]; }
  float rc = rsqrtf(wsumb(s) * (1.0f / 512.0f) + 1e-12f);

  s = 0.f;
  #pragma unroll
  for (int j = 0; j < 8; ++j) s += gv[j];
  float mg = wsumb(s) * (1.0f / 512.0f);
  s = 0.f;
  #pragma unroll
  for (int j = 0; j < 8; ++j) { gv[j] -= mg; s += gv[j] * gv[j]; }
  float rg = rsqrtf(wsumb(s) * (1.0f / 512.0f) + 1e-12f);

  s = 0.f;
  #pragma unroll
  for (int j = 0; j < 8; ++j) s += sv[j];
  float ms = wsumb(s) * (1.0f / 512.0f);
  s = 0.f;
  #pragma unroll
  for (int j = 0; j < 8; ++j) { sv[j] -= ms; s += sv[j] * sv[j]; }
  float rs = rsqrtf(wsumb(s) * (1.0f / 512.0f) + 1e-12f);

  float o8[8];
  float ga[8], be8[8];
  ld8(gc + c0, ga); ld8(bec + c0, be8);
  #pragma unroll
  for (int j = 0; j < 8; ++j) {
    float y = ga[j] * cv[j] * rc + be8[j];
    o8[j] = (y > 0.f) ? y : expm1f(y);
  }
  ld8(gg + c0, ga); ld8(beg + c0, be8);
  #pragma unroll
  for (int j = 0; j < 8; ++j) {
    float y = ga[j] * gv[j] * rg + be8[j];
    o8[j] += (y > 0.f) ? y : expm1f(y);
  }
  ld8(gs + c0, ga); ld8(bes + c0, be8);
  #pragma unroll
  for (int j = 0; j < 8; ++j) {
    float y = ga[j] * sv[j] * rs + be8[j];
    o8[j] += (y > 0.f) ? y : expm1f(y);
  }
  uint4 o;
  u32 wpk[4];
  #pragma unroll
  for (int j = 0; j < 4; ++j)
    wpk[j] = (u32)f2bf(o8[2 * j]) | ((u32)f2bf(o8[2 * j + 1]) << 16);
  o.x = wpk[0]; o.y = wpk[1]; o.z = wpk[2]; o.w = wpk[3];
  *(uint4*)(out + (size_t)d * 1536 + c0) = o;
}

// ---------------- GAT el/er per node-head ----------------
__global__ __launch_bounds__(256) void gat_el_er(const u16* __restrict__ f, int fstride,
                                                 const u16* __restrict__ al,
                                                 const u16* __restrict__ ar,
                                                 float* __restrict__ el,
                                                 float* __restrict__ er) {
  int idx = blockIdx.x * blockDim.x + threadIdx.x;
  if (idx >= N_ * HEADS_) return;
  int n = idx >> 3, hd = idx & 7;
  const u16* fr = f + (size_t)n * fstride + hd * 64;
  const u16* alr = al + hd * 64;
  const u16* arr = ar + hd * 64;
  float a = 0.f, b = 0.f;
  for (int d0 = 0; d0 < 64; d0 += 8) {
    float fv[8], av[8], bv[8];
    ld8(fr + d0, fv); ld8(alr + d0, av); ld8(arr + d0, bv);
    #pragma unroll
    for (int j = 0; j < 8; ++j) {
      a = fmaf(fv[j], av[j], a);
      b = fmaf(fv[j], bv[j], b);
    }
  }
  el[idx] = a; er[idx] = b;
}

// ---- fused relation MHA, wave-per-node with coalesced LDS staging (R7) ----
// QKV[row=(n*3+r)][q|k|v 512 each]; wave loads node's 4608 u16 (9216B) fully
// coalesced via global_load_lds (per-wave private region, vmcnt-only sync).
// Lane l: head l>>3, dims (l&7)*8..+8. Scores reduced over 8-lane groups.
__global__ __launch_bounds__(256) void mha_fused(const u16* __restrict__ QKV,
                                                 u16* __restrict__ hout, int C) {
  __shared__ u16 buf[4 * 4608];        // 36864 B, per-wave 9216 B
  const int wv = threadIdx.x >> 6, l = threadIdx.x & 63;
  const int n = blockIdx.x * 4 + wv;
  if (n >= C) return;                  // wave-uniform
  u16* wbuf = &buf[wv * 4608];
  const u16* g = QKV + (size_t)n * 4608;

  // stage: 576 chunks of 8 u16; lane l takes chunk it*64+l -> LDS lane-contiguous
  #pragma unroll
  for (int it = 0; it < 9; ++it)
    gl_lds16(g + (size_t)(it * 64 + l) * 8, &wbuf[it * 512]);
  asm volatile("s_waitcnt vmcnt(0)" ::: "memory");

  // scores: q_r at r*1536 + l*8, k_r at r*1536+512 + l*8 (conflict-free ds_read_b128)
  float q[3][8], k[3][8];
  #pragma unroll
  for (int r = 0; r < 3; ++r) {
    ld8(&wbuf[r * 1536 + l * 8], q[r]);
    ld8(&wbuf[r * 1536 + 512 + l * 8], k[r]);
  }
  float sc[9];
  #pragma unroll
  for (int r = 0; r < 3; ++r)
    #pragma unroll
    for (int s2 = 0; s2 < 3; ++s2) {
      float a = 0.f;
      #pragma unroll
      for (int j = 0; j < 8; ++j) a = fmaf(q[r][j], k[s2][j], a);
      sc[r * 3 + s2] = a;
    }
  // reduce partial dots across the 8-lane group (lanes differ in bits 0..2)
  #pragma unroll
  for (int o = 1; o < 8; o <<= 1)
    #pragma unroll
    for (int i = 0; i < 9; ++i) sc[i] += __shfl_xor(sc[i], o, 64);

  float wp0 = 0.f, wp1 = 0.f, wp2 = 0.f;
  #pragma unroll
  for (int r = 0; r < 3; ++r) {
    float a = sc[r * 3 + 0] * 0.125f;
    float b = sc[r * 3 + 1] * 0.125f;
    float c = sc[r * 3 + 2] * 0.125f;
    float m = fmaxf(a, fmaxf(b, c));
    float ea = expf(a - m), eb = expf(b - m), ec = expf(c - m);
    float inv = 1.0f / (ea + eb + ec);
    wp0 += ea * inv; wp1 += eb * inv; wp2 += ec * inv;
  }
  wp0 *= (1.0f / 3.0f); wp1 *= (1.0f / 3.0f); wp2 *= (1.0f / 3.0f);

  float v0[8], v1[8], v2[8];
  ld8(&wbuf[1024 + l * 8], v0);
  ld8(&wbuf[1536 + 1024 + l * 8], v1);
  ld8(&wbuf[3072 + 1024 + l * 8], v2);
  uint4 o;
  u32 w4[4];
  #pragma unroll
  for (int j = 0; j < 4; ++j) {
    u16 lo = f2bf(wp0 * v0[2*j]   + wp1 * v1[2*j]   + wp2 * v2[2*j]);
    u16 hi = f2bf(wp0 * v0[2*j+1] + wp1 * v1[2*j+1] + wp2 * v2[2*j+1]);
    w4[j] = (u32)lo | ((u32)hi << 16);
  }
  o.x = w4[0]; o.y = w4[1]; o.z = w4[2]; o.w = w4[3];
  *(uint4*)(hout + (size_t)n * 512 + l * 8) = o;   // wave writes 1024B contiguous
}

// ---------------- classifier store: clsbuf[N,128] -> d_out[N,23] ----------------
__global__ __launch_bounds__(256) void cls_store(const u16* __restrict__ clsbuf,
                                                 void* __restrict__ out,
                                                 const int* __restrict__ flag) {
  int idx = blockIdx.x * blockDim.x + threadIdx.x;
  if (idx >= N_ * NCLS_) return;
  int n = idx / NCLS_, c = idx - n * NCLS_;
  float s = bf2f(clsbuf[(size_t)n * 128 + c]);
  if (!(s == s)) s = 12345.0f;   // NaN sentinel
  if (*flag) ((u16*)out)[idx] = f2bf(s);
  else       ((float*)out)[idx] = s;
}

static inline int cdiv(long long a, long long b) { return (int)((a + b - 1) / b); }

extern "C" void kernel_launch(void* const* d_in, const int* in_sizes, int n_in,
                              void* d_out, int out_size, void* d_ws, size_t ws_size,
                              hipStream_t stream) {
  // ---- workspace plan (bytes, 256-aligned) ----
  size_t off = 0;
  auto take = [&](size_t bytes) { size_t o = off; off += (bytes + 255) & ~(size_t)255; return o; };
  const size_t o_flag    = take(256);
  const size_t o_stacked = take((size_t)N_ * 1536 * 2);            // 153.6 MB bf16
  const size_t o_h       = take((size_t)N_ * 512 * 2);             //  51.2 MB
  const size_t o_trans   = take((size_t)N_ * 1536 * 2);            // 153.6 MB fbuf / qkv / clsbuf
  const size_t o_el    = take((size_t)N_ * HEADS_ * 4);
  const size_t o_er    = take((size_t)N_ * HEADS_ * 4);
  const size_t o_deg   = take((size_t)2 * R_ * N_ * 4);
  const size_t o_csrp  = take((size_t)R_ * (N_ + 1) * 4);
  const size_t o_eidx  = take((size_t)R_ * E_ * 4);
  const size_t o_fill  = take((size_t)R_ * N_ * 4);
  const size_t o_part  = take((size_t)R_ * SCNB_ * 4);             // scan partials
  const size_t o_wts   = take((size_t)6500000 * 2);                // staged bf16 weights
  const size_t need = off;

  if (ws_size < need) {
    write_const<<<cdiv(out_size, 256), 256, 0, stream>>>((u16*)d_out, out_size,
                                                         (float)(ws_size >> 20));
    return;
  }

  char* base = (char*)d_ws;
  int*   flag    = (int*)(base + o_flag);
  u16*   stacked = (u16*)(base + o_stacked);
  u16*   h       = (u16*)(base + o_h);
  u16*   fbuf    = (u16*)(base + o_trans);     // [N,1536] fused branch GEMM out
  u16*   qkv     = (u16*)(base + o_trans);     // [CHUNK*3,1536] (aliases, disjoint in time)
  u16*   clsbuf  = (u16*)(base + o_trans);     // [N,128]       (aliases, disjoint in time)
  float* el    = (float*)(base + o_el);
  float* er    = (float*)(base + o_er);
  float* degout = (float*)(base + o_deg);
  float* degin  = degout + (size_t)R_ * N_;
  u32*   csrp  = (u32*)(base + o_csrp);
  u32*   eidx  = (u32*)(base + o_eidx);
  u32*   fill  = (u32*)(base + o_fill);
  u32*   part  = (u32*)(base + o_part);

  const int* src = (const int*)d_in[1];
  const int* dst = (const int*)d_in[2];

  // ---- dtype probe ----
  detect_dtype<<<1, 256, 0, stream>>>(d_in[3], flag);

  // ---- staged weight layout (elements within o_wts) ----
  u16* wts   = (u16*)(base + o_wts);
  u16* wbrT  = wts;                              // [6][1536n][512k]: Wc | Wg | Wsk rows
  u16* wqkvT = wbrT + 6 * 786432;                // [2][1536n][512k] (q|k|v)
  u16* bqkv  = wqkvT + 2 * 786432;               // [2][1536]
  u16* wclsT = bqkv + 2 * 1536;                  // [128][512]
  u16* bcls  = wclsT + 128 * 512;                // [128]
  u16* prm   = bcls + 128;                       // 11 x [3072] small params

  stage_bf16<<<cdiv(N_ * 512, 256), 256, 0, stream>>>(d_in[0], 0, h, N_ * 512, flag);
  dim3 tb(32, 8);
  stageT<<<dim3(16, 16, 6), tb, 0, stream>>>(d_in[3],  0, 262144, wbrT,          786432, flag);
  stageT<<<dim3(16, 16, 6), tb, 0, stream>>>(d_in[7],  0, 262144, wbrT + 262144, 786432, flag);
  stageT<<<dim3(16, 16, 6), tb, 0, stream>>>(d_in[13], 0, 262144, wbrT + 524288, 786432, flag);
  stageT<<<dim3(16, 16, 2), tb, 0, stream>>>(d_in[17], 0, 262144, wqkvT,          786432, flag);
  stageT<<<dim3(16, 16, 2), tb, 0, stream>>>(d_in[19], 0, 262144, wqkvT + 262144, 786432, flag);
  stageT<<<dim3(16, 16, 2), tb, 0, stream>>>(d_in[21], 0, 262144, wqkvT + 524288, 786432, flag);
  stage_wclsT<<<cdiv(128 * 512, 256), 256, 0, stream>>>(d_in[23], wclsT, flag);
  stage_bcls<<<1, 128, 0, stream>>>(d_in[24], bcls, flag);
  stage_bqkv<<<cdiv(2 * 1536, 256), 256, 0, stream>>>(d_in[18], d_in[20], d_in[22], bqkv, flag);

  P11 p11;
  p11.p[0] = d_in[4];  p11.p[1] = d_in[5];  p11.p[2]  = d_in[6];
  p11.p[3] = d_in[8];  p11.p[4] = d_in[9];  p11.p[5]  = d_in[10];
  p11.p[6] = d_in[11]; p11.p[7] = d_in[12]; p11.p[8]  = d_in[14];
  p11.p[9] = d_in[15]; p11.p[10] = d_in[16];
  stage_p11<<<cdiv(11 * 3072, 256), 256, 0, stream>>>(p11, prm, flag);
  const u16 *bc  = prm,            *gc  = prm + 3072,  *bec = prm + 2 * 3072;
  const u16 *bg  = prm + 3 * 3072, *al  = prm + 4 * 3072, *ar = prm + 5 * 3072;
  const u16 *gg  = prm + 6 * 3072, *beg = prm + 7 * 3072;
  const u16 *bs  = prm + 8 * 3072, *gs  = prm + 9 * 3072, *bes = prm + 10 * 3072;

  // ---- degrees + CSR (parallel 3-phase scan) ----
  hipMemsetAsync(degout, 0, (size_t)2 * R_ * N_ * sizeof(float), stream);
  deg_count<<<cdiv((long long)R_ * E_, 256), 256, 0, stream>>>(src, dst, degout, degin);
  scan_blksum<<<dim3(SCNB_, R_), 256, 0, stream>>>(degin, part);
  scan_partials<<<R_, 64, 0, stream>>>(part, csrp);
  scan_write<<<dim3(SCNB_, R_), 256, 0, stream>>>(degin, part, csrp);
  deg_fin<<<cdiv((long long)2 * R_ * N_, 256), 256, 0, stream>>>(degout);
  hipMemsetAsync(fill, 0, (size_t)R_ * N_ * sizeof(u32), stream);
  csr_scatter<<<cdiv((long long)R_ * E_, 256), 256, 0, stream>>>(src, dst, csrp, fill, eidx);

  const int mbBR = cdiv(N_, 256);                    // 196
  const int mbQ  = cdiv((long long)CHUNK_ * 3, 256); // 147
  const dim3 gridCLS(cdiv(N_, 128), 1);              // [50000,512] @ [512,128] (legacy kernel)

  for (int l = 0; l < 2; ++l) {
    for (int r = 0; r < 3; ++r) {
      int lr = l * 3 + r;
      const u32* pr = csrp + (size_t)r * (N_ + 1);
      const u32* er_idx = eidx + (size_t)r * E_;
      // fused conv|gat|skip GEMM (256^2 pipelined)
      gemm256<<<mbBR * 6, 512, 0, stream>>>(h, wbrT + (size_t)lr * 786432, nullptr, fbuf, N_, 1536, 6);
      // GAT el/er per node-head (edge softmax fused into agg3_ln)
      gat_el_er<<<cdiv(N_ * HEADS_, 256), 256, 0, stream>>>(fbuf + 512, 1536,
                                                            al + lr * 512, ar + lr * 512,
                                                            el, er);
      // fused edge-softmax + CSR aggregation + 3x LN+ELU + sum -> stacked[:,r,:]
      agg3_ln<<<cdiv(N_, 4), 256, 0, stream>>>(fbuf, pr, er_idx,
                                               degout + r * N_, degin + r * N_, el, er,
                                               bc + lr * 512, gc + lr * 512, bec + lr * 512,
                                               bg + lr * 512, gg + lr * 512, beg + lr * 512,
                                               bs + lr * 512, gs + lr * 512, bes + lr * 512,
                                               stacked + r * 512);
    }
    // fused QKV + relation MHA (chunked; qkv aliases fbuf region)
    for (int c = 0; c < N_ / CHUNK_; ++c) {
      gemm256<<<mbQ * 6, 512, 0, stream>>>(stacked + (size_t)c * CHUNK_ * 1536,
                                           wqkvT + (size_t)l * 786432, bqkv + l * 1536,
                                           qkv, CHUNK_ * 3, 1536, 6);
      mha_fused<<<cdiv(CHUNK_, 4), 256, 0, stream>>>(qkv, h + (size_t)c * CHUNK_ * 512,
                                                     CHUNK_);
    }
  }
  // classifier: MFMA GEMM into padded [N,128] + store
  gemm_mfma<<<gridCLS, 256, 0, stream>>>(h, wclsT, bcls, clsbuf, N_, 128);
  cls_store<<<cdiv((long long)N_ * NCLS_, 256), 256, 0, stream>>>(clsbuf, d_out, flag);
}